// Round 1
// baseline (9376.736 us; speedup 1.0000x reference)
//
#include <hip/hip_runtime.h>

#define ESZ 1024
#define NH 16
#define HD 64
#define NLAYER 4
#define FFD 4096
#define NB 2
#define NXTOK 1023
#define SEQ 1024
#define LNEPS 1e-5f

typedef __attribute__((ext_vector_type(8))) short bf16x8;
typedef __attribute__((ext_vector_type(4))) float f32x4;

__device__ inline unsigned short f2bf(float f) {
  unsigned u = __float_as_uint(f);
  u += 0x7FFFu + ((u >> 16) & 1u);
  return (unsigned short)(u >> 16);
}
__device__ inline float bf2f(unsigned short h) {
  return __uint_as_float(((unsigned)h) << 16);
}

// ---------------------------------------------------------------------------
// Generic MFMA GEMM: C = A @ B (+bias) with f32 inputs converted to bf16
// during LDS staging. NT: C[m][n] = sum_k A[m][k]*B[n][k].
// SPLIT: hi/lo bf16 decomposition, 3 MFMA passes (pseudo-fp32 precision).
// HEADW: scatter C into [B,H,S,HD] head-major layout.
// Batched over blockIdx.z with strides; C offset = (z/cdiv)*sC1 + (z%cdiv)*sC2.
// ---------------------------------------------------------------------------
template<bool NT, bool SPLIT, bool HEADW, bool RELU>
__global__ __launch_bounds__(256)
void gemm_k(const float* __restrict__ A, const float* __restrict__ Bm,
            const float* __restrict__ bias, float* __restrict__ C,
            int M, int N, int K, int lda, int ldb, int ldc,
            long sAz, long sBz, int cdiv, long sC1, long sC2)
{
  constexpr int BM = 128, BN = 128, BK = 32, LSTR = 48;
  __shared__ unsigned short Ah[BM * LSTR];
  __shared__ unsigned short Bh[BN * LSTR];
  __shared__ unsigned short Al[SPLIT ? BM * LSTR : 1];
  __shared__ unsigned short Bl[SPLIT ? BN * LSTR : 1];

  const int z = blockIdx.z;
  const float* Ab = A + (size_t)z * sAz;
  const float* Bb = Bm + (size_t)z * sBz;
  const size_t coff = (size_t)(z / cdiv) * sC1 + (size_t)(z % cdiv) * sC2;

  const int m0 = blockIdx.x * BM;
  const int n0 = blockIdx.y * BN;
  const int tid = threadIdx.x;
  const int lane = tid & 63;
  const int w = tid >> 6;
  const int wr = (w >> 1) * 64;
  const int wc = (w & 1) * 64;
  const int lr = lane & 15;
  const int lk = (lane >> 4) * 8;

  const f32x4 vzero = {0.f, 0.f, 0.f, 0.f};
  f32x4 acc[4][4];
#pragma unroll
  for (int i = 0; i < 4; i++)
#pragma unroll
    for (int j = 0; j < 4; j++) acc[i][j] = vzero;

  const int nk = K / BK;
  for (int kt = 0; kt < nk; ++kt) {
    const int k0 = kt * BK;
    // ---- stage A tile [BM x BK] ----
    for (int f = tid; f < BM * BK / 4; f += 256) {
      int r = f >> 3;
      int c4 = (f & 7) << 2;
      int gr = m0 + r;
      float4 v = make_float4(0.f, 0.f, 0.f, 0.f);
      if (gr < M) v = *(const float4*)(Ab + (size_t)gr * lda + k0 + c4);
      int base = r * LSTR + c4;
      float vv[4] = {v.x, v.y, v.z, v.w};
#pragma unroll
      for (int j = 0; j < 4; j++) {
        unsigned short h = f2bf(vv[j]);
        Ah[base + j] = h;
        if (SPLIT) Al[base + j] = f2bf(vv[j] - bf2f(h));
      }
    }
    // ---- stage B tile ----
    if (NT) {
      for (int f = tid; f < BN * BK / 4; f += 256) {
        int r = f >> 3;
        int c4 = (f & 7) << 2;
        int gr = n0 + r;
        float4 v = make_float4(0.f, 0.f, 0.f, 0.f);
        if (gr < N) v = *(const float4*)(Bb + (size_t)gr * ldb + k0 + c4);
        int base = r * LSTR + c4;
        float vv[4] = {v.x, v.y, v.z, v.w};
#pragma unroll
        for (int j = 0; j < 4; j++) {
          unsigned short h = f2bf(vv[j]);
          Bh[base + j] = h;
          if (SPLIT) Bl[base + j] = f2bf(vv[j] - bf2f(h));
        }
      }
    } else {
      for (int f = tid; f < BK * BN / 4; f += 256) {
        int kk = f >> 5;
        int c4 = (f & 31) << 2;
        int gc = n0 + c4;
        float4 v = make_float4(0.f, 0.f, 0.f, 0.f);
        if (gc + 3 < N) v = *(const float4*)(Bb + (size_t)(k0 + kk) * ldb + gc);
        float vv[4] = {v.x, v.y, v.z, v.w};
#pragma unroll
        for (int j = 0; j < 4; j++) {
          unsigned short h = f2bf(vv[j]);
          Bh[(c4 + j) * LSTR + kk] = h;
          if (SPLIT) Bl[(c4 + j) * LSTR + kk] = f2bf(vv[j] - bf2f(h));
        }
      }
    }
    __syncthreads();

    bf16x8 af[4], bfv[4];
#pragma unroll
    for (int i = 0; i < 4; i++) af[i] = *(const bf16x8*)(&Ah[(wr + i * 16 + lr) * LSTR + lk]);
#pragma unroll
    for (int j = 0; j < 4; j++) bfv[j] = *(const bf16x8*)(&Bh[(wc + j * 16 + lr) * LSTR + lk]);
#pragma unroll
    for (int i = 0; i < 4; i++)
#pragma unroll
      for (int j = 0; j < 4; j++)
        acc[i][j] = __builtin_amdgcn_mfma_f32_16x16x32_bf16(af[i], bfv[j], acc[i][j], 0, 0, 0);
    if (SPLIT) {
      bf16x8 al[4], bl[4];
#pragma unroll
      for (int i = 0; i < 4; i++) al[i] = *(const bf16x8*)(&Al[(wr + i * 16 + lr) * LSTR + lk]);
#pragma unroll
      for (int j = 0; j < 4; j++) bl[j] = *(const bf16x8*)(&Bl[(wc + j * 16 + lr) * LSTR + lk]);
#pragma unroll
      for (int i = 0; i < 4; i++)
#pragma unroll
        for (int j = 0; j < 4; j++) {
          acc[i][j] = __builtin_amdgcn_mfma_f32_16x16x32_bf16(af[i], bl[j], acc[i][j], 0, 0, 0);
          acc[i][j] = __builtin_amdgcn_mfma_f32_16x16x32_bf16(al[i], bfv[j], acc[i][j], 0, 0, 0);
        }
    }
    __syncthreads();
  }

  // ---- epilogue: D lane mapping col=lane&15, row=(lane>>4)*4+reg ----
#pragma unroll
  for (int i = 0; i < 4; i++) {
#pragma unroll
    for (int j = 0; j < 4; j++) {
      int col = n0 + wc + j * 16 + lr;
      if (col >= N) continue;
      float bv = bias ? bias[col] : 0.f;
#pragma unroll
      for (int r = 0; r < 4; r++) {
        int row = m0 + wr + i * 16 + (lane >> 4) * 4 + r;
        if (row >= M) continue;
        float out = acc[i][j][r] + bv;
        if (RELU) out = fmaxf(out, 0.f);
        if (HEADW) {
          size_t idx = ((size_t)(row >> 10) * NH + (col >> 6)) * (size_t)(SEQ * HD)
                     + (size_t)(row & (SEQ - 1)) * HD + (col & (HD - 1));
          C[idx] = out;
        } else {
          C[coff + (size_t)row * ldc + col] = out;
        }
      }
    }
  }
}

// ---------------------------------------------------------------------------
// Row softmax over 1024 cols, scale 1/32 applied pre-softmax. causal=1 limits
// to k<=q (mask-before-scale gives exp()==0 for masked, identical result).
// ---------------------------------------------------------------------------
__global__ __launch_bounds__(256)
void softmax_k(float* __restrict__ sc, int causal)
{
  int rowg = blockIdx.x;
  int q = rowg & (SEQ - 1);
  float* p = sc + (size_t)rowg * SEQ;
  int limit = causal ? (q + 1) : SEQ;
  int tid = threadIdx.x;
  float4 v = *(const float4*)(p + tid * 4);
  float x[4] = {v.x, v.y, v.z, v.w};
  const float scl = 1.f / 32.f;
  float mx = -1e30f;
#pragma unroll
  for (int j = 0; j < 4; j++) {
    int c = tid * 4 + j;
    if (c < limit) mx = fmaxf(mx, x[j] * scl);
  }
  for (int o = 32; o > 0; o >>= 1) mx = fmaxf(mx, __shfl_xor(mx, o, 64));
  __shared__ float red[4];
  __shared__ float red2[4];
  if ((tid & 63) == 0) red[tid >> 6] = mx;
  __syncthreads();
  mx = fmaxf(fmaxf(red[0], red[1]), fmaxf(red[2], red[3]));
  float sum = 0.f;
  float e[4];
#pragma unroll
  for (int j = 0; j < 4; j++) {
    int c = tid * 4 + j;
    e[j] = (c < limit) ? expf(x[j] * scl - mx) : 0.f;
    sum += e[j];
  }
  for (int o = 32; o > 0; o >>= 1) sum += __shfl_xor(sum, o, 64);
  if ((tid & 63) == 0) red2[tid >> 6] = sum;
  __syncthreads();
  sum = red2[0] + red2[1] + red2[2] + red2[3];
  float inv = 1.f / sum;
  float4 ov;
  ov.x = e[0] * inv; ov.y = e[1] * inv; ov.z = e[2] * inv; ov.w = e[3] * inv;
  *(float4*)(p + tid * 4) = ov;
}

// ---------------------------------------------------------------------------
// out = LayerNorm(a + r) * g + b, one block per row of E=1024
// ---------------------------------------------------------------------------
__global__ __launch_bounds__(256)
void lnres_k(const float* __restrict__ a, const float* __restrict__ r,
             const float* __restrict__ g, const float* __restrict__ b,
             float* __restrict__ out)
{
  int row = blockIdx.x;
  size_t off = (size_t)row * ESZ;
  int tid = threadIdx.x;
  float4 va = *(const float4*)(a + off + tid * 4);
  float4 vr = *(const float4*)(r + off + tid * 4);
  float x[4] = {va.x + vr.x, va.y + vr.y, va.z + vr.z, va.w + vr.w};
  float s = x[0] + x[1] + x[2] + x[3];
  float s2 = x[0] * x[0] + x[1] * x[1] + x[2] * x[2] + x[3] * x[3];
  for (int o = 32; o > 0; o >>= 1) {
    s += __shfl_xor(s, o, 64);
    s2 += __shfl_xor(s2, o, 64);
  }
  __shared__ float rs[4], rs2[4];
  if ((tid & 63) == 0) { rs[tid >> 6] = s; rs2[tid >> 6] = s2; }
  __syncthreads();
  s = rs[0] + rs[1] + rs[2] + rs[3];
  s2 = rs2[0] + rs2[1] + rs2[2] + rs2[3];
  float mean = s * (1.f / ESZ);
  float var = s2 * (1.f / ESZ) - mean * mean;
  float inv = 1.f / sqrtf(var + LNEPS);
  float4 vo;
#pragma unroll
  for (int j = 0; j < 4; j++) {
    int c = tid * 4 + j;
    ((float*)&vo)[j] = (x[j] - mean) * inv * g[c] + b[c];
  }
  *(float4*)(out + off + tid * 4) = vo;
}

// ---------------------------------------------------------------------------
// Embedding + positional encoding (quirk: pe row index = BATCH index,
// broadcast over sequence). x gets cls appended raw at t=1023.
// rows 0..2047 -> x, 2048..4095 -> y
// ---------------------------------------------------------------------------
__global__ __launch_bounds__(256)
void embed_k(const int* __restrict__ xt, const int* __restrict__ yt,
             const float* __restrict__ emb, const float* __restrict__ cls,
             float* __restrict__ x, float* __restrict__ y)
{
  int row = blockIdx.x;
  bool isx = row < NB * SEQ;
  int rr = isx ? row : row - NB * SEQ;
  int b = rr >> 10, t = rr & (SEQ - 1);
  float* out = (isx ? x : y) + (size_t)rr * ESZ;
  int col0 = threadIdx.x * 4;
  if (isx && t == SEQ - 1) {
#pragma unroll
    for (int j = 0; j < 4; j++) out[col0 + j] = cls[col0 + j];
    return;
  }
  int tok = isx ? xt[b * NXTOK + t] : yt[b * SEQ + t];
  const float* erow = emb + (size_t)tok * ESZ;
#pragma unroll
  for (int j = 0; j < 4; j++) {
    int e = col0 + j;
    int i2 = e & ~1;
    float div = expf((float)i2 * (-9.210340371976184f / 1024.f));
    float ang = (float)b * div;
    float pe = (e & 1) ? cosf(ang) : sinf(ang);
    out[e] = erow[e] * 32.f + pe;
  }
}

// ---------------------------------------------------------------------------

template<bool NT, bool SPLIT, bool HEADW, bool RELU>
static void gemm_launch(hipStream_t st, const float* A, const float* Bm,
                        const float* bias, float* C,
                        int M, int N, int K, int lda, int ldb, int ldc,
                        int Z, long sAz, long sBz, int cdiv, long sC1, long sC2)
{
  dim3 g((M + 127) / 128, (N + 127) / 128, Z);
  gemm_k<NT, SPLIT, HEADW, RELU><<<g, dim3(256), 0, st>>>(
      A, Bm, bias, C, M, N, K, lda, ldb, ldc, sAz, sBz, cdiv, sC1, sC2);
}

extern "C" void kernel_launch(void* const* d_in, const int* in_sizes, int n_in,
                              void* d_out, int out_size, void* d_ws, size_t ws_size,
                              hipStream_t stream) {
  (void)n_in; (void)out_size; (void)ws_size;
  const float *emb, *cls, *sWq, *sbq, *sWk, *sbk, *sWv, *sbv, *sWo, *sbo;
  const float *cWq, *cbq, *cWk, *cbk, *cWv, *cbv, *cWo, *cbo;
  const float *fW1, *fb1, *fW2, *fb2, *g1, *g2, *g3, *b1, *b2, *b3;
  const int *xt, *yt;
  if (in_sizes[0] == NB * NXTOK) {
    // reference-signature order fallback
    xt = (const int*)d_in[0]; yt = (const int*)d_in[1];
    emb = (const float*)d_in[2]; cls = (const float*)d_in[3];
    sWq = (const float*)d_in[4]; sbq = (const float*)d_in[5];
    sWk = (const float*)d_in[6]; sbk = (const float*)d_in[7];
    sWv = (const float*)d_in[8]; sbv = (const float*)d_in[9];
    sWo = (const float*)d_in[10]; sbo = (const float*)d_in[11];
    cWq = (const float*)d_in[12]; cbq = (const float*)d_in[13];
    cWk = (const float*)d_in[14]; cbk = (const float*)d_in[15];
    cWv = (const float*)d_in[16]; cbv = (const float*)d_in[17];
    cWo = (const float*)d_in[18]; cbo = (const float*)d_in[19];
    g1 = (const float*)d_in[20]; b1 = (const float*)d_in[21];
    g2 = (const float*)d_in[22]; b2 = (const float*)d_in[23];
    g3 = (const float*)d_in[24]; b3 = (const float*)d_in[25];
    fW1 = (const float*)d_in[26]; fb1 = (const float*)d_in[27];
    fW2 = (const float*)d_in[28]; fb2 = (const float*)d_in[29];
  } else {
    // setup_inputs() dict order (expected)
    emb = (const float*)d_in[0]; cls = (const float*)d_in[1];
    sWq = (const float*)d_in[2]; sbq = (const float*)d_in[3];
    sWk = (const float*)d_in[4]; sbk = (const float*)d_in[5];
    sWv = (const float*)d_in[6]; sbv = (const float*)d_in[7];
    sWo = (const float*)d_in[8]; sbo = (const float*)d_in[9];
    cWq = (const float*)d_in[10]; cbq = (const float*)d_in[11];
    cWk = (const float*)d_in[12]; cbk = (const float*)d_in[13];
    cWv = (const float*)d_in[14]; cbv = (const float*)d_in[15];
    cWo = (const float*)d_in[16]; cbo = (const float*)d_in[17];
    fW1 = (const float*)d_in[18]; fb1 = (const float*)d_in[19];
    fW2 = (const float*)d_in[20]; fb2 = (const float*)d_in[21];
    g1 = (const float*)d_in[22]; g2 = (const float*)d_in[23]; g3 = (const float*)d_in[24];
    b1 = (const float*)d_in[25]; b2 = (const float*)d_in[26]; b3 = (const float*)d_in[27];
    xt = (const int*)d_in[28]; yt = (const int*)d_in[29];
  }

  float* W = (float*)d_ws;
  const size_t T = (size_t)NB * SEQ * ESZ;  // 2M floats
  float* y   = W;
  float* x   = W + T;
  float* yl  = W + 2 * T;
  float* qh  = W + 3 * T;
  float* kh  = W + 4 * T;
  float* vh  = W + 5 * T;
  float* ob  = W + 6 * T;
  float* tmp = W + 7 * T;
  float* ffn = W + 8 * T;          // 4*T floats
  float* sc  = W + 12 * T;         // 16*T floats

  embed_k<<<dim3(2 * NB * SEQ), dim3(256), 0, stream>>>(xt, yt, emb, cls, x, y);

  const int M2 = NB * SEQ;  // 2048
  const long SH = (long)SEQ * HD;    // 65536
  const long SS = (long)SEQ * SEQ;   // 1048576
  const long SE = (long)SEQ * ESZ;   // 1048576

  for (int l = 0; l < NLAYER; l++) {
    const float* sWq_l = sWq + (size_t)l * ESZ * ESZ;
    const float* sWk_l = sWk + (size_t)l * ESZ * ESZ;
    const float* sWv_l = sWv + (size_t)l * ESZ * ESZ;
    const float* sWo_l = sWo + (size_t)l * ESZ * ESZ;
    const float* cWq_l = cWq + (size_t)l * ESZ * ESZ;
    const float* cWk_l = cWk + (size_t)l * ESZ * ESZ;
    const float* cWv_l = cWv + (size_t)l * ESZ * ESZ;
    const float* cWo_l = cWo + (size_t)l * ESZ * ESZ;
    const float* fW1_l = fW1 + (size_t)l * ESZ * FFD;
    const float* fW2_l = fW2 + (size_t)l * ESZ * FFD;

    // ---- self-attention over ORIGINAL y (quirk) ----
    gemm_launch<false, true, true, false>(stream, y, sWq_l, sbq + l * ESZ, qh,
        M2, ESZ, ESZ, ESZ, ESZ, 0, 1, 0, 0, 1, 0, 0);
    gemm_launch<false, true, true, false>(stream, y, sWk_l, sbk + l * ESZ, kh,
        M2, ESZ, ESZ, ESZ, ESZ, 0, 1, 0, 0, 1, 0, 0);
    gemm_launch<false, false, true, false>(stream, y, sWv_l, sbv + l * ESZ, vh,
        M2, ESZ, ESZ, ESZ, ESZ, 0, 1, 0, 0, 1, 0, 0);
    gemm_launch<true, true, false, false>(stream, qh, kh, nullptr, sc,
        SEQ, SEQ, HD, HD, HD, SEQ, NB * NH, SH, SH, NB * NH, 0, SS);
    softmax_k<<<dim3(NB * NH * SEQ), dim3(256), 0, stream>>>(sc, 1);
    gemm_launch<false, false, false, false>(stream, sc, vh, nullptr, ob,
        SEQ, HD, SEQ, SEQ, HD, ESZ, NB * NH, SS, SH, NH, SE, (long)HD);
    gemm_launch<false, false, false, false>(stream, ob, sWo_l, sbo + l * ESZ, tmp,
        M2, ESZ, ESZ, ESZ, ESZ, ESZ, 1, 0, 0, 1, 0, 0);
    lnres_k<<<dim3(M2), dim3(256), 0, stream>>>(y, tmp, g1 + l * ESZ, b1 + l * ESZ, yl);

    // ---- cross-attention: q from yl, k/v from current x ----
    gemm_launch<false, false, true, false>(stream, yl, cWq_l, cbq + l * ESZ, qh,
        M2, ESZ, ESZ, ESZ, ESZ, 0, 1, 0, 0, 1, 0, 0);
    gemm_launch<false, false, true, false>(stream, x, cWk_l, cbk + l * ESZ, kh,
        M2, ESZ, ESZ, ESZ, ESZ, 0, 1, 0, 0, 1, 0, 0);
    gemm_launch<false, false, true, false>(stream, x, cWv_l, cbv + l * ESZ, vh,
        M2, ESZ, ESZ, ESZ, ESZ, 0, 1, 0, 0, 1, 0, 0);
    gemm_launch<true, false, false, false>(stream, qh, kh, nullptr, sc,
        SEQ, SEQ, HD, HD, HD, SEQ, NB * NH, SH, SH, NB * NH, 0, SS);
    softmax_k<<<dim3(NB * NH * SEQ), dim3(256), 0, stream>>>(sc, 0);
    gemm_launch<false, false, false, false>(stream, sc, vh, nullptr, ob,
        SEQ, HD, SEQ, SEQ, HD, ESZ, NB * NH, SS, SH, NH, SE, (long)HD);
    gemm_launch<false, false, false, false>(stream, ob, cWo_l, cbo + l * ESZ, tmp,
        M2, ESZ, ESZ, ESZ, ESZ, ESZ, 1, 0, 0, 1, 0, 0);
    lnres_k<<<dim3(M2), dim3(256), 0, stream>>>(yl, tmp, g2 + l * ESZ, b2 + l * ESZ, x);

    // ---- FFN ----
    gemm_launch<false, false, false, true>(stream, x, fW1_l, fb1 + l * FFD, ffn,
        M2, FFD, ESZ, ESZ, FFD, FFD, 1, 0, 0, 1, 0, 0);
    gemm_launch<false, false, false, false>(stream, ffn, fW2_l, fb2 + l * ESZ, tmp,
        M2, ESZ, FFD, FFD, ESZ, ESZ, 1, 0, 0, 1, 0, 0);
    float* xout = (l == NLAYER - 1) ? (float*)d_out : x;
    lnres_k<<<dim3(M2), dim3(256), 0, stream>>>(x, tmp, g3 + l * ESZ, b3 + l * ESZ, xout);
  }
}

// Round 2
// 1713.189 us; speedup vs baseline: 5.4733x; 5.4733x over previous
//
#include <hip/hip_runtime.h>
#include <cstdint>

#define ESZ 1024
#define NH 16
#define HD 64
#define NLAYER 4
#define FFD 4096
#define NB 2
#define NXTOK 1023
#define SEQ 1024
#define LNEPS 1e-5f

typedef __attribute__((ext_vector_type(8))) _Float16 f16x8;
typedef __attribute__((ext_vector_type(4))) _Float16 f16x4;
typedef __attribute__((ext_vector_type(4))) float f32x4;

__device__ __forceinline__ void gld16(const void* g, void* l) {
  __builtin_amdgcn_global_load_lds(
      (const __attribute__((address_space(1))) unsigned int*)g,
      (__attribute__((address_space(3))) unsigned int*)l, 16, 0, 0);
}

// ---------------------------------------------------------------------------
// NT MFMA GEMM, f16 inputs: C = A @ B^T (+bias). A [M][K] lda, B [N][K] ldb.
// BK=64, BM=128, BN template. global_load_lds staging with XOR-swizzled
// global source (LDS stays linear); ds_read applies the same XOR -> 2-way
// conflicts only (free). EPI: 0 = f32 C, 1 = f16 C, 2 = QKV head scatter
// (seg<vseg -> [seg][b][h][s][d] at C0, seg==vseg -> V^T [b][h][d][s] at C1).
// ---------------------------------------------------------------------------
template<int BN, int EPI, bool RELU>
__global__ __launch_bounds__(256)
void gemm_k(const _Float16* __restrict__ A, const _Float16* __restrict__ Bm,
            const float* __restrict__ bias0, const float* __restrict__ bias1,
            const float* __restrict__ bias2,
            void* __restrict__ C0, void* __restrict__ C1,
            int K, int lda, int ldb, int ldc,
            long sAz, long sBz, int cdiv, long sC1, long sC2,
            float cscale, int vseg)
{
  constexpr int NJ = BN / 32;
  __shared__ _Float16 Ah[128 * 64];
  __shared__ _Float16 Bh[BN * 64];

  const int z = blockIdx.z;
  const _Float16* Ab = A + (size_t)z * sAz;
  const _Float16* Bb = Bm + (size_t)z * sBz;
  const size_t coff = (size_t)(z / cdiv) * sC1 + (size_t)(z % cdiv) * sC2;
  const int m0 = blockIdx.x * 128;
  const int n0 = blockIdx.y * BN;
  const int tid = threadIdx.x;
  const int lane = tid & 63;
  const int w = tid >> 6;
  const int lr = lane & 15;
  const int hi = lane >> 4;
  const int wr = (w >> 1) * 64;
  const int wc = (w & 1) * (BN / 2);

  const f32x4 vz = {0.f, 0.f, 0.f, 0.f};
  f32x4 acc[4][NJ];
#pragma unroll
  for (int i = 0; i < 4; i++)
#pragma unroll
    for (int j = 0; j < NJ; j++) acc[i][j] = vz;

  const int nk = K >> 6;
  for (int kt = 0; kt < nk; ++kt) {
    const int k0 = kt << 6;
    // stage A: each wave 32 rows, 4 calls; LDS linear, global col swizzled
#pragma unroll
    for (int c = 0; c < 4; c++) {
      int r = w * 32 + c * 8 + (lane >> 3);
      int cg = ((lane & 7) ^ (r & 7)) << 3;
      gld16(Ab + (size_t)(m0 + r) * lda + k0 + cg, &Ah[(w * 32 + c * 8) * 64]);
    }
#pragma unroll
    for (int c = 0; c < BN / 32; c++) {
      int r = w * (BN / 4) + c * 8 + (lane >> 3);
      int cg = ((lane & 7) ^ (r & 7)) << 3;
      gld16(Bb + (size_t)(n0 + r) * ldb + k0 + cg, &Bh[(w * (BN / 4) + c * 8) * 64]);
    }
    __syncthreads();
#pragma unroll
    for (int kk = 0; kk < 2; kk++) {
      f16x8 af[4], bf[NJ];
#pragma unroll
      for (int i = 0; i < 4; i++) {
        int row = wr + i * 16 + lr;
        int off = ((kk << 6) | (hi << 4)) ^ ((row & 7) << 4);
        af[i] = *(const f16x8*)((const char*)Ah + row * 128 + off);
      }
#pragma unroll
      for (int j = 0; j < NJ; j++) {
        int row = wc + j * 16 + lr;
        int off = ((kk << 6) | (hi << 4)) ^ ((row & 7) << 4);
        bf[j] = *(const f16x8*)((const char*)Bh + row * 128 + off);
      }
#pragma unroll
      for (int i = 0; i < 4; i++)
#pragma unroll
        for (int j = 0; j < NJ; j++)
          acc[i][j] = __builtin_amdgcn_mfma_f32_16x16x32_f16(af[i], bf[j], acc[i][j], 0, 0, 0);
    }
    __syncthreads();
  }

  const int rb = hi * 4;
#pragma unroll
  for (int j = 0; j < NJ; j++) {
    const int n = n0 + wc + j * 16 + lr;
    float bv = 0.f;
    if (EPI == 2) {
      int seg = n >> 10;
      const float* bp = (seg == 0) ? bias0 : ((seg == 1) ? bias1 : bias2);
      bv = bp[n & 1023];
    } else if (bias0) bv = bias0[n];
#pragma unroll
    for (int i = 0; i < 4; i++) {
#pragma unroll
      for (int r = 0; r < 4; r++) {
        int row = m0 + wr + i * 16 + rb + r;
        float out = acc[i][j][r] * cscale + bv;
        if (RELU) out = fmaxf(out, 0.f);
        if (EPI == 0) {
          ((float*)C0)[coff + (size_t)row * ldc + n] = out;
        } else if (EPI == 1) {
          ((_Float16*)C0)[coff + (size_t)row * ldc + n] = (_Float16)out;
        } else {
          int seg = n >> 10, n1 = n & 1023, h = n1 >> 6, d = n1 & 63;
          int b = row >> 10, s = row & 1023;
          if (seg == vseg)
            ((_Float16*)C1)[(((size_t)b * NH + h) * HD + d) * SEQ + s] = (_Float16)out;
          else
            ((_Float16*)C0)[(size_t)seg * ((size_t)NB * NH * SEQ * HD)
                            + (((size_t)b * NH + h) * SEQ + s) * HD + d] = (_Float16)out;
        }
      }
    }
  }
}

// ---------------------------------------------------------------------------
// Weight convert+transpose: src f32 [K][Ns] -> dst f16 [Ns][K]
// ---------------------------------------------------------------------------
__global__ __launch_bounds__(256)
void wtr_k(const float* __restrict__ src, _Float16* __restrict__ dst, int K, int Ns)
{
  __shared__ _Float16 t[64][80];
  const int k0 = blockIdx.x * 64, n0 = blockIdx.y * 64;
  const int tid = threadIdx.x;
  {
    int r = tid >> 4, c4 = (tid & 15) << 2;
#pragma unroll
    for (int rr = 0; rr < 4; rr++) {
      int row = r + rr * 16;
      float4 v = *(const float4*)(src + (size_t)(k0 + row) * Ns + n0 + c4);
      t[c4 + 0][row] = (_Float16)v.x; t[c4 + 1][row] = (_Float16)v.y;
      t[c4 + 2][row] = (_Float16)v.z; t[c4 + 3][row] = (_Float16)v.w;
    }
  }
  __syncthreads();
  {
    int nr = tid >> 3, c8 = (tid & 7) << 3;
#pragma unroll
    for (int rr = 0; rr < 2; rr++) {
      int n = nr + rr * 32;
      f16x8 v = *(const f16x8*)&t[n][c8];
      *(f16x8*)(dst + (size_t)(n0 + n) * K + k0 + c8) = v;
    }
  }
}

// ---------------------------------------------------------------------------
// Embedding + PE (quirk: pe row = batch index). x rows get f16 only; y rows
// get f32 (residual) + f16 (GEMM input).
// ---------------------------------------------------------------------------
__global__ __launch_bounds__(256)
void embed_k(const int* __restrict__ xt, const int* __restrict__ yt,
             const float* __restrict__ emb, const float* __restrict__ cls,
             float* __restrict__ y32, _Float16* __restrict__ y16,
             _Float16* __restrict__ x16)
{
  int row = blockIdx.x;
  bool isx = row < NB * SEQ;
  int rr = isx ? row : row - NB * SEQ;
  int b = rr >> 10, tpos = rr & (SEQ - 1);
  int col0 = threadIdx.x * 4;
  float v[4];
  if (isx && tpos == SEQ - 1) {
#pragma unroll
    for (int j = 0; j < 4; j++) v[j] = cls[col0 + j];
  } else {
    int tok = isx ? xt[b * NXTOK + tpos] : yt[b * SEQ + tpos];
    const float* erow = emb + (size_t)tok * ESZ;
#pragma unroll
    for (int j = 0; j < 4; j++) {
      int e = col0 + j;
      float div = expf((float)(e & ~1) * (-9.210340371976184f / 1024.f));
      float ang = (float)b * div;
      float pe = (e & 1) ? cosf(ang) : sinf(ang);
      v[j] = erow[e] * 32.f + pe;
    }
  }
  size_t off = (size_t)rr * ESZ + col0;
  if (isx) {
#pragma unroll
    for (int j = 0; j < 4; j++) x16[off + j] = (_Float16)v[j];
  } else {
#pragma unroll
    for (int j = 0; j < 4; j++) { y32[off + j] = v[j]; y16[off + j] = (_Float16)v[j]; }
  }
}

// ---------------------------------------------------------------------------
// In-place f16 row softmax (scores already scaled by 1/32 in GEMM epilogue).
// ---------------------------------------------------------------------------
__global__ __launch_bounds__(256)
void softmax_k(_Float16* __restrict__ sc, int causal)
{
  int rowg = blockIdx.x;
  int q = rowg & (SEQ - 1);
  int limit = causal ? (q + 1) : SEQ;
  _Float16* p = sc + (size_t)rowg * SEQ;
  int tid = threadIdx.x;
  f16x4 v = *(const f16x4*)(p + tid * 4);
  float x[4];
#pragma unroll
  for (int j = 0; j < 4; j++) x[j] = (float)v[j];
  float mx = -1e30f;
#pragma unroll
  for (int j = 0; j < 4; j++) if (tid * 4 + j < limit) mx = fmaxf(mx, x[j]);
  for (int o = 32; o > 0; o >>= 1) mx = fmaxf(mx, __shfl_xor(mx, o, 64));
  __shared__ float r1[4], r2[4];
  if ((tid & 63) == 0) r1[tid >> 6] = mx;
  __syncthreads();
  mx = fmaxf(fmaxf(r1[0], r1[1]), fmaxf(r1[2], r1[3]));
  float e[4], sum = 0.f;
#pragma unroll
  for (int j = 0; j < 4; j++) {
    e[j] = (tid * 4 + j < limit) ? expf(x[j] - mx) : 0.f;
    sum += e[j];
  }
  for (int o = 32; o > 0; o >>= 1) sum += __shfl_xor(sum, o, 64);
  if ((tid & 63) == 0) r2[tid >> 6] = sum;
  __syncthreads();
  sum = r2[0] + r2[1] + r2[2] + r2[3];
  float inv = 1.f / sum;
  f16x4 ov;
#pragma unroll
  for (int j = 0; j < 4; j++) ov[j] = (_Float16)(e[j] * inv);
  *(f16x4*)(p + tid * 4) = ov;
}

// ---------------------------------------------------------------------------
// out = LN(a + r)*g + b; writes f32 (residual stream) and f16 (GEMM input)
// ---------------------------------------------------------------------------
__global__ __launch_bounds__(256)
void lnres_k(const float* __restrict__ a, const float* __restrict__ r,
             const float* __restrict__ g, const float* __restrict__ b,
             float* __restrict__ o32, _Float16* __restrict__ o16)
{
  int row = blockIdx.x;
  size_t off = (size_t)row * ESZ;
  int tid = threadIdx.x;
  float4 va = *(const float4*)(a + off + tid * 4);
  float4 vr = *(const float4*)(r + off + tid * 4);
  float x[4] = {va.x + vr.x, va.y + vr.y, va.z + vr.z, va.w + vr.w};
  float s = x[0] + x[1] + x[2] + x[3];
  float s2 = x[0] * x[0] + x[1] * x[1] + x[2] * x[2] + x[3] * x[3];
  for (int o = 32; o > 0; o >>= 1) {
    s += __shfl_xor(s, o, 64);
    s2 += __shfl_xor(s2, o, 64);
  }
  __shared__ float rs[4], rs2[4];
  if ((tid & 63) == 0) { rs[tid >> 6] = s; rs2[tid >> 6] = s2; }
  __syncthreads();
  s = rs[0] + rs[1] + rs[2] + rs[3];
  s2 = rs2[0] + rs2[1] + rs2[2] + rs2[3];
  float mean = s * (1.f / ESZ);
  float var = s2 * (1.f / ESZ) - mean * mean;
  float inv = 1.f / sqrtf(var + LNEPS);
  float4 vo;
#pragma unroll
  for (int j = 0; j < 4; j++) {
    int c = tid * 4 + j;
    float o = (x[j] - mean) * inv * g[c] + b[c];
    ((float*)&vo)[j] = o;
    o16[off + c] = (_Float16)o;
  }
  *(float4*)(o32 + off + tid * 4) = vo;
}

// ---------------------------------------------------------------------------

template<int BN, int EPI, bool RELU>
static void gemm(hipStream_t st, const _Float16* A, const _Float16* B,
                 const float* b0, const float* b1, const float* b2,
                 void* C0, void* C1, int M, int N, int K,
                 int lda, int ldb, int ldc,
                 int Z, long sAz, long sBz, int cdiv, long sC1, long sC2,
                 float cscale, int vseg)
{
  dim3 g(M / 128, N / BN, Z);
  gemm_k<BN, EPI, RELU><<<g, dim3(256), 0, st>>>(
      A, B, b0, b1, b2, C0, C1, K, lda, ldb, ldc, sAz, sBz, cdiv, sC1, sC2, cscale, vseg);
}

extern "C" void kernel_launch(void* const* d_in, const int* in_sizes, int n_in,
                              void* d_out, int out_size, void* d_ws, size_t ws_size,
                              hipStream_t stream) {
  (void)n_in; (void)out_size; (void)ws_size;
  const float *emb, *cls, *sWq, *sbq, *sWk, *sbk, *sWv, *sbv, *sWo, *sbo;
  const float *cWq, *cbq, *cWk, *cbk, *cWv, *cbv, *cWo, *cbo;
  const float *fW1, *fb1, *fW2, *fb2, *g1, *g2, *g3, *b1, *b2, *b3;
  const int *xt, *yt;
  if (in_sizes[0] == NB * NXTOK) {
    xt = (const int*)d_in[0]; yt = (const int*)d_in[1];
    emb = (const float*)d_in[2]; cls = (const float*)d_in[3];
    sWq = (const float*)d_in[4]; sbq = (const float*)d_in[5];
    sWk = (const float*)d_in[6]; sbk = (const float*)d_in[7];
    sWv = (const float*)d_in[8]; sbv = (const float*)d_in[9];
    sWo = (const float*)d_in[10]; sbo = (const float*)d_in[11];
    cWq = (const float*)d_in[12]; cbq = (const float*)d_in[13];
    cWk = (const float*)d_in[14]; cbk = (const float*)d_in[15];
    cWv = (const float*)d_in[16]; cbv = (const float*)d_in[17];
    cWo = (const float*)d_in[18]; cbo = (const float*)d_in[19];
    g1 = (const float*)d_in[20]; b1 = (const float*)d_in[21];
    g2 = (const float*)d_in[22]; b2 = (const float*)d_in[23];
    g3 = (const float*)d_in[24]; b3 = (const float*)d_in[25];
    fW1 = (const float*)d_in[26]; fb1 = (const float*)d_in[27];
    fW2 = (const float*)d_in[28]; fb2 = (const float*)d_in[29];
  } else {
    emb = (const float*)d_in[0]; cls = (const float*)d_in[1];
    sWq = (const float*)d_in[2]; sbq = (const float*)d_in[3];
    sWk = (const float*)d_in[4]; sbk = (const float*)d_in[5];
    sWv = (const float*)d_in[6]; sbv = (const float*)d_in[7];
    sWo = (const float*)d_in[8]; sbo = (const float*)d_in[9];
    cWq = (const float*)d_in[10]; cbq = (const float*)d_in[11];
    cWk = (const float*)d_in[12]; cbk = (const float*)d_in[13];
    cWv = (const float*)d_in[14]; cbv = (const float*)d_in[15];
    cWo = (const float*)d_in[16]; cbo = (const float*)d_in[17];
    fW1 = (const float*)d_in[18]; fb1 = (const float*)d_in[19];
    fW2 = (const float*)d_in[20]; fb2 = (const float*)d_in[21];
    g1 = (const float*)d_in[22]; g2 = (const float*)d_in[23]; g3 = (const float*)d_in[24];
    b1 = (const float*)d_in[25]; b2 = (const float*)d_in[26]; b3 = (const float*)d_in[27];
    xt = (const int*)d_in[28]; yt = (const int*)d_in[29];
  }

  // ---- ws layout (172 MB total) ----
  const size_t MM = (size_t)1 << 20;
  _Float16* W16 = (_Float16*)d_ws;
  _Float16* wqkv = W16;            // 3M f16
  _Float16* wcq  = W16 + 3 * MM;   // 1M
  _Float16* wckv = W16 + 4 * MM;   // 2M
  _Float16* wso  = W16 + 6 * MM;   // 1M
  _Float16* wco  = W16 + 7 * MM;   // 1M
  _Float16* wf1  = W16 + 8 * MM;   // 4M
  _Float16* wf2  = W16 + 12 * MM;  // 4M
  _Float16* sc   = W16 + 16 * MM;  // 32M
  _Float16* qh   = W16 + 48 * MM;  // 2M  (kh must follow qh contiguously)
  _Float16* kh   = W16 + 50 * MM;  // 2M
  _Float16* vT   = W16 + 52 * MM;  // 2M
  _Float16* ob   = W16 + 54 * MM;  // 2M
  _Float16* y16  = W16 + 56 * MM;  // 2M
  _Float16* yl16 = W16 + 58 * MM;  // 2M
  _Float16* x16  = W16 + 60 * MM;  // 2M
  _Float16* ffn  = W16 + 62 * MM;  // 8M
  float* y32  = (float*)(W16 + 70 * MM);  // 2M f32
  float* yl32 = y32 + 2 * MM;
  float* x32  = y32 + 4 * MM;
  float* tmp  = y32 + 6 * MM;

  const size_t EE = (size_t)ESZ * ESZ;
  const long SH = (long)SEQ * HD;       // 65536
  const long SS = (long)SEQ * SEQ;      // 1048576

  embed_k<<<dim3(2 * NB * SEQ), dim3(256), 0, stream>>>(xt, yt, emb, cls, y32, y16, x16);

  for (int l = 0; l < NLAYER; l++) {
    // ---- per-layer weight convert+transpose ----
    wtr_k<<<dim3(16, 16), 256, 0, stream>>>(sWq + l * EE, wqkv, 1024, 1024);
    wtr_k<<<dim3(16, 16), 256, 0, stream>>>(sWk + l * EE, wqkv + 1 * MM, 1024, 1024);
    wtr_k<<<dim3(16, 16), 256, 0, stream>>>(sWv + l * EE, wqkv + 2 * MM, 1024, 1024);
    wtr_k<<<dim3(16, 16), 256, 0, stream>>>(cWq + l * EE, wcq, 1024, 1024);
    wtr_k<<<dim3(16, 16), 256, 0, stream>>>(cWk + l * EE, wckv, 1024, 1024);
    wtr_k<<<dim3(16, 16), 256, 0, stream>>>(cWv + l * EE, wckv + 1 * MM, 1024, 1024);
    wtr_k<<<dim3(16, 16), 256, 0, stream>>>(sWo + l * EE, wso, 1024, 1024);
    wtr_k<<<dim3(16, 16), 256, 0, stream>>>(cWo + l * EE, wco, 1024, 1024);
    wtr_k<<<dim3(16, 64), 256, 0, stream>>>(fW1 + l * EE * 4, wf1, 1024, 4096);
    wtr_k<<<dim3(64, 16), 256, 0, stream>>>(fW2 + l * EE * 4, wf2, 4096, 1024);

    // ---- self-attention (over original y) ----
    gemm<128, 2, false>(stream, y16, wqkv, sbq + l * ESZ, sbk + l * ESZ, sbv + l * ESZ,
        qh, vT, 2048, 3072, 1024, 1024, 1024, 0, 1, 0, 0, 1, 0, 0, 1.f, 2);
    gemm<128, 1, false>(stream, qh, kh, nullptr, nullptr, nullptr, sc, nullptr,
        1024, 1024, 64, 64, 64, 1024, 32, SH, SH, 1, SS, 0, 0.03125f, 0);
    softmax_k<<<dim3(NB * NH * SEQ), 256, 0, stream>>>(sc, 1);
    gemm<64, 1, false>(stream, sc, vT, nullptr, nullptr, nullptr, ob, nullptr,
        1024, 64, 1024, 1024, 1024, 1024, 32, SS, SH, 16, SS, 64, 1.f, 0);
    gemm<128, 0, false>(stream, ob, wso, sbo + l * ESZ, nullptr, nullptr, tmp, nullptr,
        2048, 1024, 1024, 1024, 1024, 1024, 1, 0, 0, 1, 0, 0, 1.f, 0);
    lnres_k<<<dim3(2048), 256, 0, stream>>>(y32, tmp, g1 + l * ESZ, b1 + l * ESZ, yl32, yl16);

    // ---- cross-attention ----
    gemm<128, 2, false>(stream, yl16, wcq, cbq + l * ESZ, nullptr, nullptr,
        qh, vT, 2048, 1024, 1024, 1024, 1024, 0, 1, 0, 0, 1, 0, 0, 1.f, 3);
    gemm<128, 2, false>(stream, x16, wckv, cbk + l * ESZ, cbv + l * ESZ, nullptr,
        kh, vT, 2048, 2048, 1024, 1024, 1024, 0, 1, 0, 0, 1, 0, 0, 1.f, 1);
    gemm<128, 1, false>(stream, qh, kh, nullptr, nullptr, nullptr, sc, nullptr,
        1024, 1024, 64, 64, 64, 1024, 32, SH, SH, 1, SS, 0, 0.03125f, 0);
    softmax_k<<<dim3(NB * NH * SEQ), 256, 0, stream>>>(sc, 0);
    gemm<64, 1, false>(stream, sc, vT, nullptr, nullptr, nullptr, ob, nullptr,
        1024, 64, 1024, 1024, 1024, 1024, 32, SS, SH, 16, SS, 64, 1.f, 0);
    gemm<128, 0, false>(stream, ob, wco, cbo + l * ESZ, nullptr, nullptr, tmp, nullptr,
        2048, 1024, 1024, 1024, 1024, 1024, 1, 0, 0, 1, 0, 0, 1.f, 0);
    lnres_k<<<dim3(2048), 256, 0, stream>>>(yl32, tmp, g2 + l * ESZ, b2 + l * ESZ, x32, x16);

    // ---- FFN ----
    gemm<128, 1, true>(stream, x16, wf1, fb1 + l * FFD, nullptr, nullptr, ffn, nullptr,
        2048, 4096, 1024, 1024, 1024, 4096, 1, 0, 0, 1, 0, 0, 1.f, 0);
    gemm<128, 0, false>(stream, ffn, wf2, fb2 + l * ESZ, nullptr, nullptr, tmp, nullptr,
        2048, 1024, 4096, 4096, 4096, 1024, 1, 0, 0, 1, 0, 0, 1.f, 0);
    lnres_k<<<dim3(2048), 256, 0, stream>>>(x32, tmp, g3 + l * ESZ, b3 + l * ESZ,
        (l == NLAYER - 1) ? (float*)d_out : x32, x16);
  }
}

// Round 3
// 1604.031 us; speedup vs baseline: 5.8457x; 1.0681x over previous
//
#include <hip/hip_runtime.h>
#include <cstdint>

#define ESZ 1024
#define NH 16
#define HD 64
#define NLAYER 4
#define FFD 4096
#define NB 2
#define NXTOK 1023
#define SEQ 1024
#define LNEPS 1e-5f

typedef __attribute__((ext_vector_type(8))) _Float16 f16x8;
typedef __attribute__((ext_vector_type(4))) _Float16 f16x4;
typedef __attribute__((ext_vector_type(4))) float f32x4;

__device__ __forceinline__ void gld16(const void* g, void* l) {
  __builtin_amdgcn_global_load_lds(
      (const __attribute__((address_space(1))) unsigned int*)g,
      (__attribute__((address_space(3))) unsigned int*)l, 16, 0, 0);
}

// Bijective XCD-aware block swizzle: hardware slot lin -> work id such that
// each XCD (lin%8) owns a contiguous chunk of the linear work space.
__device__ __forceinline__ uint3 xcd_swz() {
  unsigned gx = gridDim.x, gy = gridDim.y;
  unsigned nwg = gx * gy * gridDim.z;
  unsigned lin = (blockIdx.z * gy + blockIdx.y) * gx + blockIdx.x;
  unsigned q = nwg >> 3, r = nwg & 7;
  unsigned xcd = lin & 7, idx = lin >> 3;
  unsigned wid = (xcd < r ? xcd * (q + 1) : r * (q + 1) + (xcd - r) * q) + idx;
  uint3 o;
  o.x = wid % gx;
  unsigned t = wid / gx;
  o.y = t % gy;
  o.z = t / gy;
  return o;
}

// ---------------------------------------------------------------------------
// NT MFMA GEMM, f16: C = A @ B^T (+bias). A [M][K], B [N][K]. BK=64.
// 2-phase double-buffered global_load_lds staging, XOR-swizzled global source
// (LDS linear), same XOR on ds_read -> 2-way conflicts only (free).
// EPI: 0 = f32 C, 1 = f16 C, 2 = QKV head scatter (seg<vseg -> [seg][b][h][s][d]
// at C0, seg==vseg -> V^T [b][h][d][s] at C1).
// CAUSAL: skip blocks fully above diagonal. PVC: K-limit = m0+BM (causal PV).
// ---------------------------------------------------------------------------
template<int BM, int BN, int EPI, bool RELU, bool CAUSAL, bool PVC>
__global__ __launch_bounds__(256)
void gemm_k(const _Float16* __restrict__ A, const _Float16* __restrict__ Bm,
            const float* __restrict__ bias0, const float* __restrict__ bias1,
            const float* __restrict__ bias2,
            void* __restrict__ C0, void* __restrict__ C1,
            int K, int lda, int ldb, int ldc,
            long sAz, long sBz, int cdiv, long sC1, long sC2,
            float cscale, int vseg)
{
  constexpr int MI = BM / 32, NJ = BN / 32;
  __shared__ _Float16 Ah[2][BM * 64];
  __shared__ _Float16 Bh[2][BN * 64];

  const uint3 bi = xcd_swz();
  const int m0 = bi.x * BM;
  const int n0 = bi.y * BN;
  if (CAUSAL && n0 > m0 + BM - 1) return;
  const int z = bi.z;
  const _Float16* Ab = A + (size_t)z * sAz;
  const _Float16* Bb = Bm + (size_t)z * sBz;
  const size_t coff = (size_t)(z / cdiv) * sC1 + (size_t)(z % cdiv) * sC2;
  const int tid = threadIdx.x;
  const int lane = tid & 63;
  const int w = tid >> 6;
  const int lr = lane & 15;
  const int hi = lane >> 4;
  const int wr = (w >> 1) * (BM / 2);
  const int wc = (w & 1) * (BN / 2);

  const f32x4 vz = {0.f, 0.f, 0.f, 0.f};
  f32x4 acc[MI][NJ];
#pragma unroll
  for (int i = 0; i < MI; i++)
#pragma unroll
    for (int j = 0; j < NJ; j++) acc[i][j] = vz;

  const int nk = PVC ? ((m0 + BM) >> 6) : (K >> 6);

  auto stage = [&](int b, int kt) {
    const int k0 = kt << 6;
#pragma unroll
    for (int c = 0; c < MI; c++) {
      int r = w * (BM / 4) + c * 8 + (lane >> 3);
      int cg = ((lane & 7) ^ (r & 7)) << 3;
      gld16(Ab + (size_t)(m0 + r) * lda + k0 + cg, &Ah[b][(w * (BM / 4) + c * 8) * 64]);
    }
#pragma unroll
    for (int c = 0; c < NJ; c++) {
      int r = w * (BN / 4) + c * 8 + (lane >> 3);
      int cg = ((lane & 7) ^ (r & 7)) << 3;
      gld16(Bb + (size_t)(n0 + r) * ldb + k0 + cg, &Bh[b][(w * (BN / 4) + c * 8) * 64]);
    }
  };

  stage(0, 0);
  int cur = 0;
  for (int kt = 0; kt < nk; ++kt) {
    __syncthreads();  // drains vmcnt for buf[cur] loads, syncs waves
    if (kt + 1 < nk) stage(cur ^ 1, kt + 1);
#pragma unroll
    for (int kk = 0; kk < 2; kk++) {
      f16x8 af[MI], bf[NJ];
#pragma unroll
      for (int i = 0; i < MI; i++) {
        int row = wr + i * 16 + lr;
        int off = ((kk << 6) | (hi << 4)) ^ ((row & 7) << 4);
        af[i] = *(const f16x8*)((const char*)&Ah[cur][0] + row * 128 + off);
      }
#pragma unroll
      for (int j = 0; j < NJ; j++) {
        int row = wc + j * 16 + lr;
        int off = ((kk << 6) | (hi << 4)) ^ ((row & 7) << 4);
        bf[j] = *(const f16x8*)((const char*)&Bh[cur][0] + row * 128 + off);
      }
#pragma unroll
      for (int i = 0; i < MI; i++)
#pragma unroll
        for (int j = 0; j < NJ; j++)
          acc[i][j] = __builtin_amdgcn_mfma_f32_16x16x32_f16(af[i], bf[j], acc[i][j], 0, 0, 0);
    }
    cur ^= 1;
  }

  const int rb = hi * 4;
#pragma unroll
  for (int j = 0; j < NJ; j++) {
    const int n = n0 + wc + j * 16 + lr;
    float bv = 0.f;
    if (EPI == 2) {
      int seg = n >> 10;
      const float* bp = (seg == 0) ? bias0 : ((seg == 1) ? bias1 : bias2);
      bv = bp[n & 1023];
    } else if (bias0) bv = bias0[n];
#pragma unroll
    for (int i = 0; i < MI; i++) {
#pragma unroll
      for (int r = 0; r < 4; r++) {
        int row = m0 + wr + i * 16 + rb + r;
        float out = acc[i][j][r] * cscale + bv;
        if (RELU) out = fmaxf(out, 0.f);
        if (EPI == 0) {
          ((float*)C0)[coff + (size_t)row * ldc + n] = out;
        } else if (EPI == 1) {
          ((_Float16*)C0)[coff + (size_t)row * ldc + n] = (_Float16)out;
        } else {
          int seg = n >> 10, n1 = n & 1023, h = n1 >> 6, d = n1 & 63;
          int b = row >> 10, s = row & 1023;
          if (seg == vseg)
            ((_Float16*)C1)[(((size_t)b * NH + h) * HD + d) * SEQ + s] = (_Float16)out;
          else
            ((_Float16*)C0)[(size_t)seg * ((size_t)NB * NH * SEQ * HD)
                            + (((size_t)b * NH + h) * SEQ + s) * HD + d] = (_Float16)out;
        }
      }
    }
  }
}

// ---------------------------------------------------------------------------
// Weight convert+transpose: src f32 [K][Ns] -> dst f16 [Ns][K]
// ---------------------------------------------------------------------------
__global__ __launch_bounds__(256)
void wtr_k(const float* __restrict__ src, _Float16* __restrict__ dst, int K, int Ns)
{
  __shared__ _Float16 t[64][80];
  const int k0 = blockIdx.x * 64, n0 = blockIdx.y * 64;
  const int tid = threadIdx.x;
  {
    int r = tid >> 4, c4 = (tid & 15) << 2;
#pragma unroll
    for (int rr = 0; rr < 4; rr++) {
      int row = r + rr * 16;
      float4 v = *(const float4*)(src + (size_t)(k0 + row) * Ns + n0 + c4);
      t[c4 + 0][row] = (_Float16)v.x; t[c4 + 1][row] = (_Float16)v.y;
      t[c4 + 2][row] = (_Float16)v.z; t[c4 + 3][row] = (_Float16)v.w;
    }
  }
  __syncthreads();
  {
    int nr = tid >> 3, c8 = (tid & 7) << 3;
#pragma unroll
    for (int rr = 0; rr < 2; rr++) {
      int n = nr + rr * 32;
      f16x8 v = *(const f16x8*)&t[n][c8];
      *(f16x8*)(dst + (size_t)(n0 + n) * K + k0 + c8) = v;
    }
  }
}

// ---------------------------------------------------------------------------
// Embedding + PE (quirk: pe row = batch index).
// ---------------------------------------------------------------------------
__global__ __launch_bounds__(256)
void embed_k(const int* __restrict__ xt, const int* __restrict__ yt,
             const float* __restrict__ emb, const float* __restrict__ cls,
             float* __restrict__ y32, _Float16* __restrict__ y16,
             _Float16* __restrict__ x16)
{
  int row = blockIdx.x;
  bool isx = row < NB * SEQ;
  int rr = isx ? row : row - NB * SEQ;
  int b = rr >> 10, tpos = rr & (SEQ - 1);
  int col0 = threadIdx.x * 4;
  float v[4];
  if (isx && tpos == SEQ - 1) {
#pragma unroll
    for (int j = 0; j < 4; j++) v[j] = cls[col0 + j];
  } else {
    int tok = isx ? xt[b * NXTOK + tpos] : yt[b * SEQ + tpos];
    const float* erow = emb + (size_t)tok * ESZ;
#pragma unroll
    for (int j = 0; j < 4; j++) {
      int e = col0 + j;
      float div = expf((float)(e & ~1) * (-9.210340371976184f / 1024.f));
      float ang = (float)b * div;
      float pe = (e & 1) ? cosf(ang) : sinf(ang);
      v[j] = erow[e] * 32.f + pe;
    }
  }
  size_t off = (size_t)rr * ESZ + col0;
  if (isx) {
#pragma unroll
    for (int j = 0; j < 4; j++) x16[off + j] = (_Float16)v[j];
  } else {
#pragma unroll
    for (int j = 0; j < 4; j++) { y32[off + j] = v[j]; y16[off + j] = (_Float16)v[j]; }
  }
}

// ---------------------------------------------------------------------------
// In-place f16 row softmax (scores pre-scaled in GEMM epilogue).
// causal: reads only k<=q, writes zeros beyond (PV reads them as zeros).
// ---------------------------------------------------------------------------
__global__ __launch_bounds__(256)
void softmax_k(_Float16* __restrict__ sc, int causal)
{
  int rowg = blockIdx.x;
  int q = rowg & (SEQ - 1);
  int limit = causal ? (q + 1) : SEQ;
  _Float16* p = sc + (size_t)rowg * SEQ;
  int tid = threadIdx.x;
  float x[4] = {-1e30f, -1e30f, -1e30f, -1e30f};
  if (tid * 4 < limit) {
    f16x4 v = *(const f16x4*)(p + tid * 4);
#pragma unroll
    for (int j = 0; j < 4; j++) x[j] = (float)v[j];
  }
  float mx = -1e30f;
#pragma unroll
  for (int j = 0; j < 4; j++) if (tid * 4 + j < limit) mx = fmaxf(mx, x[j]);
  for (int o = 32; o > 0; o >>= 1) mx = fmaxf(mx, __shfl_xor(mx, o, 64));
  __shared__ float r1[4], r2[4];
  if ((tid & 63) == 0) r1[tid >> 6] = mx;
  __syncthreads();
  mx = fmaxf(fmaxf(r1[0], r1[1]), fmaxf(r1[2], r1[3]));
  float e[4], sum = 0.f;
#pragma unroll
  for (int j = 0; j < 4; j++) {
    e[j] = (tid * 4 + j < limit) ? expf(x[j] - mx) : 0.f;
    sum += e[j];
  }
  for (int o = 32; o > 0; o >>= 1) sum += __shfl_xor(sum, o, 64);
  if ((tid & 63) == 0) r2[tid >> 6] = sum;
  __syncthreads();
  sum = r2[0] + r2[1] + r2[2] + r2[3];
  float inv = 1.f / sum;
  f16x4 ov;
#pragma unroll
  for (int j = 0; j < 4; j++) ov[j] = (_Float16)(e[j] * inv);
  *(f16x4*)(p + tid * 4) = ov;
}

// ---------------------------------------------------------------------------
// out = LN(a + r)*g + b; writes f32 (residual) and f16 (GEMM input)
// ---------------------------------------------------------------------------
__global__ __launch_bounds__(256)
void lnres_k(const float* __restrict__ a, const float* __restrict__ r,
             const float* __restrict__ g, const float* __restrict__ b,
             float* __restrict__ o32, _Float16* __restrict__ o16)
{
  int row = blockIdx.x;
  size_t off = (size_t)row * ESZ;
  int tid = threadIdx.x;
  float4 va = *(const float4*)(a + off + tid * 4);
  float4 vr = *(const float4*)(r + off + tid * 4);
  float x[4] = {va.x + vr.x, va.y + vr.y, va.z + vr.z, va.w + vr.w};
  float s = x[0] + x[1] + x[2] + x[3];
  float s2 = x[0] * x[0] + x[1] * x[1] + x[2] * x[2] + x[3] * x[3];
  for (int o = 32; o > 0; o >>= 1) {
    s += __shfl_xor(s, o, 64);
    s2 += __shfl_xor(s2, o, 64);
  }
  __shared__ float rs[4], rs2[4];
  if ((tid & 63) == 0) { rs[tid >> 6] = s; rs2[tid >> 6] = s2; }
  __syncthreads();
  s = rs[0] + rs[1] + rs[2] + rs[3];
  s2 = rs2[0] + rs2[1] + rs2[2] + rs2[3];
  float mean = s * (1.f / ESZ);
  float var = s2 * (1.f / ESZ) - mean * mean;
  float inv = 1.f / sqrtf(var + LNEPS);
  float4 vo;
#pragma unroll
  for (int j = 0; j < 4; j++) {
    int c = tid * 4 + j;
    float o = (x[j] - mean) * inv * g[c] + b[c];
    ((float*)&vo)[j] = o;
    o16[off + c] = (_Float16)o;
  }
  *(float4*)(o32 + off + tid * 4) = vo;
}

// ---------------------------------------------------------------------------

template<int BM, int BN, int EPI, bool RELU, bool CAUSAL, bool PVC>
static void gemm(hipStream_t st, const _Float16* A, const _Float16* B,
                 const float* b0, const float* b1, const float* b2,
                 void* C0, void* C1, int M, int N, int K,
                 int lda, int ldb, int ldc,
                 int Z, long sAz, long sBz, int cdiv, long sC1, long sC2,
                 float cscale, int vseg)
{
  dim3 g(M / BM, N / BN, Z);
  gemm_k<BM, BN, EPI, RELU, CAUSAL, PVC><<<g, dim3(256), 0, st>>>(
      A, B, b0, b1, b2, C0, C1, K, lda, ldb, ldc, sAz, sBz, cdiv, sC1, sC2, cscale, vseg);
}

extern "C" void kernel_launch(void* const* d_in, const int* in_sizes, int n_in,
                              void* d_out, int out_size, void* d_ws, size_t ws_size,
                              hipStream_t stream) {
  (void)n_in; (void)out_size; (void)ws_size;
  const float *emb, *cls, *sWq, *sbq, *sWk, *sbk, *sWv, *sbv, *sWo, *sbo;
  const float *cWq, *cbq, *cWk, *cbk, *cWv, *cbv, *cWo, *cbo;
  const float *fW1, *fb1, *fW2, *fb2, *g1, *g2, *g3, *b1, *b2, *b3;
  const int *xt, *yt;
  if (in_sizes[0] == NB * NXTOK) {
    xt = (const int*)d_in[0]; yt = (const int*)d_in[1];
    emb = (const float*)d_in[2]; cls = (const float*)d_in[3];
    sWq = (const float*)d_in[4]; sbq = (const float*)d_in[5];
    sWk = (const float*)d_in[6]; sbk = (const float*)d_in[7];
    sWv = (const float*)d_in[8]; sbv = (const float*)d_in[9];
    sWo = (const float*)d_in[10]; sbo = (const float*)d_in[11];
    cWq = (const float*)d_in[12]; cbq = (const float*)d_in[13];
    cWk = (const float*)d_in[14]; cbk = (const float*)d_in[15];
    cWv = (const float*)d_in[16]; cbv = (const float*)d_in[17];
    cWo = (const float*)d_in[18]; cbo = (const float*)d_in[19];
    g1 = (const float*)d_in[20]; b1 = (const float*)d_in[21];
    g2 = (const float*)d_in[22]; b2 = (const float*)d_in[23];
    g3 = (const float*)d_in[24]; b3 = (const float*)d_in[25];
    fW1 = (const float*)d_in[26]; fb1 = (const float*)d_in[27];
    fW2 = (const float*)d_in[28]; fb2 = (const float*)d_in[29];
  } else {
    emb = (const float*)d_in[0]; cls = (const float*)d_in[1];
    sWq = (const float*)d_in[2]; sbq = (const float*)d_in[3];
    sWk = (const float*)d_in[4]; sbk = (const float*)d_in[5];
    sWv = (const float*)d_in[6]; sbv = (const float*)d_in[7];
    sWo = (const float*)d_in[8]; sbo = (const float*)d_in[9];
    cWq = (const float*)d_in[10]; cbq = (const float*)d_in[11];
    cWk = (const float*)d_in[12]; cbk = (const float*)d_in[13];
    cWv = (const float*)d_in[14]; cbv = (const float*)d_in[15];
    cWo = (const float*)d_in[16]; cbo = (const float*)d_in[17];
    fW1 = (const float*)d_in[18]; fb1 = (const float*)d_in[19];
    fW2 = (const float*)d_in[20]; fb2 = (const float*)d_in[21];
    g1 = (const float*)d_in[22]; g2 = (const float*)d_in[23]; g3 = (const float*)d_in[24];
    b1 = (const float*)d_in[25]; b2 = (const float*)d_in[26]; b3 = (const float*)d_in[27];
    xt = (const int*)d_in[28]; yt = (const int*)d_in[29];
  }

  const size_t MM = (size_t)1 << 20;
  _Float16* W16 = (_Float16*)d_ws;
  _Float16* wqkv = W16;            // 3M f16
  _Float16* wcq  = W16 + 3 * MM;   // 1M
  _Float16* wckv = W16 + 4 * MM;   // 2M
  _Float16* wso  = W16 + 6 * MM;   // 1M
  _Float16* wco  = W16 + 7 * MM;   // 1M
  _Float16* wf1  = W16 + 8 * MM;   // 4M
  _Float16* wf2  = W16 + 12 * MM;  // 4M
  _Float16* sc   = W16 + 16 * MM;  // 32M
  _Float16* qh   = W16 + 48 * MM;  // 2M  (kh must follow qh contiguously)
  _Float16* kh   = W16 + 50 * MM;  // 2M
  _Float16* vT   = W16 + 52 * MM;  // 2M
  _Float16* ob   = W16 + 54 * MM;  // 2M
  _Float16* y16  = W16 + 56 * MM;  // 2M
  _Float16* yl16 = W16 + 58 * MM;  // 2M
  _Float16* x16  = W16 + 60 * MM;  // 2M
  _Float16* ffn  = W16 + 62 * MM;  // 8M
  float* y32  = (float*)(W16 + 70 * MM);  // 2M f32
  float* yl32 = y32 + 2 * MM;
  float* x32  = y32 + 4 * MM;
  float* tmp  = y32 + 6 * MM;

  const size_t EE = (size_t)ESZ * ESZ;
  const long SH = (long)SEQ * HD;       // 65536
  const long SS = (long)SEQ * SEQ;      // 1048576

  embed_k<<<dim3(2 * NB * SEQ), dim3(256), 0, stream>>>(xt, yt, emb, cls, y32, y16, x16);

  for (int l = 0; l < NLAYER; l++) {
    wtr_k<<<dim3(16, 16), 256, 0, stream>>>(sWq + l * EE, wqkv, 1024, 1024);
    wtr_k<<<dim3(16, 16), 256, 0, stream>>>(sWk + l * EE, wqkv + 1 * MM, 1024, 1024);
    wtr_k<<<dim3(16, 16), 256, 0, stream>>>(sWv + l * EE, wqkv + 2 * MM, 1024, 1024);
    wtr_k<<<dim3(16, 16), 256, 0, stream>>>(cWq + l * EE, wcq, 1024, 1024);
    wtr_k<<<dim3(16, 16), 256, 0, stream>>>(cWk + l * EE, wckv, 1024, 1024);
    wtr_k<<<dim3(16, 16), 256, 0, stream>>>(cWv + l * EE, wckv + 1 * MM, 1024, 1024);
    wtr_k<<<dim3(16, 16), 256, 0, stream>>>(sWo + l * EE, wso, 1024, 1024);
    wtr_k<<<dim3(16, 16), 256, 0, stream>>>(cWo + l * EE, wco, 1024, 1024);
    wtr_k<<<dim3(16, 64), 256, 0, stream>>>(fW1 + l * EE * 4, wf1, 1024, 4096);
    wtr_k<<<dim3(64, 16), 256, 0, stream>>>(fW2 + l * EE * 4, wf2, 4096, 1024);

    // ---- self-attention (over original y) ----
    gemm<128, 128, 2, false, false, false>(stream, y16, wqkv,
        sbq + l * ESZ, sbk + l * ESZ, sbv + l * ESZ,
        qh, vT, 2048, 3072, 1024, 1024, 1024, 0, 1, 0, 0, 1, 0, 0, 1.f, 2);
    gemm<128, 128, 1, false, true, false>(stream, qh, kh, nullptr, nullptr, nullptr,
        sc, nullptr, 1024, 1024, 64, 64, 64, 1024, 32, SH, SH, 1, SS, 0, 0.03125f, 0);
    softmax_k<<<dim3(NB * NH * SEQ), 256, 0, stream>>>(sc, 1);
    gemm<128, 64, 1, false, false, true>(stream, sc, vT, nullptr, nullptr, nullptr,
        ob, nullptr, 1024, 64, 1024, 1024, 1024, 1024, 32, SS, SH, 16, SS, 64, 1.f, 0);
    gemm<64, 128, 0, false, false, false>(stream, ob, wso, sbo + l * ESZ, nullptr, nullptr,
        tmp, nullptr, 2048, 1024, 1024, 1024, 1024, 1024, 1, 0, 0, 1, 0, 0, 1.f, 0);
    lnres_k<<<dim3(2048), 256, 0, stream>>>(y32, tmp, g1 + l * ESZ, b1 + l * ESZ, yl32, yl16);

    // ---- cross-attention ----
    gemm<64, 128, 2, false, false, false>(stream, yl16, wcq, cbq + l * ESZ, nullptr, nullptr,
        qh, vT, 2048, 1024, 1024, 1024, 1024, 0, 1, 0, 0, 1, 0, 0, 1.f, 3);
    gemm<128, 128, 2, false, false, false>(stream, x16, wckv, cbk + l * ESZ, cbv + l * ESZ,
        nullptr, kh, vT, 2048, 2048, 1024, 1024, 1024, 0, 1, 0, 0, 1, 0, 0, 1.f, 1);
    gemm<128, 128, 1, false, false, false>(stream, qh, kh, nullptr, nullptr, nullptr,
        sc, nullptr, 1024, 1024, 64, 64, 64, 1024, 32, SH, SH, 1, SS, 0, 0.03125f, 0);
    softmax_k<<<dim3(NB * NH * SEQ), 256, 0, stream>>>(sc, 0);
    gemm<128, 64, 1, false, false, false>(stream, sc, vT, nullptr, nullptr, nullptr,
        ob, nullptr, 1024, 64, 1024, 1024, 1024, 1024, 32, SS, SH, 16, SS, 64, 1.f, 0);
    gemm<64, 128, 0, false, false, false>(stream, ob, wco, cbo + l * ESZ, nullptr, nullptr,
        tmp, nullptr, 2048, 1024, 1024, 1024, 1024, 1024, 1, 0, 0, 1, 0, 0, 1.f, 0);
    lnres_k<<<dim3(2048), 256, 0, stream>>>(yl32, tmp, g2 + l * ESZ, b2 + l * ESZ, x32, x16);

    // ---- FFN ----
    gemm<128, 128, 1, true, false, false>(stream, x16, wf1, fb1 + l * FFD, nullptr, nullptr,
        ffn, nullptr, 2048, 4096, 1024, 1024, 1024, 4096, 1, 0, 0, 1, 0, 0, 1.f, 0);
    gemm<64, 128, 0, false, false, false>(stream, ffn, wf2, fb2 + l * ESZ, nullptr, nullptr,
        tmp, nullptr, 2048, 1024, 4096, 4096, 4096, 1024, 1, 0, 0, 1, 0, 0, 1.f, 0);
    lnres_k<<<dim3(2048), 256, 0, stream>>>(x32, tmp, g3 + l * ESZ, b3 + l * ESZ,
        (l == NLAYER - 1) ? (float*)d_out : x32, x16);
  }
}

// Round 4
// 1286.127 us; speedup vs baseline: 7.2907x; 1.2472x over previous
//
#include <hip/hip_runtime.h>
#include <cstdint>

#define ESZ 1024
#define NH 16
#define HD 64
#define NLAYER 4
#define FFD 4096
#define NB 2
#define NXTOK 1023
#define SEQ 1024
#define LNEPS 1e-5f

typedef __attribute__((ext_vector_type(8))) _Float16 f16x8;
typedef __attribute__((ext_vector_type(4))) _Float16 f16x4;
typedef __attribute__((ext_vector_type(4))) float f32x4;

__device__ __forceinline__ void gld16(const void* g, void* l) {
  __builtin_amdgcn_global_load_lds(
      (const __attribute__((address_space(1))) unsigned int*)g,
      (__attribute__((address_space(3))) unsigned int*)l, 16, 0, 0);
}

// Bijective XCD-aware block swizzle (each XCD gets a contiguous work chunk).
__device__ __forceinline__ uint3 xcd_swz() {
  unsigned gx = gridDim.x, gy = gridDim.y;
  unsigned nwg = gx * gy * gridDim.z;
  unsigned lin = (blockIdx.z * gy + blockIdx.y) * gx + blockIdx.x;
  unsigned q = nwg >> 3, r = nwg & 7;
  unsigned xcd = lin & 7, idx = lin >> 3;
  unsigned wid = (xcd < r ? xcd * (q + 1) : r * (q + 1) + (xcd - r) * q) + idx;
  uint3 o;
  o.x = wid % gx;
  unsigned t = wid / gx;
  o.y = t % gy;
  o.z = t / gy;
  return o;
}

// ---------------------------------------------------------------------------
// NT MFMA GEMM, f16: C = A @ B^T (+bias). A [M][K], B [N][K]. BK=64.
// 2-phase double-buffered global_load_lds staging, XOR-swizzled global source
// (LDS linear), same XOR on ds_read -> conflict-free.
// EPI: 0 = f32 C, 1 = f16 C, 2 = QKV head scatter (seg<vseg -> head-major
// [b][h][s][d] at C0, seg==vseg -> V^T [b][h][d][s] at C1).
// ---------------------------------------------------------------------------
template<int BM, int BN, int EPI, bool RELU>
__global__ __launch_bounds__(256)
void gemm_k(const _Float16* __restrict__ A, const _Float16* __restrict__ Bm,
            const float* __restrict__ bias0, const float* __restrict__ bias1,
            const float* __restrict__ bias2,
            void* __restrict__ C0, void* __restrict__ C1,
            int K, int lda, int ldb, int ldc,
            long sAz, long sBz, int cdiv, long sC1, long sC2, int vseg)
{
  constexpr int MI = BM / 32, NJ = BN / 32;
  __shared__ _Float16 Ah[2][BM * 64];
  __shared__ _Float16 Bh[2][BN * 64];

  const uint3 bi = xcd_swz();
  const int m0 = bi.x * BM;
  const int n0 = bi.y * BN;
  const int z = bi.z;
  const _Float16* Ab = A + (size_t)z * sAz;
  const _Float16* Bb = Bm + (size_t)z * sBz;
  const size_t coff = (size_t)(z / cdiv) * sC1 + (size_t)(z % cdiv) * sC2;
  const int tid = threadIdx.x;
  const int lane = tid & 63;
  const int w = tid >> 6;
  const int lr = lane & 15;
  const int hi = lane >> 4;
  const int wr = (w >> 1) * (BM / 2);
  const int wc = (w & 1) * (BN / 2);

  const f32x4 vz = {0.f, 0.f, 0.f, 0.f};
  f32x4 acc[MI][NJ];
#pragma unroll
  for (int i = 0; i < MI; i++)
#pragma unroll
    for (int j = 0; j < NJ; j++) acc[i][j] = vz;

  const int nk = K >> 6;

  auto stage = [&](int b, int kt) {
    const int k0 = kt << 6;
#pragma unroll
    for (int c = 0; c < MI; c++) {
      int r = w * (BM / 4) + c * 8 + (lane >> 3);
      int cg = ((lane & 7) ^ (r & 7)) << 3;
      gld16(Ab + (size_t)(m0 + r) * lda + k0 + cg, &Ah[b][(w * (BM / 4) + c * 8) * 64]);
    }
#pragma unroll
    for (int c = 0; c < NJ; c++) {
      int r = w * (BN / 4) + c * 8 + (lane >> 3);
      int cg = ((lane & 7) ^ (r & 7)) << 3;
      gld16(Bb + (size_t)(n0 + r) * ldb + k0 + cg, &Bh[b][(w * (BN / 4) + c * 8) * 64]);
    }
  };

  stage(0, 0);
  int cur = 0;
  for (int kt = 0; kt < nk; ++kt) {
    __syncthreads();
    if (kt + 1 < nk) stage(cur ^ 1, kt + 1);
#pragma unroll
    for (int kk = 0; kk < 2; kk++) {
      f16x8 af[MI], bf[NJ];
#pragma unroll
      for (int i = 0; i < MI; i++) {
        int row = wr + i * 16 + lr;
        int off = ((kk << 6) | (hi << 4)) ^ ((row & 7) << 4);
        af[i] = *(const f16x8*)((const char*)&Ah[cur][0] + row * 128 + off);
      }
#pragma unroll
      for (int j = 0; j < NJ; j++) {
        int row = wc + j * 16 + lr;
        int off = ((kk << 6) | (hi << 4)) ^ ((row & 7) << 4);
        bf[j] = *(const f16x8*)((const char*)&Bh[cur][0] + row * 128 + off);
      }
#pragma unroll
      for (int i = 0; i < MI; i++)
#pragma unroll
        for (int j = 0; j < NJ; j++)
          acc[i][j] = __builtin_amdgcn_mfma_f32_16x16x32_f16(af[i], bf[j], acc[i][j], 0, 0, 0);
    }
    cur ^= 1;
  }

  const int rb = hi * 4;
#pragma unroll
  for (int j = 0; j < NJ; j++) {
    const int n = n0 + wc + j * 16 + lr;
    float bv = 0.f;
    if (EPI == 2) {
      int seg = n >> 10;
      const float* bp = (seg == 0) ? bias0 : ((seg == 1) ? bias1 : bias2);
      bv = bp[n & 1023];
    } else if (bias0) bv = bias0[n];
#pragma unroll
    for (int i = 0; i < MI; i++) {
#pragma unroll
      for (int r = 0; r < 4; r++) {
        int row = m0 + wr + i * 16 + rb + r;
        float out = acc[i][j][r] + bv;
        if (RELU) out = fmaxf(out, 0.f);
        if (EPI == 0) {
          ((float*)C0)[coff + (size_t)row * ldc + n] = out;
        } else if (EPI == 1) {
          ((_Float16*)C0)[coff + (size_t)row * ldc + n] = (_Float16)out;
        } else {
          int seg = n >> 10, n1 = n & 1023, h = n1 >> 6, d = n1 & 63;
          int b = row >> 10, s = row & 1023;
          if (seg == vseg)
            ((_Float16*)C1)[(((size_t)b * NH + h) * HD + d) * SEQ + s] = (_Float16)out;
          else
            ((_Float16*)C0)[(size_t)seg * ((size_t)NB * NH * SEQ * HD)
                            + (((size_t)b * NH + h) * SEQ + s) * HD + d] = (_Float16)out;
        }
      }
    }
  }
}

// ---------------------------------------------------------------------------
// Flash attention: one block = 128 q rows of one (b,h); 4 waves x 32 q rows.
// Swapped QK^T (S^T = K @ Q^T) so softmax reduce is 2 shfl_xor; S^T C-layout
// (k=hi*4+reg, q=lane&15) IS the B-fragment of mfma_16x16x16_f16, so PV
// (O^T = V^T @ P^T) needs no P relayout. K/V double-buffered via
// global_load_lds with XOR swizzle. Scores scaled 1/32 (reference quirk:
// mask-before-scale == skip masked).
// ---------------------------------------------------------------------------
template<bool CAUSAL>
__global__ __launch_bounds__(256)
void flash_k(const _Float16* __restrict__ qh, const _Float16* __restrict__ kh,
             const _Float16* __restrict__ vTp, _Float16* __restrict__ ob)
{
  __shared__ _Float16 Kl[2][64 * 64];
  __shared__ _Float16 Vl[2][64 * 64];
  const int qb = blockIdx.x;
  const int bh = blockIdx.y;
  const int b = bh >> 4, h = bh & 15;
  const int q0 = qb * 128;
  const int tid = threadIdx.x;
  const int w = tid >> 6, lane = tid & 63;
  const int lr = lane & 15, hi = lane >> 4;
  const int qw = q0 + w * 32;

  const _Float16* Qp = qh + (size_t)bh * SEQ * HD;
  const _Float16* Kp = kh + (size_t)bh * SEQ * HD;
  const _Float16* Vp = vTp + (size_t)bh * HD * SEQ;

  f16x8 qf[2][2];
#pragma unroll
  for (int jq = 0; jq < 2; jq++)
#pragma unroll
    for (int ds = 0; ds < 2; ds++)
      qf[jq][ds] = *(const f16x8*)(Qp + (size_t)(qw + jq * 16 + lr) * HD + ds * 32 + hi * 8);

  float m[2] = {-1e30f, -1e30f}, l[2] = {0.f, 0.f};
  const f32x4 vz = {0.f, 0.f, 0.f, 0.f};
  f32x4 o[4][2];
#pragma unroll
  for (int dt = 0; dt < 4; dt++)
#pragma unroll
    for (int jq = 0; jq < 2; jq++) o[dt][jq] = vz;

  const int nst = CAUSAL ? ((q0 >> 6) + 2) : (SEQ / 64);

  auto stage = [&](int buf, int kt) {
    const int k0 = kt << 6;
#pragma unroll
    for (int c = 0; c < 2; c++) {
      int r = w * 16 + c * 8 + (lane >> 3);
      int cg = ((lane & 7) ^ (r & 7)) << 3;
      gld16(Kp + (size_t)(k0 + r) * HD + cg, &Kl[buf][(w * 16 + c * 8) * 64]);
      gld16(Vp + (size_t)r * SEQ + k0 + cg, &Vl[buf][(w * 16 + c * 8) * 64]);
    }
  };

  stage(0, 0);
  int cur = 0;
  for (int kt = 0; kt < nst; ++kt) {
    __syncthreads();
    if (kt + 1 < nst) stage(cur ^ 1, kt + 1);
    const int k0 = kt << 6;
    if (!CAUSAL || k0 <= qw + 31) {
      // ---- S^T = K @ Q^T ----
      f32x4 s[4][2];
#pragma unroll
      for (int ik = 0; ik < 4; ik++)
#pragma unroll
        for (int jq = 0; jq < 2; jq++) s[ik][jq] = vz;
#pragma unroll
      for (int ds = 0; ds < 2; ds++) {
        f16x8 kf[4];
#pragma unroll
        for (int ik = 0; ik < 4; ik++) {
          int row = ik * 16 + lr;
          int off = (ds * 64 + hi * 16) ^ ((row & 7) << 4);
          kf[ik] = *(const f16x8*)((const char*)&Kl[cur][0] + row * 128 + off);
        }
#pragma unroll
        for (int ik = 0; ik < 4; ik++)
#pragma unroll
          for (int jq = 0; jq < 2; jq++)
            s[ik][jq] = __builtin_amdgcn_mfma_f32_16x16x32_f16(kf[ik], qf[jq][ds], s[ik][jq], 0, 0, 0);
      }
      // ---- scale + causal mask + row max ----
      float mx[2] = {-1e30f, -1e30f};
#pragma unroll
      for (int ik = 0; ik < 4; ik++)
#pragma unroll
        for (int jq = 0; jq < 2; jq++)
#pragma unroll
          for (int r = 0; r < 4; r++) {
            float v = s[ik][jq][r] * 0.03125f;
            if (CAUSAL) {
              int kk = k0 + ik * 16 + hi * 4 + r;
              int qq = qw + jq * 16 + lr;
              if (kk > qq) v = -1e30f;
            }
            s[ik][jq][r] = v;
            mx[jq] = fmaxf(mx[jq], v);
          }
      float sc[2], cs[2] = {0.f, 0.f};
      f16x4 pb[4][2];
#pragma unroll
      for (int jq = 0; jq < 2; jq++) {
        mx[jq] = fmaxf(mx[jq], __shfl_xor(mx[jq], 16, 64));
        mx[jq] = fmaxf(mx[jq], __shfl_xor(mx[jq], 32, 64));
        float mn = fmaxf(m[jq], mx[jq]);
        sc[jq] = __expf(m[jq] - mn);
        m[jq] = mn;
      }
#pragma unroll
      for (int ik = 0; ik < 4; ik++)
#pragma unroll
        for (int jq = 0; jq < 2; jq++)
#pragma unroll
          for (int r = 0; r < 4; r++) {
            float p = __expf(s[ik][jq][r] - m[jq]);
            cs[jq] += p;
            pb[ik][jq][r] = (_Float16)p;
          }
#pragma unroll
      for (int jq = 0; jq < 2; jq++) {
        float t = cs[jq];
        t += __shfl_xor(t, 16, 64);
        t += __shfl_xor(t, 32, 64);
        l[jq] = l[jq] * sc[jq] + t;
      }
#pragma unroll
      for (int dt = 0; dt < 4; dt++)
#pragma unroll
        for (int jq = 0; jq < 2; jq++)
#pragma unroll
          for (int r = 0; r < 4; r++) o[dt][jq][r] *= sc[jq];
      // ---- O^T += V^T @ P^T (16x16x16, P already in B-frag layout) ----
#pragma unroll
      for (int ks = 0; ks < 4; ks++) {
        f16x4 va[4];
#pragma unroll
        for (int dt = 0; dt < 4; dt++) {
          int row = dt * 16 + lr;
          int off = (ks * 32 + hi * 8) ^ ((row & 7) << 4);
          va[dt] = *(const f16x4*)((const char*)&Vl[cur][0] + row * 128 + off);
        }
#pragma unroll
        for (int dt = 0; dt < 4; dt++)
#pragma unroll
          for (int jq = 0; jq < 2; jq++)
            o[dt][jq] = __builtin_amdgcn_mfma_f32_16x16x16f16(va[dt], pb[ks][jq], o[dt][jq], 0, 0, 0);
      }
    }
    cur ^= 1;
  }

  float inv[2] = {1.f / l[0], 1.f / l[1]};
#pragma unroll
  for (int jq = 0; jq < 2; jq++) {
    int q = qw + jq * 16 + lr;
    size_t rowoff = (size_t)(b * SEQ + q) * ESZ + h * 64;
#pragma unroll
    for (int dt = 0; dt < 4; dt++) {
      f16x4 ov;
#pragma unroll
      for (int r = 0; r < 4; r++) ov[r] = (_Float16)(o[dt][jq][r] * inv[jq]);
      *(f16x4*)(ob + rowoff + dt * 16 + hi * 4) = ov;
    }
  }
}

// ---------------------------------------------------------------------------
// Weight convert+transpose body: src f32 [K][Ns] tile -> dst f16 [Ns][K]
// ---------------------------------------------------------------------------
__device__ __forceinline__ void wtr_body(const float* src, _Float16* dst,
                                         int K, int Ns, int k0, int n0,
                                         _Float16 (*t)[80], int tid)
{
  {
    int r = tid >> 4, c4 = (tid & 15) << 2;
#pragma unroll
    for (int rr = 0; rr < 4; rr++) {
      int row = r + rr * 16;
      float4 v = *(const float4*)(src + (size_t)(k0 + row) * Ns + n0 + c4);
      t[c4 + 0][row] = (_Float16)v.x; t[c4 + 1][row] = (_Float16)v.y;
      t[c4 + 2][row] = (_Float16)v.z; t[c4 + 3][row] = (_Float16)v.w;
    }
  }
  __syncthreads();
  {
    int nr = tid >> 3, c8 = (tid & 7) << 3;
#pragma unroll
    for (int rr = 0; rr < 2; rr++) {
      int n = nr + rr * 32;
      f16x8 v = *(const f16x8*)&t[n][c8];
      *(f16x8*)(dst + (size_t)(n0 + n) * K + k0 + c8) = v;
    }
  }
}

struct W8 { const float* p[8]; };

// all 8 square weights x 4 layers in one launch; z = widx*4 + layer
__global__ __launch_bounds__(256)
void wtr8_k(W8 w8, _Float16* dstbase)
{
  __shared__ _Float16 t[64][80];
  int z = blockIdx.z;
  int widx = z >> 2, layer = z & 3;
  const float* src = w8.p[widx] + (size_t)layer * (ESZ * ESZ);
  _Float16* dst = dstbase + (size_t)layer * 16777216 + (size_t)widx * 1048576;
  wtr_body(src, dst, 1024, 1024, blockIdx.x * 64, blockIdx.y * 64, t, threadIdx.x);
}

// FFN weights, all layers; z = layer
__global__ __launch_bounds__(256)
void wtrL_k(const float* src, _Float16* dst, int K, int Ns)
{
  __shared__ _Float16 t[64][80];
  int layer = blockIdx.z;
  src += (size_t)layer * K * Ns;
  dst += (size_t)layer * 16777216;
  wtr_body(src, dst, K, Ns, blockIdx.x * 64, blockIdx.y * 64, t, threadIdx.x);
}

// ---------------------------------------------------------------------------
// Embedding + PE (quirk: pe row = batch index).
// ---------------------------------------------------------------------------
__global__ __launch_bounds__(256)
void embed_k(const int* __restrict__ xt, const int* __restrict__ yt,
             const float* __restrict__ emb, const float* __restrict__ cls,
             float* __restrict__ y32, _Float16* __restrict__ y16,
             _Float16* __restrict__ x16)
{
  int row = blockIdx.x;
  bool isx = row < NB * SEQ;
  int rr = isx ? row : row - NB * SEQ;
  int b = rr >> 10, tpos = rr & (SEQ - 1);
  int col0 = threadIdx.x * 4;
  float v[4];
  if (isx && tpos == SEQ - 1) {
#pragma unroll
    for (int j = 0; j < 4; j++) v[j] = cls[col0 + j];
  } else {
    int tok = isx ? xt[b * NXTOK + tpos] : yt[b * SEQ + tpos];
    const float* erow = emb + (size_t)tok * ESZ;
#pragma unroll
    for (int j = 0; j < 4; j++) {
      int e = col0 + j;
      float div = expf((float)(e & ~1) * (-9.210340371976184f / 1024.f));
      float ang = (float)b * div;
      float pe = (e & 1) ? cosf(ang) : sinf(ang);
      v[j] = erow[e] * 32.f + pe;
    }
  }
  size_t off = (size_t)rr * ESZ + col0;
  if (isx) {
#pragma unroll
    for (int j = 0; j < 4; j++) x16[off + j] = (_Float16)v[j];
  } else {
#pragma unroll
    for (int j = 0; j < 4; j++) { y32[off + j] = v[j]; y16[off + j] = (_Float16)v[j]; }
  }
}

// ---------------------------------------------------------------------------
// out = LN(a + r)*g + b; writes f32 (residual) and f16 (GEMM input)
// ---------------------------------------------------------------------------
__global__ __launch_bounds__(256)
void lnres_k(const float* __restrict__ a, const float* __restrict__ r,
             const float* __restrict__ g, const float* __restrict__ b,
             float* __restrict__ o32, _Float16* __restrict__ o16)
{
  int row = blockIdx.x;
  size_t off = (size_t)row * ESZ;
  int tid = threadIdx.x;
  float4 va = *(const float4*)(a + off + tid * 4);
  float4 vr = *(const float4*)(r + off + tid * 4);
  float x[4] = {va.x + vr.x, va.y + vr.y, va.z + vr.z, va.w + vr.w};
  float s = x[0] + x[1] + x[2] + x[3];
  float s2 = x[0] * x[0] + x[1] * x[1] + x[2] * x[2] + x[3] * x[3];
  for (int o = 32; o > 0; o >>= 1) {
    s += __shfl_xor(s, o, 64);
    s2 += __shfl_xor(s2, o, 64);
  }
  __shared__ float rs[4], rs2[4];
  if ((tid & 63) == 0) { rs[tid >> 6] = s; rs2[tid >> 6] = s2; }
  __syncthreads();
  s = rs[0] + rs[1] + rs[2] + rs[3];
  s2 = rs2[0] + rs2[1] + rs2[2] + rs2[3];
  float mean = s * (1.f / ESZ);
  float var = s2 * (1.f / ESZ) - mean * mean;
  float inv = 1.f / sqrtf(var + LNEPS);
  float4 vo;
#pragma unroll
  for (int j = 0; j < 4; j++) {
    int c = tid * 4 + j;
    float o = (x[j] - mean) * inv * g[c] + b[c];
    ((float*)&vo)[j] = o;
    o16[off + c] = (_Float16)o;
  }
  *(float4*)(o32 + off + tid * 4) = vo;
}

// ---------------------------------------------------------------------------

template<int BM, int BN, int EPI, bool RELU>
static void gemm(hipStream_t st, const _Float16* A, const _Float16* B,
                 const float* b0, const float* b1, const float* b2,
                 void* C0, void* C1, int M, int N, int K,
                 int lda, int ldb, int ldc,
                 int Z, long sAz, long sBz, int cdiv, long sC1, long sC2, int vseg)
{
  dim3 g(M / BM, N / BN, Z);
  gemm_k<BM, BN, EPI, RELU><<<g, dim3(256), 0, st>>>(
      A, B, b0, b1, b2, C0, C1, K, lda, ldb, ldc, sAz, sBz, cdiv, sC1, sC2, vseg);
}

extern "C" void kernel_launch(void* const* d_in, const int* in_sizes, int n_in,
                              void* d_out, int out_size, void* d_ws, size_t ws_size,
                              hipStream_t stream) {
  (void)n_in; (void)out_size; (void)ws_size;
  const float *emb, *cls, *sWq, *sbq, *sWk, *sbk, *sWv, *sbv, *sWo, *sbo;
  const float *cWq, *cbq, *cWk, *cbk, *cWv, *cbv, *cWo, *cbo;
  const float *fW1, *fb1, *fW2, *fb2, *g1, *g2, *g3, *b1, *b2, *b3;
  const int *xt, *yt;
  if (in_sizes[0] == NB * NXTOK) {
    xt = (const int*)d_in[0]; yt = (const int*)d_in[1];
    emb = (const float*)d_in[2]; cls = (const float*)d_in[3];
    sWq = (const float*)d_in[4]; sbq = (const float*)d_in[5];
    sWk = (const float*)d_in[6]; sbk = (const float*)d_in[7];
    sWv = (const float*)d_in[8]; sbv = (const float*)d_in[9];
    sWo = (const float*)d_in[10]; sbo = (const float*)d_in[11];
    cWq = (const float*)d_in[12]; cbq = (const float*)d_in[13];
    cWk = (const float*)d_in[14]; cbk = (const float*)d_in[15];
    cWv = (const float*)d_in[16]; cbv = (const float*)d_in[17];
    cWo = (const float*)d_in[18]; cbo = (const float*)d_in[19];
    g1 = (const float*)d_in[20]; b1 = (const float*)d_in[21];
    g2 = (const float*)d_in[22]; b2 = (const float*)d_in[23];
    g3 = (const float*)d_in[24]; b3 = (const float*)d_in[25];
    fW1 = (const float*)d_in[26]; fb1 = (const float*)d_in[27];
    fW2 = (const float*)d_in[28]; fb2 = (const float*)d_in[29];
  } else {
    emb = (const float*)d_in[0]; cls = (const float*)d_in[1];
    sWq = (const float*)d_in[2]; sbq = (const float*)d_in[3];
    sWk = (const float*)d_in[4]; sbk = (const float*)d_in[5];
    sWv = (const float*)d_in[6]; sbv = (const float*)d_in[7];
    sWo = (const float*)d_in[8]; sbo = (const float*)d_in[9];
    cWq = (const float*)d_in[10]; cbq = (const float*)d_in[11];
    cWk = (const float*)d_in[12]; cbk = (const float*)d_in[13];
    cWv = (const float*)d_in[14]; cbv = (const float*)d_in[15];
    cWo = (const float*)d_in[16]; cbo = (const float*)d_in[17];
    fW1 = (const float*)d_in[18]; fb1 = (const float*)d_in[19];
    fW2 = (const float*)d_in[20]; fb2 = (const float*)d_in[21];
    g1 = (const float*)d_in[22]; g2 = (const float*)d_in[23]; g3 = (const float*)d_in[24];
    b1 = (const float*)d_in[25]; b2 = (const float*)d_in[26]; b3 = (const float*)d_in[27];
    xt = (const int*)d_in[28]; yt = (const int*)d_in[29];
  }

  // ---- ws layout (~204 MB of ~512 MB) ----
  const size_t MM = (size_t)1 << 20;
  _Float16* W16 = (_Float16*)d_ws;       // weights: 64 MM f16 (4 layers x 16 MM)
  _Float16* qh   = W16 + 64 * MM;
  _Float16* kh   = W16 + 66 * MM;
  _Float16* vT   = W16 + 68 * MM;
  _Float16* ob   = W16 + 70 * MM;
  _Float16* y16  = W16 + 72 * MM;
  _Float16* yl16 = W16 + 74 * MM;
  _Float16* x16  = W16 + 76 * MM;
  _Float16* ffn  = W16 + 78 * MM;        // 8 MM
  float* y32  = (float*)(W16 + 86 * MM);
  float* yl32 = y32 + 2 * MM;
  float* x32  = y32 + 4 * MM;
  float* tmp  = y32 + 6 * MM;

  // ---- all-layer weight conversion (3 launches) ----
  W8 w8;
  w8.p[0] = sWq; w8.p[1] = sWk; w8.p[2] = sWv; w8.p[3] = cWq;
  w8.p[4] = cWk; w8.p[5] = cWv; w8.p[6] = sWo; w8.p[7] = cWo;
  wtr8_k<<<dim3(16, 16, 32), 256, 0, stream>>>(w8, W16);
  wtrL_k<<<dim3(16, 64, 4), 256, 0, stream>>>(fW1, W16 + 8 * MM, 1024, 4096);
  wtrL_k<<<dim3(64, 16, 4), 256, 0, stream>>>(fW2, W16 + 12 * MM, 4096, 1024);

  embed_k<<<dim3(2 * NB * SEQ), dim3(256), 0, stream>>>(xt, yt, emb, cls, y32, y16, x16);

  for (int l = 0; l < NLAYER; l++) {
    _Float16* wl   = W16 + (size_t)l * 16 * MM;
    _Float16* wqkv = wl;
    _Float16* wcq  = wl + 3 * MM;
    _Float16* wckv = wl + 4 * MM;
    _Float16* wso  = wl + 6 * MM;
    _Float16* wco  = wl + 7 * MM;
    _Float16* wf1  = wl + 8 * MM;
    _Float16* wf2  = wl + 12 * MM;

    // ---- self-attention (over original y) ----
    gemm<128, 128, 2, false>(stream, y16, wqkv,
        sbq + l * ESZ, sbk + l * ESZ, sbv + l * ESZ,
        qh, vT, 2048, 3072, 1024, 1024, 1024, 0, 1, 0, 0, 1, 0, 0, 2);
    flash_k<true><<<dim3(8, 32), 256, 0, stream>>>(qh, kh, vT, ob);
    gemm<64, 128, 0, false>(stream, ob, wso, sbo + l * ESZ, nullptr, nullptr,
        tmp, nullptr, 2048, 1024, 1024, 1024, 1024, 1024, 1, 0, 0, 1, 0, 0, 0);
    lnres_k<<<dim3(2048), 256, 0, stream>>>(y32, tmp, g1 + l * ESZ, b1 + l * ESZ, yl32, yl16);

    // ---- cross-attention ----
    gemm<64, 128, 2, false>(stream, yl16, wcq, cbq + l * ESZ, nullptr, nullptr,
        qh, vT, 2048, 1024, 1024, 1024, 1024, 0, 1, 0, 0, 1, 0, 0, 3);
    gemm<128, 128, 2, false>(stream, x16, wckv, cbk + l * ESZ, cbv + l * ESZ,
        nullptr, kh, vT, 2048, 2048, 1024, 1024, 1024, 0, 1, 0, 0, 1, 0, 0, 1);
    flash_k<false><<<dim3(8, 32), 256, 0, stream>>>(qh, kh, vT, ob);
    gemm<64, 128, 0, false>(stream, ob, wco, cbo + l * ESZ, nullptr, nullptr,
        tmp, nullptr, 2048, 1024, 1024, 1024, 1024, 1024, 1, 0, 0, 1, 0, 0, 0);
    lnres_k<<<dim3(2048), 256, 0, stream>>>(yl32, tmp, g2 + l * ESZ, b2 + l * ESZ, x32, x16);

    // ---- FFN ----
    gemm<128, 128, 1, true>(stream, x16, wf1, fb1 + l * FFD, nullptr, nullptr,
        ffn, nullptr, 2048, 4096, 1024, 1024, 1024, 4096, 1, 0, 0, 1, 0, 0, 0);
    gemm<64, 128, 0, false>(stream, ffn, wf2, fb2 + l * ESZ, nullptr, nullptr,
        tmp, nullptr, 2048, 1024, 4096, 4096, 4096, 1024, 1, 0, 0, 1, 0, 0, 0);
    lnres_k<<<dim3(2048), 256, 0, stream>>>(x32, tmp, g3 + l * ESZ, b3 + l * ESZ,
        (l == NLAYER - 1) ? (float*)d_out : x32, x16);
  }
}

// Round 5
// 1231.145 us; speedup vs baseline: 7.6163x; 1.0447x over previous
//
#include <hip/hip_runtime.h>
#include <cstdint>

#define ESZ 1024
#define NH 16
#define HD 64
#define NLAYER 4
#define FFD 4096
#define NB 2
#define NXTOK 1023
#define SEQ 1024
#define LNEPS 1e-5f

typedef __attribute__((ext_vector_type(8))) _Float16 f16x8;
typedef __attribute__((ext_vector_type(4))) _Float16 f16x4;
typedef __attribute__((ext_vector_type(4))) float f32x4;

__device__ __forceinline__ void gld16(const void* g, void* l) {
  __builtin_amdgcn_global_load_lds(
      (const __attribute__((address_space(1))) unsigned int*)g,
      (__attribute__((address_space(3))) unsigned int*)l, 16, 0, 0);
}

// Bijective XCD-aware block swizzle (each XCD gets a contiguous work chunk).
__device__ __forceinline__ uint3 xcd_swz() {
  unsigned gx = gridDim.x, gy = gridDim.y;
  unsigned nwg = gx * gy * gridDim.z;
  unsigned lin = (blockIdx.z * gy + blockIdx.y) * gx + blockIdx.x;
  unsigned q = nwg >> 3, r = nwg & 7;
  unsigned xcd = lin & 7, idx = lin >> 3;
  unsigned wid = (xcd < r ? xcd * (q + 1) : r * (q + 1) + (xcd - r) * q) + idx;
  uint3 o;
  o.x = wid % gx;
  unsigned t = wid / gx;
  o.y = t % gy;
  o.z = t / gy;
  return o;
}

// ---------------------------------------------------------------------------
// NT MFMA GEMM, f16: C = A @ B^T (+bias). A [M][K], B [N][K]. BK=64.
// 2-phase double-buffered global_load_lds staging, XOR-swizzled global source
// (LDS linear), same XOR on ds_read -> conflict-free.
// EPI: 0 = f32 C, 1 = f16 C, 2 = QKV head scatter (seg<vseg -> head-major
// [b][h][s][d] at C0, seg==vseg -> V^T [b][h][d][s] at C1).
// SPLITK>1: blockIdx.z = K-split index; partial C at C0 + z*sC1 (f32), bias
// applied by z==0 only; consumer sums partials.
// ---------------------------------------------------------------------------
template<int BM, int BN, int EPI, bool RELU, int SPLITK>
__global__ __launch_bounds__(256)
void gemm_k(const _Float16* __restrict__ A, const _Float16* __restrict__ Bm,
            const float* __restrict__ bias0, const float* __restrict__ bias1,
            const float* __restrict__ bias2,
            void* __restrict__ C0, void* __restrict__ C1,
            int K, int lda, int ldb, int ldc,
            long sAz, long sBz, int cdiv, long sC1, long sC2, int vseg)
{
  constexpr int MI = BM / 32, NJ = BN / 32;
  __shared__ _Float16 Ah[2][BM * 64];
  __shared__ _Float16 Bh[2][BN * 64];

  const uint3 bi = xcd_swz();
  const int m0 = bi.x * BM;
  const int n0 = bi.y * BN;
  const int z = bi.z;
  const _Float16* Ab;
  const _Float16* Bb;
  size_t coff;
  if (SPLITK > 1) {
    int koff = z * (K / SPLITK);
    Ab = A + koff;
    Bb = Bm + koff;
    coff = (size_t)z * sC1;
  } else {
    Ab = A + (size_t)z * sAz;
    Bb = Bm + (size_t)z * sBz;
    coff = (size_t)(z / cdiv) * sC1 + (size_t)(z % cdiv) * sC2;
  }
  const int tid = threadIdx.x;
  const int lane = tid & 63;
  const int w = tid >> 6;
  const int lr = lane & 15;
  const int hi = lane >> 4;
  const int wr = (w >> 1) * (BM / 2);
  const int wc = (w & 1) * (BN / 2);

  const f32x4 vz = {0.f, 0.f, 0.f, 0.f};
  f32x4 acc[MI][NJ];
#pragma unroll
  for (int i = 0; i < MI; i++)
#pragma unroll
    for (int j = 0; j < NJ; j++) acc[i][j] = vz;

  const int nk = (K / SPLITK) >> 6;

  auto stage = [&](int b, int kt) {
    const int k0 = kt << 6;
#pragma unroll
    for (int c = 0; c < MI; c++) {
      int r = w * (BM / 4) + c * 8 + (lane >> 3);
      int cg = ((lane & 7) ^ (r & 7)) << 3;
      gld16(Ab + (size_t)(m0 + r) * lda + k0 + cg, &Ah[b][(w * (BM / 4) + c * 8) * 64]);
    }
#pragma unroll
    for (int c = 0; c < NJ; c++) {
      int r = w * (BN / 4) + c * 8 + (lane >> 3);
      int cg = ((lane & 7) ^ (r & 7)) << 3;
      gld16(Bb + (size_t)(n0 + r) * ldb + k0 + cg, &Bh[b][(w * (BN / 4) + c * 8) * 64]);
    }
  };

  stage(0, 0);
  int cur = 0;
  for (int kt = 0; kt < nk; ++kt) {
    __syncthreads();
    if (kt + 1 < nk) stage(cur ^ 1, kt + 1);
#pragma unroll
    for (int kk = 0; kk < 2; kk++) {
      f16x8 af[MI], bf[NJ];
#pragma unroll
      for (int i = 0; i < MI; i++) {
        int row = wr + i * 16 + lr;
        int off = ((kk << 6) | (hi << 4)) ^ ((row & 7) << 4);
        af[i] = *(const f16x8*)((const char*)&Ah[cur][0] + row * 128 + off);
      }
#pragma unroll
      for (int j = 0; j < NJ; j++) {
        int row = wc + j * 16 + lr;
        int off = ((kk << 6) | (hi << 4)) ^ ((row & 7) << 4);
        bf[j] = *(const f16x8*)((const char*)&Bh[cur][0] + row * 128 + off);
      }
#pragma unroll
      for (int i = 0; i < MI; i++)
#pragma unroll
        for (int j = 0; j < NJ; j++)
          acc[i][j] = __builtin_amdgcn_mfma_f32_16x16x32_f16(af[i], bf[j], acc[i][j], 0, 0, 0);
    }
    cur ^= 1;
  }

  const int rb = hi * 4;
#pragma unroll
  for (int j = 0; j < NJ; j++) {
    const int n = n0 + wc + j * 16 + lr;
    float bv = 0.f;
    if (EPI == 2) {
      int seg = n >> 10;
      const float* bp = (seg == 0) ? bias0 : ((seg == 1) ? bias1 : bias2);
      bv = bp[n & 1023];
    } else if (bias0) bv = bias0[n];
    if (SPLITK > 1 && z > 0) bv = 0.f;
#pragma unroll
    for (int i = 0; i < MI; i++) {
#pragma unroll
      for (int r = 0; r < 4; r++) {
        int row = m0 + wr + i * 16 + rb + r;
        float out = acc[i][j][r] + bv;
        if (RELU) out = fmaxf(out, 0.f);
        if (EPI == 0) {
          ((float*)C0)[coff + (size_t)row * ldc + n] = out;
        } else if (EPI == 1) {
          ((_Float16*)C0)[coff + (size_t)row * ldc + n] = (_Float16)out;
        } else {
          int seg = n >> 10, n1 = n & 1023, h = n1 >> 6, d = n1 & 63;
          int b = row >> 10, s = row & 1023;
          if (seg == vseg)
            ((_Float16*)C1)[(((size_t)b * NH + h) * HD + d) * SEQ + s] = (_Float16)out;
          else
            ((_Float16*)C0)[(size_t)seg * ((size_t)NB * NH * SEQ * HD)
                            + (((size_t)b * NH + h) * SEQ + s) * HD + d] = (_Float16)out;
        }
      }
    }
  }
}

// ---------------------------------------------------------------------------
// Flash attention: one block = 64 q rows of one (b,h); 2 waves x 32 q rows.
// Swapped QK^T (S^T = K @ Q^T); S^T C-layout IS the B-fragment of
// mfma_16x16x16_f16 so PV (O^T = V^T @ P^T) needs no P relayout.
// K/V double-buffered via global_load_lds with XOR swizzle. Scores scaled
// 1/32 (reference quirk: mask-before-scale == skip masked).
// ---------------------------------------------------------------------------
template<bool CAUSAL>
__global__ __launch_bounds__(128)
void flash_k(const _Float16* __restrict__ qh, const _Float16* __restrict__ kh,
             const _Float16* __restrict__ vTp, _Float16* __restrict__ ob)
{
  __shared__ _Float16 Kl[2][64 * 64];
  __shared__ _Float16 Vl[2][64 * 64];
  const uint3 bi = xcd_swz();
  const int qb = bi.x;
  const int bh = bi.y;
  const int b = bh >> 4, h = bh & 15;
  const int q0 = qb * 64;
  const int tid = threadIdx.x;
  const int w = tid >> 6, lane = tid & 63;
  const int lr = lane & 15, hi = lane >> 4;
  const int qw = q0 + w * 32;

  const _Float16* Qp = qh + (size_t)bh * SEQ * HD;
  const _Float16* Kp = kh + (size_t)bh * SEQ * HD;
  const _Float16* Vp = vTp + (size_t)bh * HD * SEQ;

  f16x8 qf[2][2];
#pragma unroll
  for (int jq = 0; jq < 2; jq++)
#pragma unroll
    for (int ds = 0; ds < 2; ds++)
      qf[jq][ds] = *(const f16x8*)(Qp + (size_t)(qw + jq * 16 + lr) * HD + ds * 32 + hi * 8);

  float m[2] = {-1e30f, -1e30f}, l[2] = {0.f, 0.f};
  const f32x4 vz = {0.f, 0.f, 0.f, 0.f};
  f32x4 o[4][2];
#pragma unroll
  for (int dt = 0; dt < 4; dt++)
#pragma unroll
    for (int jq = 0; jq < 2; jq++) o[dt][jq] = vz;

  const int nst = CAUSAL ? ((q0 >> 6) + 1) : (SEQ / 64);

  auto stage = [&](int buf, int kt) {
    const int k0 = kt << 6;
#pragma unroll
    for (int c = 0; c < 4; c++) {
      int r = w * 32 + c * 8 + (lane >> 3);
      int cg = ((lane & 7) ^ (r & 7)) << 3;
      gld16(Kp + (size_t)(k0 + r) * HD + cg, &Kl[buf][(w * 32 + c * 8) * 64]);
      gld16(Vp + (size_t)r * SEQ + k0 + cg, &Vl[buf][(w * 32 + c * 8) * 64]);
    }
  };

  stage(0, 0);
  int cur = 0;
  for (int kt = 0; kt < nst; ++kt) {
    __syncthreads();
    if (kt + 1 < nst) stage(cur ^ 1, kt + 1);
    const int k0 = kt << 6;
    {
      // ---- S^T = K @ Q^T ----
      f32x4 s[4][2];
#pragma unroll
      for (int ik = 0; ik < 4; ik++)
#pragma unroll
        for (int jq = 0; jq < 2; jq++) s[ik][jq] = vz;
#pragma unroll
      for (int ds = 0; ds < 2; ds++) {
        f16x8 kf[4];
#pragma unroll
        for (int ik = 0; ik < 4; ik++) {
          int row = ik * 16 + lr;
          int off = (ds * 64 + hi * 16) ^ ((row & 7) << 4);
          kf[ik] = *(const f16x8*)((const char*)&Kl[cur][0] + row * 128 + off);
        }
#pragma unroll
        for (int ik = 0; ik < 4; ik++)
#pragma unroll
          for (int jq = 0; jq < 2; jq++)
            s[ik][jq] = __builtin_amdgcn_mfma_f32_16x16x32_f16(kf[ik], qf[jq][ds], s[ik][jq], 0, 0, 0);
      }
      // ---- scale + causal mask + row max ----
      float mx[2] = {-1e30f, -1e30f};
#pragma unroll
      for (int ik = 0; ik < 4; ik++)
#pragma unroll
        for (int jq = 0; jq < 2; jq++)
#pragma unroll
          for (int r = 0; r < 4; r++) {
            float v = s[ik][jq][r] * 0.03125f;
            if (CAUSAL) {
              int kk = k0 + ik * 16 + hi * 4 + r;
              int qq = qw + jq * 16 + lr;
              if (kk > qq) v = -1e30f;
            }
            s[ik][jq][r] = v;
            mx[jq] = fmaxf(mx[jq], v);
          }
      float sc[2], cs[2] = {0.f, 0.f};
      f16x4 pb[4][2];
#pragma unroll
      for (int jq = 0; jq < 2; jq++) {
        mx[jq] = fmaxf(mx[jq], __shfl_xor(mx[jq], 16, 64));
        mx[jq] = fmaxf(mx[jq], __shfl_xor(mx[jq], 32, 64));
        float mn = fmaxf(m[jq], mx[jq]);
        sc[jq] = __expf(m[jq] - mn);
        m[jq] = mn;
      }
#pragma unroll
      for (int ik = 0; ik < 4; ik++)
#pragma unroll
        for (int jq = 0; jq < 2; jq++)
#pragma unroll
          for (int r = 0; r < 4; r++) {
            float p = __expf(s[ik][jq][r] - m[jq]);
            cs[jq] += p;
            pb[ik][jq][r] = (_Float16)p;
          }
#pragma unroll
      for (int jq = 0; jq < 2; jq++) {
        float t = cs[jq];
        t += __shfl_xor(t, 16, 64);
        t += __shfl_xor(t, 32, 64);
        l[jq] = l[jq] * sc[jq] + t;
      }
#pragma unroll
      for (int dt = 0; dt < 4; dt++)
#pragma unroll
        for (int jq = 0; jq < 2; jq++)
#pragma unroll
          for (int r = 0; r < 4; r++) o[dt][jq][r] *= sc[jq];
      // ---- O^T += V^T @ P^T (16x16x16, P already in B-frag layout) ----
#pragma unroll
      for (int ks = 0; ks < 4; ks++) {
        f16x4 va[4];
#pragma unroll
        for (int dt = 0; dt < 4; dt++) {
          int row = dt * 16 + lr;
          int off = (ks * 32 + hi * 8) ^ ((row & 7) << 4);
          va[dt] = *(const f16x4*)((const char*)&Vl[cur][0] + row * 128 + off);
        }
#pragma unroll
        for (int dt = 0; dt < 4; dt++)
#pragma unroll
          for (int jq = 0; jq < 2; jq++)
            o[dt][jq] = __builtin_amdgcn_mfma_f32_16x16x16f16(va[dt], pb[ks][jq], o[dt][jq], 0, 0, 0);
      }
    }
    cur ^= 1;
  }

  float inv[2] = {1.f / l[0], 1.f / l[1]};
#pragma unroll
  for (int jq = 0; jq < 2; jq++) {
    int q = qw + jq * 16 + lr;
    size_t rowoff = (size_t)(b * SEQ + q) * ESZ + h * 64;
#pragma unroll
    for (int dt = 0; dt < 4; dt++) {
      f16x4 ov;
#pragma unroll
      for (int r = 0; r < 4; r++) ov[r] = (_Float16)(o[dt][jq][r] * inv[jq]);
      *(f16x4*)(ob + rowoff + dt * 16 + hi * 4) = ov;
    }
  }
}

// ---------------------------------------------------------------------------
// Weight convert+transpose body: src f32 [K][Ns] tile -> dst f16 [Ns][K]
// ---------------------------------------------------------------------------
__device__ __forceinline__ void wtr_body(const float* src, _Float16* dst,
                                         int K, int Ns, int k0, int n0,
                                         _Float16 (*t)[80], int tid)
{
  {
    int r = tid >> 4, c4 = (tid & 15) << 2;
#pragma unroll
    for (int rr = 0; rr < 4; rr++) {
      int row = r + rr * 16;
      float4 v = *(const float4*)(src + (size_t)(k0 + row) * Ns + n0 + c4);
      t[c4 + 0][row] = (_Float16)v.x; t[c4 + 1][row] = (_Float16)v.y;
      t[c4 + 2][row] = (_Float16)v.z; t[c4 + 3][row] = (_Float16)v.w;
    }
  }
  __syncthreads();
  {
    int nr = tid >> 3, c8 = (tid & 7) << 3;
#pragma unroll
    for (int rr = 0; rr < 2; rr++) {
      int n = nr + rr * 32;
      f16x8 v = *(const f16x8*)&t[n][c8];
      *(f16x8*)(dst + (size_t)(n0 + n) * K + k0 + c8) = v;
    }
  }
}

struct W8 { const float* p[8]; };

// all 8 square weights x 4 layers in one launch; z = widx*4 + layer
__global__ __launch_bounds__(256)
void wtr8_k(W8 w8, _Float16* dstbase)
{
  __shared__ _Float16 t[64][80];
  int z = blockIdx.z;
  int widx = z >> 2, layer = z & 3;
  const float* src = w8.p[widx] + (size_t)layer * (ESZ * ESZ);
  _Float16* dst = dstbase + (size_t)layer * 16777216 + (size_t)widx * 1048576;
  wtr_body(src, dst, 1024, 1024, blockIdx.x * 64, blockIdx.y * 64, t, threadIdx.x);
}

// FFN weights, all layers; z = layer
__global__ __launch_bounds__(256)
void wtrL_k(const float* src, _Float16* dst, int K, int Ns)
{
  __shared__ _Float16 t[64][80];
  int layer = blockIdx.z;
  src += (size_t)layer * K * Ns;
  dst += (size_t)layer * 16777216;
  wtr_body(src, dst, K, Ns, blockIdx.x * 64, blockIdx.y * 64, t, threadIdx.x);
}

// ---------------------------------------------------------------------------
// Embedding + PE (quirk: pe row = batch index).
// ---------------------------------------------------------------------------
__global__ __launch_bounds__(256)
void embed_k(const int* __restrict__ xt, const int* __restrict__ yt,
             const float* __restrict__ emb, const float* __restrict__ cls,
             float* __restrict__ y32, _Float16* __restrict__ y16,
             _Float16* __restrict__ x16)
{
  int row = blockIdx.x;
  bool isx = row < NB * SEQ;
  int rr = isx ? row : row - NB * SEQ;
  int b = rr >> 10, tpos = rr & (SEQ - 1);
  int col0 = threadIdx.x * 4;
  float v[4];
  if (isx && tpos == SEQ - 1) {
#pragma unroll
    for (int j = 0; j < 4; j++) v[j] = cls[col0 + j];
  } else {
    int tok = isx ? xt[b * NXTOK + tpos] : yt[b * SEQ + tpos];
    const float* erow = emb + (size_t)tok * ESZ;
#pragma unroll
    for (int j = 0; j < 4; j++) {
      int e = col0 + j;
      float div = expf((float)(e & ~1) * (-9.210340371976184f / 1024.f));
      float ang = (float)b * div;
      float pe = (e & 1) ? cosf(ang) : sinf(ang);
      v[j] = erow[e] * 32.f + pe;
    }
  }
  size_t off = (size_t)rr * ESZ + col0;
  if (isx) {
#pragma unroll
    for (int j = 0; j < 4; j++) x16[off + j] = (_Float16)v[j];
  } else {
#pragma unroll
    for (int j = 0; j < 4; j++) { y32[off + j] = v[j]; y16[off + j] = (_Float16)v[j]; }
  }
}

// ---------------------------------------------------------------------------
// out = LN(a + sum of NP partials)*g + b; writes f32 + f16
// ---------------------------------------------------------------------------
template<int NP>
__global__ __launch_bounds__(256)
void lnres_k(const float* __restrict__ a, const float* __restrict__ r0,
             const float* __restrict__ r1, const float* __restrict__ r2,
             const float* __restrict__ r3,
             const float* __restrict__ g, const float* __restrict__ b,
             float* __restrict__ o32, _Float16* __restrict__ o16)
{
  int row = blockIdx.x;
  size_t off = (size_t)row * ESZ;
  int tid = threadIdx.x;
  float4 va = *(const float4*)(a + off + tid * 4);
  float x[4] = {va.x, va.y, va.z, va.w};
  {
    float4 v = *(const float4*)(r0 + off + tid * 4);
    x[0] += v.x; x[1] += v.y; x[2] += v.z; x[3] += v.w;
  }
  if (NP >= 2) {
    float4 v = *(const float4*)(r1 + off + tid * 4);
    x[0] += v.x; x[1] += v.y; x[2] += v.z; x[3] += v.w;
  }
  if (NP >= 4) {
    float4 v = *(const float4*)(r2 + off + tid * 4);
    x[0] += v.x; x[1] += v.y; x[2] += v.z; x[3] += v.w;
    float4 u = *(const float4*)(r3 + off + tid * 4);
    x[0] += u.x; x[1] += u.y; x[2] += u.z; x[3] += u.w;
  }
  float s = x[0] + x[1] + x[2] + x[3];
  float s2 = x[0] * x[0] + x[1] * x[1] + x[2] * x[2] + x[3] * x[3];
  for (int o = 32; o > 0; o >>= 1) {
    s += __shfl_xor(s, o, 64);
    s2 += __shfl_xor(s2, o, 64);
  }
  __shared__ float rs[4], rs2[4];
  if ((tid & 63) == 0) { rs[tid >> 6] = s; rs2[tid >> 6] = s2; }
  __syncthreads();
  s = rs[0] + rs[1] + rs[2] + rs[3];
  s2 = rs2[0] + rs2[1] + rs2[2] + rs2[3];
  float mean = s * (1.f / ESZ);
  float var = s2 * (1.f / ESZ) - mean * mean;
  float inv = 1.f / sqrtf(var + LNEPS);
  float4 vo;
#pragma unroll
  for (int j = 0; j < 4; j++) {
    int c = tid * 4 + j;
    float o = (x[j] - mean) * inv * g[c] + b[c];
    ((float*)&vo)[j] = o;
    o16[off + c] = (_Float16)o;
  }
  *(float4*)(o32 + off + tid * 4) = vo;
}

// ---------------------------------------------------------------------------

template<int BM, int BN, int EPI, bool RELU, int SPLITK>
static void gemm(hipStream_t st, const _Float16* A, const _Float16* B,
                 const float* b0, const float* b1, const float* b2,
                 void* C0, void* C1, int M, int N, int K,
                 int lda, int ldb, int ldc,
                 int Z, long sAz, long sBz, int cdiv, long sC1, long sC2, int vseg)
{
  dim3 g(M / BM, N / BN, Z);
  gemm_k<BM, BN, EPI, RELU, SPLITK><<<g, dim3(256), 0, st>>>(
      A, B, b0, b1, b2, C0, C1, K, lda, ldb, ldc, sAz, sBz, cdiv, sC1, sC2, vseg);
}

extern "C" void kernel_launch(void* const* d_in, const int* in_sizes, int n_in,
                              void* d_out, int out_size, void* d_ws, size_t ws_size,
                              hipStream_t stream) {
  (void)n_in; (void)out_size; (void)ws_size;
  const float *emb, *cls, *sWq, *sbq, *sWk, *sbk, *sWv, *sbv, *sWo, *sbo;
  const float *cWq, *cbq, *cWk, *cbk, *cWv, *cbv, *cWo, *cbo;
  const float *fW1, *fb1, *fW2, *fb2, *g1, *g2, *g3, *b1, *b2, *b3;
  const int *xt, *yt;
  if (in_sizes[0] == NB * NXTOK) {
    xt = (const int*)d_in[0]; yt = (const int*)d_in[1];
    emb = (const float*)d_in[2]; cls = (const float*)d_in[3];
    sWq = (const float*)d_in[4]; sbq = (const float*)d_in[5];
    sWk = (const float*)d_in[6]; sbk = (const float*)d_in[7];
    sWv = (const float*)d_in[8]; sbv = (const float*)d_in[9];
    sWo = (const float*)d_in[10]; sbo = (const float*)d_in[11];
    cWq = (const float*)d_in[12]; cbq = (const float*)d_in[13];
    cWk = (const float*)d_in[14]; cbk = (const float*)d_in[15];
    cWv = (const float*)d_in[16]; cbv = (const float*)d_in[17];
    cWo = (const float*)d_in[18]; cbo = (const float*)d_in[19];
    g1 = (const float*)d_in[20]; b1 = (const float*)d_in[21];
    g2 = (const float*)d_in[22]; b2 = (const float*)d_in[23];
    g3 = (const float*)d_in[24]; b3 = (const float*)d_in[25];
    fW1 = (const float*)d_in[26]; fb1 = (const float*)d_in[27];
    fW2 = (const float*)d_in[28]; fb2 = (const float*)d_in[29];
  } else {
    emb = (const float*)d_in[0]; cls = (const float*)d_in[1];
    sWq = (const float*)d_in[2]; sbq = (const float*)d_in[3];
    sWk = (const float*)d_in[4]; sbk = (const float*)d_in[5];
    sWv = (const float*)d_in[6]; sbv = (const float*)d_in[7];
    sWo = (const float*)d_in[8]; sbo = (const float*)d_in[9];
    cWq = (const float*)d_in[10]; cbq = (const float*)d_in[11];
    cWk = (const float*)d_in[12]; cbk = (const float*)d_in[13];
    cWv = (const float*)d_in[14]; cbv = (const float*)d_in[15];
    cWo = (const float*)d_in[16]; cbo = (const float*)d_in[17];
    fW1 = (const float*)d_in[18]; fb1 = (const float*)d_in[19];
    fW2 = (const float*)d_in[20]; fb2 = (const float*)d_in[21];
    g1 = (const float*)d_in[22]; g2 = (const float*)d_in[23]; g3 = (const float*)d_in[24];
    b1 = (const float*)d_in[25]; b2 = (const float*)d_in[26]; b3 = (const float*)d_in[27];
    xt = (const int*)d_in[28]; yt = (const int*)d_in[29];
  }

  // ---- ws layout (~236 MB of ~512 MB) ----
  const size_t MM = (size_t)1 << 20;
  _Float16* W16 = (_Float16*)d_ws;       // weights: 64 MM f16 (4 layers x 16 MM)
  _Float16* qh   = W16 + 64 * MM;
  _Float16* kh   = W16 + 66 * MM;
  _Float16* vT   = W16 + 68 * MM;
  _Float16* ob   = W16 + 70 * MM;
  _Float16* y16  = W16 + 72 * MM;
  _Float16* yl16 = W16 + 74 * MM;
  _Float16* x16  = W16 + 76 * MM;
  _Float16* ffn  = W16 + 78 * MM;        // 8 MM
  float* y32  = (float*)(W16 + 86 * MM);
  float* yl32 = y32 + 2 * MM;
  float* x32  = y32 + 4 * MM;
  float* tmp  = y32 + 6 * MM;            // 4 partials x 2 MM f32
  const long SPf = 2048L * 1024;         // partial stride (f32 elems)

  // ---- all-layer weight conversion (3 launches) ----
  W8 w8;
  w8.p[0] = sWq; w8.p[1] = sWk; w8.p[2] = sWv; w8.p[3] = cWq;
  w8.p[4] = cWk; w8.p[5] = cWv; w8.p[6] = sWo; w8.p[7] = cWo;
  wtr8_k<<<dim3(16, 16, 32), 256, 0, stream>>>(w8, W16);
  wtrL_k<<<dim3(16, 64, 4), 256, 0, stream>>>(fW1, W16 + 8 * MM, 1024, 4096);
  wtrL_k<<<dim3(64, 16, 4), 256, 0, stream>>>(fW2, W16 + 12 * MM, 4096, 1024);

  embed_k<<<dim3(2 * NB * SEQ), dim3(256), 0, stream>>>(xt, yt, emb, cls, y32, y16, x16);

  for (int l = 0; l < NLAYER; l++) {
    _Float16* wl   = W16 + (size_t)l * 16 * MM;
    _Float16* wqkv = wl;
    _Float16* wcq  = wl + 3 * MM;
    _Float16* wckv = wl + 4 * MM;
    _Float16* wso  = wl + 6 * MM;
    _Float16* wco  = wl + 7 * MM;
    _Float16* wf1  = wl + 8 * MM;
    _Float16* wf2  = wl + 12 * MM;

    // ---- self-attention (over original y) ----
    gemm<64, 128, 2, false, 1>(stream, y16, wqkv,
        sbq + l * ESZ, sbk + l * ESZ, sbv + l * ESZ,
        qh, vT, 2048, 3072, 1024, 1024, 1024, 0, 1, 0, 0, 1, 0, 0, 2);
    flash_k<true><<<dim3(16, 32), 128, 0, stream>>>(qh, kh, vT, ob);
    gemm<64, 64, 0, false, 2>(stream, ob, wso, sbo + l * ESZ, nullptr, nullptr,
        tmp, nullptr, 2048, 1024, 1024, 1024, 1024, 1024, 2, 0, 0, 1, SPf, 0, 0);
    lnres_k<2><<<dim3(2048), 256, 0, stream>>>(y32, tmp, tmp + SPf, nullptr, nullptr,
        g1 + l * ESZ, b1 + l * ESZ, yl32, yl16);

    // ---- cross-attention ----
    gemm<64, 64, 2, false, 1>(stream, yl16, wcq, cbq + l * ESZ, nullptr, nullptr,
        qh, vT, 2048, 1024, 1024, 1024, 1024, 0, 1, 0, 0, 1, 0, 0, 3);
    gemm<64, 128, 2, false, 1>(stream, x16, wckv, cbk + l * ESZ, cbv + l * ESZ,
        nullptr, kh, vT, 2048, 2048, 1024, 1024, 1024, 0, 1, 0, 0, 1, 0, 0, 1);
    flash_k<false><<<dim3(16, 32), 128, 0, stream>>>(qh, kh, vT, ob);
    gemm<64, 64, 0, false, 2>(stream, ob, wco, cbo + l * ESZ, nullptr, nullptr,
        tmp, nullptr, 2048, 1024, 1024, 1024, 1024, 1024, 2, 0, 0, 1, SPf, 0, 0);
    lnres_k<2><<<dim3(2048), 256, 0, stream>>>(yl32, tmp, tmp + SPf, nullptr, nullptr,
        g2 + l * ESZ, b2 + l * ESZ, x32, x16);

    // ---- FFN ----
    gemm<64, 128, 1, true, 1>(stream, x16, wf1, fb1 + l * FFD, nullptr, nullptr,
        ffn, nullptr, 2048, 4096, 1024, 1024, 1024, 4096, 1, 0, 0, 1, 0, 0, 0);
    gemm<64, 128, 0, false, 4>(stream, ffn, wf2, fb2 + l * ESZ, nullptr, nullptr,
        tmp, nullptr, 2048, 1024, 4096, 4096, 4096, 1024, 4, 0, 0, 1, SPf, 0, 0);
    lnres_k<4><<<dim3(2048), 256, 0, stream>>>(x32, tmp, tmp + SPf, tmp + 2 * SPf,
        tmp + 3 * SPf, g3 + l * ESZ, b3 + l * ESZ,
        (l == NLAYER - 1) ? (float*)d_out : x32, x16);
  }
}

// Round 6
// 1121.072 us; speedup vs baseline: 8.3641x; 1.0982x over previous
//
#include <hip/hip_runtime.h>
#include <cstdint>

#define ESZ 1024
#define NH 16
#define HD 64
#define NLAYER 4
#define FFD 4096
#define NB 2
#define NXTOK 1023
#define SEQ 1024
#define LNEPS 1e-5f

typedef __attribute__((ext_vector_type(8))) _Float16 f16x8;
typedef __attribute__((ext_vector_type(4))) _Float16 f16x4;
typedef __attribute__((ext_vector_type(4))) float f32x4;

__device__ __forceinline__ void gld16(const void* g, void* l) {
  __builtin_amdgcn_global_load_lds(
      (const __attribute__((address_space(1))) unsigned int*)g,
      (__attribute__((address_space(3))) unsigned int*)l, 16, 0, 0);
}

// Bijective XCD-aware block swizzle (each XCD gets a contiguous work chunk).
__device__ __forceinline__ uint3 xcd_swz() {
  unsigned gx = gridDim.x, gy = gridDim.y;
  unsigned nwg = gx * gy * gridDim.z;
  unsigned lin = (blockIdx.z * gy + blockIdx.y) * gx + blockIdx.x;
  unsigned q = nwg >> 3, r = nwg & 7;
  unsigned xcd = lin & 7, idx = lin >> 3;
  unsigned wid = (xcd < r ? xcd * (q + 1) : r * (q + 1) + (xcd - r) * q) + idx;
  uint3 o;
  o.x = wid % gx;
  unsigned t = wid / gx;
  o.y = t % gy;
  o.z = t / gy;
  return o;
}

// ---------------------------------------------------------------------------
// NT MFMA GEMM, f16: C = A @ B^T (+bias). A [M][K], B [N][K]. BK=64.
// 2-phase double-buffered global_load_lds staging, XOR-swizzled global source
// (LDS linear), same XOR on ds_read -> conflict-free.
// EPI: 0 = f32 C, 1 = f16 C, 2 = QKV head scatter (seg<vseg -> head-major
// [b][h][s][d] at C0 + z*sC1, seg==vseg -> V^T [b][h][d][s] at C1 + z*sC2).
// SPLITK>1: z = K-split index; partial C at C0 + z*sC1 (f32), bias z==0 only.
// Batched (SPLITK==1): z selects A (sAz), B (sBz), bias (bstr), C (sC1/sC2).
// ---------------------------------------------------------------------------
template<int BM, int BN, int EPI, bool RELU, int SPLITK>
__global__ __launch_bounds__(256)
void gemm_k(const _Float16* __restrict__ A, const _Float16* __restrict__ Bm,
            const float* __restrict__ bias0, const float* __restrict__ bias1,
            const float* __restrict__ bias2,
            void* __restrict__ C0, void* __restrict__ C1,
            int K, int lda, int ldb, int ldc,
            long sAz, long sBz, int cdiv, long sC1, long sC2, int vseg, int bstr)
{
  constexpr int MI = BM / 32, NJ = BN / 32;
  __shared__ _Float16 Ah[2][BM * 64];
  __shared__ _Float16 Bh[2][BN * 64];

  const uint3 bi = xcd_swz();
  const int m0 = bi.x * BM;
  const int n0 = bi.y * BN;
  const int z = bi.z;
  const _Float16* Ab;
  const _Float16* Bb;
  size_t coff;
  if (SPLITK > 1) {
    int koff = z * (K / SPLITK);
    Ab = A + koff;
    Bb = Bm + koff;
    coff = (size_t)z * sC1;
  } else {
    Ab = A + (size_t)z * sAz;
    Bb = Bm + (size_t)z * sBz;
    coff = (size_t)(z / cdiv) * sC1 + (size_t)(z % cdiv) * sC2;
  }
  const int tid = threadIdx.x;
  const int lane = tid & 63;
  const int w = tid >> 6;
  const int lr = lane & 15;
  const int hi = lane >> 4;
  const int wr = (w >> 1) * (BM / 2);
  const int wc = (w & 1) * (BN / 2);

  const f32x4 vz = {0.f, 0.f, 0.f, 0.f};
  f32x4 acc[MI][NJ];
#pragma unroll
  for (int i = 0; i < MI; i++)
#pragma unroll
    for (int j = 0; j < NJ; j++) acc[i][j] = vz;

  const int nk = (K / SPLITK) >> 6;

  auto stage = [&](int b, int kt) {
    const int k0 = kt << 6;
#pragma unroll
    for (int c = 0; c < MI; c++) {
      int r = w * (BM / 4) + c * 8 + (lane >> 3);
      int cg = ((lane & 7) ^ (r & 7)) << 3;
      gld16(Ab + (size_t)(m0 + r) * lda + k0 + cg, &Ah[b][(w * (BM / 4) + c * 8) * 64]);
    }
#pragma unroll
    for (int c = 0; c < NJ; c++) {
      int r = w * (BN / 4) + c * 8 + (lane >> 3);
      int cg = ((lane & 7) ^ (r & 7)) << 3;
      gld16(Bb + (size_t)(n0 + r) * ldb + k0 + cg, &Bh[b][(w * (BN / 4) + c * 8) * 64]);
    }
  };

  stage(0, 0);
  int cur = 0;
  for (int kt = 0; kt < nk; ++kt) {
    __syncthreads();
    if (kt + 1 < nk) stage(cur ^ 1, kt + 1);
#pragma unroll
    for (int kk = 0; kk < 2; kk++) {
      f16x8 af[MI], bf[NJ];
#pragma unroll
      for (int i = 0; i < MI; i++) {
        int row = wr + i * 16 + lr;
        int off = ((kk << 6) | (hi << 4)) ^ ((row & 7) << 4);
        af[i] = *(const f16x8*)((const char*)&Ah[cur][0] + row * 128 + off);
      }
#pragma unroll
      for (int j = 0; j < NJ; j++) {
        int row = wc + j * 16 + lr;
        int off = ((kk << 6) | (hi << 4)) ^ ((row & 7) << 4);
        bf[j] = *(const f16x8*)((const char*)&Bh[cur][0] + row * 128 + off);
      }
#pragma unroll
      for (int i = 0; i < MI; i++)
#pragma unroll
        for (int j = 0; j < NJ; j++)
          acc[i][j] = __builtin_amdgcn_mfma_f32_16x16x32_f16(af[i], bf[j], acc[i][j], 0, 0, 0);
    }
    cur ^= 1;
  }

  const int rb = hi * 4;
#pragma unroll
  for (int j = 0; j < NJ; j++) {
    const int n = n0 + wc + j * 16 + lr;
    float bv = 0.f;
    if (EPI == 2) {
      int seg = n >> 10;
      const float* bp = (seg == 0) ? bias0 : ((seg == 1) ? bias1 : bias2);
      bv = bp[bstr * z + (n & 1023)];
    } else if (bias0) bv = bias0[bstr * z + n];
    if (SPLITK > 1 && z > 0) bv = 0.f;
#pragma unroll
    for (int i = 0; i < MI; i++) {
#pragma unroll
      for (int r = 0; r < 4; r++) {
        int row = m0 + wr + i * 16 + rb + r;
        float out = acc[i][j][r] + bv;
        if (RELU) out = fmaxf(out, 0.f);
        if (EPI == 0) {
          ((float*)C0)[coff + (size_t)row * ldc + n] = out;
        } else if (EPI == 1) {
          ((_Float16*)C0)[coff + (size_t)row * ldc + n] = (_Float16)out;
        } else {
          int seg = n >> 10, n1 = n & 1023, h = n1 >> 6, d = n1 & 63;
          int b = row >> 10, s = row & 1023;
          if (seg == vseg)
            ((_Float16*)C1)[(size_t)z * sC2 + (((size_t)b * NH + h) * HD + d) * SEQ + s] = (_Float16)out;
          else
            ((_Float16*)C0)[(size_t)z * sC1 + (size_t)seg * ((size_t)NB * NH * SEQ * HD)
                            + (((size_t)b * NH + h) * SEQ + s) * HD + d] = (_Float16)out;
        }
      }
    }
  }
}

// ---------------------------------------------------------------------------
// Flash attention: one block = 64 q rows of one (b,h); 2 waves x 32 q rows.
// blockIdx.z = layer (batched); per-layer strides qs/ks/vs/os.
// Swapped QK^T (S^T = K @ Q^T); S^T C-layout IS the B-fragment of
// mfma_16x16x16_f16 so PV (O^T = V^T @ P^T) needs no P relayout.
// ---------------------------------------------------------------------------
template<bool CAUSAL>
__global__ __launch_bounds__(128)
void flash_k(const _Float16* __restrict__ qh, const _Float16* __restrict__ kh,
             const _Float16* __restrict__ vTp, _Float16* __restrict__ ob,
             long qs, long ks, long vs, long os)
{
  __shared__ _Float16 Kl[2][64 * 64];
  __shared__ _Float16 Vl[2][64 * 64];
  const uint3 bi = xcd_swz();
  const int qb = bi.x;
  const int bh = bi.y;
  const int layer = bi.z;
  const int b = bh >> 4, h = bh & 15;
  const int q0 = qb * 64;
  const int tid = threadIdx.x;
  const int w = tid >> 6, lane = tid & 63;
  const int lr = lane & 15, hi = lane >> 4;
  const int qw = q0 + w * 32;

  const _Float16* Qp = qh + (size_t)layer * qs + (size_t)bh * SEQ * HD;
  const _Float16* Kp = kh + (size_t)layer * ks + (size_t)bh * SEQ * HD;
  const _Float16* Vp = vTp + (size_t)layer * vs + (size_t)bh * HD * SEQ;
  ob += (size_t)layer * os;

  f16x8 qf[2][2];
#pragma unroll
  for (int jq = 0; jq < 2; jq++)
#pragma unroll
    for (int ds = 0; ds < 2; ds++)
      qf[jq][ds] = *(const f16x8*)(Qp + (size_t)(qw + jq * 16 + lr) * HD + ds * 32 + hi * 8);

  float m[2] = {-1e30f, -1e30f}, l[2] = {0.f, 0.f};
  const f32x4 vz = {0.f, 0.f, 0.f, 0.f};
  f32x4 o[4][2];
#pragma unroll
  for (int dt = 0; dt < 4; dt++)
#pragma unroll
    for (int jq = 0; jq < 2; jq++) o[dt][jq] = vz;

  const int nst = CAUSAL ? ((q0 >> 6) + 1) : (SEQ / 64);

  auto stage = [&](int buf, int kt) {
    const int k0 = kt << 6;
#pragma unroll
    for (int c = 0; c < 4; c++) {
      int r = w * 32 + c * 8 + (lane >> 3);
      int cg = ((lane & 7) ^ (r & 7)) << 3;
      gld16(Kp + (size_t)(k0 + r) * HD + cg, &Kl[buf][(w * 32 + c * 8) * 64]);
      gld16(Vp + (size_t)r * SEQ + k0 + cg, &Vl[buf][(w * 32 + c * 8) * 64]);
    }
  };

  stage(0, 0);
  int cur = 0;
  for (int kt = 0; kt < nst; ++kt) {
    __syncthreads();
    if (kt + 1 < nst) stage(cur ^ 1, kt + 1);
    const int k0 = kt << 6;
    {
      // ---- S^T = K @ Q^T ----
      f32x4 s[4][2];
#pragma unroll
      for (int ik = 0; ik < 4; ik++)
#pragma unroll
        for (int jq = 0; jq < 2; jq++) s[ik][jq] = vz;
#pragma unroll
      for (int ds = 0; ds < 2; ds++) {
        f16x8 kf[4];
#pragma unroll
        for (int ik = 0; ik < 4; ik++) {
          int row = ik * 16 + lr;
          int off = (ds * 64 + hi * 16) ^ ((row & 7) << 4);
          kf[ik] = *(const f16x8*)((const char*)&Kl[cur][0] + row * 128 + off);
        }
#pragma unroll
        for (int ik = 0; ik < 4; ik++)
#pragma unroll
          for (int jq = 0; jq < 2; jq++)
            s[ik][jq] = __builtin_amdgcn_mfma_f32_16x16x32_f16(kf[ik], qf[jq][ds], s[ik][jq], 0, 0, 0);
      }
      // ---- scale + causal mask + row max ----
      float mx[2] = {-1e30f, -1e30f};
#pragma unroll
      for (int ik = 0; ik < 4; ik++)
#pragma unroll
        for (int jq = 0; jq < 2; jq++)
#pragma unroll
          for (int r = 0; r < 4; r++) {
            float v = s[ik][jq][r] * 0.03125f;
            if (CAUSAL) {
              int kk = k0 + ik * 16 + hi * 4 + r;
              int qq = qw + jq * 16 + lr;
              if (kk > qq) v = -1e30f;
            }
            s[ik][jq][r] = v;
            mx[jq] = fmaxf(mx[jq], v);
          }
      float sc[2], cs[2] = {0.f, 0.f};
      f16x4 pb[4][2];
#pragma unroll
      for (int jq = 0; jq < 2; jq++) {
        mx[jq] = fmaxf(mx[jq], __shfl_xor(mx[jq], 16, 64));
        mx[jq] = fmaxf(mx[jq], __shfl_xor(mx[jq], 32, 64));
        float mn = fmaxf(m[jq], mx[jq]);
        sc[jq] = __expf(m[jq] - mn);
        m[jq] = mn;
      }
#pragma unroll
      for (int ik = 0; ik < 4; ik++)
#pragma unroll
        for (int jq = 0; jq < 2; jq++)
#pragma unroll
          for (int r = 0; r < 4; r++) {
            float p = __expf(s[ik][jq][r] - m[jq]);
            cs[jq] += p;
            pb[ik][jq][r] = (_Float16)p;
          }
#pragma unroll
      for (int jq = 0; jq < 2; jq++) {
        float t = cs[jq];
        t += __shfl_xor(t, 16, 64);
        t += __shfl_xor(t, 32, 64);
        l[jq] = l[jq] * sc[jq] + t;
      }
#pragma unroll
      for (int dt = 0; dt < 4; dt++)
#pragma unroll
        for (int jq = 0; jq < 2; jq++)
#pragma unroll
          for (int r = 0; r < 4; r++) o[dt][jq][r] *= sc[jq];
      // ---- O^T += V^T @ P^T (16x16x16, P already in B-frag layout) ----
#pragma unroll
      for (int ks2 = 0; ks2 < 4; ks2++) {
        f16x4 va[4];
#pragma unroll
        for (int dt = 0; dt < 4; dt++) {
          int row = dt * 16 + lr;
          int off = (ks2 * 32 + hi * 8) ^ ((row & 7) << 4);
          va[dt] = *(const f16x4*)((const char*)&Vl[cur][0] + row * 128 + off);
        }
#pragma unroll
        for (int dt = 0; dt < 4; dt++)
#pragma unroll
          for (int jq = 0; jq < 2; jq++)
            o[dt][jq] = __builtin_amdgcn_mfma_f32_16x16x16f16(va[dt], pb[ks2][jq], o[dt][jq], 0, 0, 0);
      }
    }
    cur ^= 1;
  }

  float inv[2] = {1.f / l[0], 1.f / l[1]};
#pragma unroll
  for (int jq = 0; jq < 2; jq++) {
    int q = qw + jq * 16 + lr;
    size_t rowoff = (size_t)(b * SEQ + q) * ESZ + h * 64;
#pragma unroll
    for (int dt = 0; dt < 4; dt++) {
      f16x4 ov;
#pragma unroll
      for (int r = 0; r < 4; r++) ov[r] = (_Float16)(o[dt][jq][r] * inv[jq]);
      *(f16x4*)(ob + rowoff + dt * 16 + hi * 4) = ov;
    }
  }
}

// ---------------------------------------------------------------------------
// Weight convert+transpose body: src f32 [K][Ns] tile -> dst f16 [Ns][K]
// ---------------------------------------------------------------------------
__device__ __forceinline__ void wtr_body(const float* src, _Float16* dst,
                                         int K, int Ns, int k0, int n0,
                                         _Float16 (*t)[80], int tid)
{
  {
    int r = tid >> 4, c4 = (tid & 15) << 2;
#pragma unroll
    for (int rr = 0; rr < 4; rr++) {
      int row = r + rr * 16;
      float4 v = *(const float4*)(src + (size_t)(k0 + row) * Ns + n0 + c4);
      t[c4 + 0][row] = (_Float16)v.x; t[c4 + 1][row] = (_Float16)v.y;
      t[c4 + 2][row] = (_Float16)v.z; t[c4 + 3][row] = (_Float16)v.w;
    }
  }
  __syncthreads();
  {
    int nr = tid >> 3, c8 = (tid & 7) << 3;
#pragma unroll
    for (int rr = 0; rr < 2; rr++) {
      int n = nr + rr * 32;
      f16x8 v = *(const f16x8*)&t[n][c8];
      *(f16x8*)(dst + (size_t)(n0 + n) * K + k0 + c8) = v;
    }
  }
}

struct W8 { const float* p[8]; };

__global__ __launch_bounds__(256)
void wtr8_k(W8 w8, _Float16* dstbase)
{
  __shared__ _Float16 t[64][80];
  int z = blockIdx.z;
  int widx = z >> 2, layer = z & 3;
  const float* src = w8.p[widx] + (size_t)layer * (ESZ * ESZ);
  _Float16* dst = dstbase + (size_t)layer * 16777216 + (size_t)widx * 1048576;
  wtr_body(src, dst, 1024, 1024, blockIdx.x * 64, blockIdx.y * 64, t, threadIdx.x);
}

__global__ __launch_bounds__(256)
void wtrL_k(const float* src, _Float16* dst, int K, int Ns)
{
  __shared__ _Float16 t[64][80];
  int layer = blockIdx.z;
  src += (size_t)layer * K * Ns;
  dst += (size_t)layer * 16777216;
  wtr_body(src, dst, K, Ns, blockIdx.x * 64, blockIdx.y * 64, t, threadIdx.x);
}

// ---------------------------------------------------------------------------
// Embedding + PE (quirk: pe row = batch index).
// ---------------------------------------------------------------------------
__global__ __launch_bounds__(256)
void embed_k(const int* __restrict__ xt, const int* __restrict__ yt,
             const float* __restrict__ emb, const float* __restrict__ cls,
             float* __restrict__ y32, _Float16* __restrict__ y16,
             _Float16* __restrict__ x16)
{
  int row = blockIdx.x;
  bool isx = row < NB * SEQ;
  int rr = isx ? row : row - NB * SEQ;
  int b = rr >> 10, tpos = rr & (SEQ - 1);
  int col0 = threadIdx.x * 4;
  float v[4];
  if (isx && tpos == SEQ - 1) {
#pragma unroll
    for (int j = 0; j < 4; j++) v[j] = cls[col0 + j];
  } else {
    int tok = isx ? xt[b * NXTOK + tpos] : yt[b * SEQ + tpos];
    const float* erow = emb + (size_t)tok * ESZ;
#pragma unroll
    for (int j = 0; j < 4; j++) {
      int e = col0 + j;
      float div = expf((float)(e & ~1) * (-9.210340371976184f / 1024.f));
      float ang = (float)b * div;
      float pe = (e & 1) ? cosf(ang) : sinf(ang);
      v[j] = erow[e] * 32.f + pe;
    }
  }
  size_t off = (size_t)rr * ESZ + col0;
  if (isx) {
#pragma unroll
    for (int j = 0; j < 4; j++) x16[off + j] = (_Float16)v[j];
  } else {
#pragma unroll
    for (int j = 0; j < 4; j++) { y32[off + j] = v[j]; y16[off + j] = (_Float16)v[j]; }
  }
}

// ---------------------------------------------------------------------------
// out = LN(a + sum of NP partials)*g + b; writes f32 + f16.
// blockIdx.y = layer (batched): strides aStr/rStr/oStr/gStr.
// ---------------------------------------------------------------------------
template<int NP>
__global__ __launch_bounds__(256)
void lnres_k(const float* __restrict__ a, const float* __restrict__ r0,
             const float* __restrict__ r1, const float* __restrict__ r2,
             const float* __restrict__ r3,
             const float* __restrict__ g, const float* __restrict__ b,
             float* __restrict__ o32, _Float16* __restrict__ o16,
             long aStr, long rStr, long oStr, int gStr)
{
  int row = blockIdx.x;
  int lz = blockIdx.y;
  a += (size_t)lz * aStr;
  r0 += (size_t)lz * rStr;
  o32 += (size_t)lz * oStr;
  o16 += (size_t)lz * oStr;
  g += (size_t)lz * gStr;
  b += (size_t)lz * gStr;
  size_t off = (size_t)row * ESZ;
  int tid = threadIdx.x;
  float4 va = *(const float4*)(a + off + tid * 4);
  float x[4] = {va.x, va.y, va.z, va.w};
  {
    float4 v = *(const float4*)(r0 + off + tid * 4);
    x[0] += v.x; x[1] += v.y; x[2] += v.z; x[3] += v.w;
  }
  if (NP >= 2) {
    float4 v = *(const float4*)(r1 + off + tid * 4);
    x[0] += v.x; x[1] += v.y; x[2] += v.z; x[3] += v.w;
  }
  if (NP >= 4) {
    float4 v = *(const float4*)(r2 + off + tid * 4);
    x[0] += v.x; x[1] += v.y; x[2] += v.z; x[3] += v.w;
    float4 u = *(const float4*)(r3 + off + tid * 4);
    x[0] += u.x; x[1] += u.y; x[2] += u.z; x[3] += u.w;
  }
  float s = x[0] + x[1] + x[2] + x[3];
  float s2 = x[0] * x[0] + x[1] * x[1] + x[2] * x[2] + x[3] * x[3];
  for (int o = 32; o > 0; o >>= 1) {
    s += __shfl_xor(s, o, 64);
    s2 += __shfl_xor(s2, o, 64);
  }
  __shared__ float rs[4], rs2[4];
  if ((tid & 63) == 0) { rs[tid >> 6] = s; rs2[tid >> 6] = s2; }
  __syncthreads();
  s = rs[0] + rs[1] + rs[2] + rs[3];
  s2 = rs2[0] + rs2[1] + rs2[2] + rs2[3];
  float mean = s * (1.f / ESZ);
  float var = s2 * (1.f / ESZ) - mean * mean;
  float inv = 1.f / sqrtf(var + LNEPS);
  float4 vo;
#pragma unroll
  for (int j = 0; j < 4; j++) {
    int c = tid * 4 + j;
    float o = (x[j] - mean) * inv * g[c] + b[c];
    ((float*)&vo)[j] = o;
    o16[off + c] = (_Float16)o;
  }
  *(float4*)(o32 + off + tid * 4) = vo;
}

// ---------------------------------------------------------------------------

template<int BM, int BN, int EPI, bool RELU, int SPLITK>
static void gemm(hipStream_t st, const _Float16* A, const _Float16* B,
                 const float* b0, const float* b1, const float* b2,
                 void* C0, void* C1, int M, int N, int K,
                 int lda, int ldb, int ldc,
                 int Z, long sAz, long sBz, int cdiv, long sC1, long sC2,
                 int vseg, int bstr)
{
  dim3 g(M / BM, N / BN, Z);
  gemm_k<BM, BN, EPI, RELU, SPLITK><<<g, dim3(256), 0, st>>>(
      A, B, b0, b1, b2, C0, C1, K, lda, ldb, ldc, sAz, sBz, cdiv, sC1, sC2, vseg, bstr);
}

extern "C" void kernel_launch(void* const* d_in, const int* in_sizes, int n_in,
                              void* d_out, int out_size, void* d_ws, size_t ws_size,
                              hipStream_t stream) {
  (void)n_in; (void)out_size; (void)ws_size;
  const float *emb, *cls, *sWq, *sbq, *sWk, *sbk, *sWv, *sbv, *sWo, *sbo;
  const float *cWq, *cbq, *cWk, *cbk, *cWv, *cbv, *cWo, *cbo;
  const float *fW1, *fb1, *fW2, *fb2, *g1, *g2, *g3, *b1, *b2, *b3;
  const int *xt, *yt;
  if (in_sizes[0] == NB * NXTOK) {
    xt = (const int*)d_in[0]; yt = (const int*)d_in[1];
    emb = (const float*)d_in[2]; cls = (const float*)d_in[3];
    sWq = (const float*)d_in[4]; sbq = (const float*)d_in[5];
    sWk = (const float*)d_in[6]; sbk = (const float*)d_in[7];
    sWv = (const float*)d_in[8]; sbv = (const float*)d_in[9];
    sWo = (const float*)d_in[10]; sbo = (const float*)d_in[11];
    cWq = (const float*)d_in[12]; cbq = (const float*)d_in[13];
    cWk = (const float*)d_in[14]; cbk = (const float*)d_in[15];
    cWv = (const float*)d_in[16]; cbv = (const float*)d_in[17];
    cWo = (const float*)d_in[18]; cbo = (const float*)d_in[19];
    g1 = (const float*)d_in[20]; b1 = (const float*)d_in[21];
    g2 = (const float*)d_in[22]; b2 = (const float*)d_in[23];
    g3 = (const float*)d_in[24]; b3 = (const float*)d_in[25];
    fW1 = (const float*)d_in[26]; fb1 = (const float*)d_in[27];
    fW2 = (const float*)d_in[28]; fb2 = (const float*)d_in[29];
  } else {
    emb = (const float*)d_in[0]; cls = (const float*)d_in[1];
    sWq = (const float*)d_in[2]; sbq = (const float*)d_in[3];
    sWk = (const float*)d_in[4]; sbk = (const float*)d_in[5];
    sWv = (const float*)d_in[6]; sbv = (const float*)d_in[7];
    sWo = (const float*)d_in[8]; sbo = (const float*)d_in[9];
    cWq = (const float*)d_in[10]; cbq = (const float*)d_in[11];
    cWk = (const float*)d_in[12]; cbk = (const float*)d_in[13];
    cWv = (const float*)d_in[14]; cbv = (const float*)d_in[15];
    cWo = (const float*)d_in[16]; cbo = (const float*)d_in[17];
    fW1 = (const float*)d_in[18]; fb1 = (const float*)d_in[19];
    fW2 = (const float*)d_in[20]; fb2 = (const float*)d_in[21];
    g1 = (const float*)d_in[22]; g2 = (const float*)d_in[23]; g3 = (const float*)d_in[24];
    b1 = (const float*)d_in[25]; b2 = (const float*)d_in[26]; b3 = (const float*)d_in[27];
    xt = (const int*)d_in[28]; yt = (const int*)d_in[29];
  }

  // ---- ws layout (~340 MB of ~512 MB) ----
  const size_t MM = (size_t)1 << 20;
  _Float16* W16 = (_Float16*)d_ws;       // weights: 64 MM f16 (4 layers x 16 MM)
  _Float16* qhk_all = W16 + 64 * MM;     // [l]{q 2MM, k 2MM} = 16 MM
  _Float16* vT_all  = W16 + 80 * MM;     // [l] 2MM = 8 MM
  _Float16* ob_all  = W16 + 88 * MM;     // [l] 2MM = 8 MM
  _Float16* y16     = W16 + 96 * MM;     // 2 MM
  _Float16* yl16_all= W16 + 98 * MM;     // [l] 2MM = 8 MM
  _Float16* cqh_all = W16 + 106 * MM;    // [l] 2MM = 8 MM
  _Float16* kh_c    = W16 + 114 * MM;    // 2 MM
  _Float16* vT_c    = W16 + 116 * MM;    // 2 MM
  _Float16* ob_c    = W16 + 118 * MM;    // 2 MM
  _Float16* x16     = W16 + 120 * MM;    // 2 MM
  _Float16* ffn     = W16 + 122 * MM;    // 8 MM
  float* y32      = (float*)(W16 + 130 * MM);  // 2 MM f32
  float* tmp_all  = y32 + 2 * MM;              // 4 x 2MM f32
  float* yl32_all = y32 + 10 * MM;             // 4 x 2MM f32
  float* x32      = y32 + 18 * MM;             // 2 MM f32
  const long SPf = 2048L * 1024;               // 2MM f32 partial/layer stride

  // ---- upfront: weight conversion + embed ----
  W8 w8;
  w8.p[0] = sWq; w8.p[1] = sWk; w8.p[2] = sWv; w8.p[3] = cWq;
  w8.p[4] = cWk; w8.p[5] = cWv; w8.p[6] = sWo; w8.p[7] = cWo;
  wtr8_k<<<dim3(16, 16, 32), 256, 0, stream>>>(w8, W16);
  wtrL_k<<<dim3(16, 64, 4), 256, 0, stream>>>(fW1, W16 + 8 * MM, 1024, 4096);
  wtrL_k<<<dim3(64, 16, 4), 256, 0, stream>>>(fW2, W16 + 12 * MM, 4096, 1024);
  embed_k<<<dim3(2 * NB * SEQ), dim3(256), 0, stream>>>(xt, yt, emb, cls, y32, y16, x16);

  // ---- hoisted: entire self-attn branch + cross-q for ALL layers ----
  // (reference quirk: self-attn always reads the ORIGINAL embedded y)
  gemm<64, 128, 2, false, 1>(stream, y16, W16, sbq, sbk, sbv,
      qhk_all, vT_all, 2048, 3072, 1024, 1024, 1024, 0,
      4, 0, 16 * MM, 1, 4 * MM, 2 * MM, 2, 1024);
  flash_k<true><<<dim3(16, 32, 4), 128, 0, stream>>>(
      qhk_all, qhk_all + 2 * MM, vT_all, ob_all, 4 * MM, 4 * MM, 2 * MM, 2 * MM);
  gemm<64, 64, 0, false, 1>(stream, ob_all, W16 + 6 * MM, sbo, nullptr, nullptr,
      tmp_all, nullptr, 2048, 1024, 1024, 1024, 1024, 1024,
      4, 2 * MM, 16 * MM, 1, SPf, 0, 0, 1024);
  lnres_k<1><<<dim3(2048, 4), 256, 0, stream>>>(y32, tmp_all, nullptr, nullptr, nullptr,
      g1, b1, yl32_all, yl16_all, 0, SPf, 2 * MM, 1024);
  gemm<64, 64, 2, false, 1>(stream, yl16_all, W16 + 3 * MM, cbq, nullptr, nullptr,
      cqh_all, nullptr, 2048, 1024, 1024, 1024, 1024, 0,
      4, 2 * MM, 16 * MM, 1, 2 * MM, 0, 3, 1024);

  // ---- sequential decoder chain ----
  for (int l = 0; l < NLAYER; l++) {
    _Float16* wl   = W16 + (size_t)l * 16 * MM;
    _Float16* wckv = wl + 4 * MM;
    _Float16* wco  = wl + 7 * MM;
    _Float16* wf1  = wl + 8 * MM;
    _Float16* wf2  = wl + 12 * MM;

    gemm<64, 128, 2, false, 1>(stream, x16, wckv, cbk + l * ESZ, cbv + l * ESZ,
        nullptr, kh_c, vT_c, 2048, 2048, 1024, 1024, 1024, 0,
        1, 0, 0, 1, 0, 0, 1, 0);
    flash_k<false><<<dim3(16, 32, 1), 128, 0, stream>>>(
        cqh_all + (size_t)l * 2 * MM, kh_c, vT_c, ob_c, 0, 0, 0, 0);
    gemm<64, 64, 0, false, 2>(stream, ob_c, wco, cbo + l * ESZ, nullptr, nullptr,
        tmp_all, nullptr, 2048, 1024, 1024, 1024, 1024, 1024,
        2, 0, 0, 1, SPf, 0, 0, 0);
    lnres_k<2><<<dim3(2048, 1), 256, 0, stream>>>(yl32_all + (size_t)l * 2 * MM,
        tmp_all, tmp_all + SPf, nullptr, nullptr,
        g2 + l * ESZ, b2 + l * ESZ, x32, x16, 0, 0, 0, 0);

    gemm<64, 128, 1, true, 1>(stream, x16, wf1, fb1 + l * FFD, nullptr, nullptr,
        ffn, nullptr, 2048, 4096, 1024, 1024, 1024, 4096,
        1, 0, 0, 1, 0, 0, 0, 0);
    gemm<64, 128, 0, false, 4>(stream, ffn, wf2, fb2 + l * ESZ, nullptr, nullptr,
        tmp_all, nullptr, 2048, 1024, 4096, 4096, 4096, 1024,
        4, 0, 0, 1, SPf, 0, 0, 0);
    lnres_k<4><<<dim3(2048, 1), 256, 0, stream>>>(x32, tmp_all, tmp_all + SPf,
        tmp_all + 2 * SPf, tmp_all + 3 * SPf, g3 + l * ESZ, b3 + l * ESZ,
        (l == NLAYER - 1) ? (float*)d_out : x32, x16, 0, 0, 0, 0);
  }
}

// Round 7
// 1047.845 us; speedup vs baseline: 8.9486x; 1.0699x over previous
//
#include <hip/hip_runtime.h>
#include <cstdint>

#define ESZ 1024
#define NH 16
#define HD 64
#define NLAYER 4
#define FFD 4096
#define NB 2
#define NXTOK 1023
#define SEQ 1024
#define LNEPS 1e-5f

typedef __attribute__((ext_vector_type(8))) _Float16 f16x8;
typedef __attribute__((ext_vector_type(4))) _Float16 f16x4;
typedef __attribute__((ext_vector_type(4))) float f32x4;

__device__ __forceinline__ void gld16(const void* g, void* l) {
  __builtin_amdgcn_global_load_lds(
      (const __attribute__((address_space(1))) unsigned int*)g,
      (__attribute__((address_space(3))) unsigned int*)l, 16, 0, 0);
}

// Bijective XCD-aware block swizzle (each XCD gets a contiguous work chunk).
__device__ __forceinline__ uint3 xcd_swz() {
  unsigned gx = gridDim.x, gy = gridDim.y;
  unsigned nwg = gx * gy * gridDim.z;
  unsigned lin = (blockIdx.z * gy + blockIdx.y) * gx + blockIdx.x;
  unsigned q = nwg >> 3, r = nwg & 7;
  unsigned xcd = lin & 7, idx = lin >> 3;
  unsigned wid = (xcd < r ? xcd * (q + 1) : r * (q + 1) + (xcd - r) * q) + idx;
  uint3 o;
  o.x = wid % gx;
  unsigned t = wid / gx;
  o.y = t % gy;
  o.z = t / gy;
  return o;
}

// ---------------------------------------------------------------------------
// Shared GEMM epilogue: writes one wave's MI x NJ fragment block.
// EPI: 0 = f32 C, 1 = f16 C, 2 = QKV head scatter.
// ---------------------------------------------------------------------------
template<int MI, int NJ, int EPI, bool RELU, int SPLITK>
__device__ __forceinline__ void gemm_epi(
    f32x4 (&acc)[MI][NJ], int m0, int n0, int wr, int wc, int lr, int hi,
    int z, size_t coff, int ldc,
    const float* bias0, const float* bias1, const float* bias2, int bstr,
    void* C0, void* C1, long sC1, long sC2, int vseg)
{
  const int rb = hi * 4;
#pragma unroll
  for (int j = 0; j < NJ; j++) {
    const int n = n0 + wc + j * 16 + lr;
    float bv = 0.f;
    if (EPI == 2) {
      int seg = n >> 10;
      const float* bp = (seg == 0) ? bias0 : ((seg == 1) ? bias1 : bias2);
      bv = bp[bstr * z + (n & 1023)];
    } else if (bias0) bv = bias0[bstr * z + n];
    if (SPLITK > 1 && z > 0) bv = 0.f;
#pragma unroll
    for (int i = 0; i < MI; i++) {
#pragma unroll
      for (int r = 0; r < 4; r++) {
        int row = m0 + wr + i * 16 + rb + r;
        float out = acc[i][j][r] + bv;
        if (RELU) out = fmaxf(out, 0.f);
        if (EPI == 0) {
          ((float*)C0)[coff + (size_t)row * ldc + n] = out;
        } else if (EPI == 1) {
          ((_Float16*)C0)[coff + (size_t)row * ldc + n] = (_Float16)out;
        } else {
          int seg = n >> 10, n1 = n & 1023, h = n1 >> 6, d = n1 & 63;
          int b = row >> 10, s = row & 1023;
          if (seg == vseg)
            ((_Float16*)C1)[(size_t)z * sC2 + (((size_t)b * NH + h) * HD + d) * SEQ + s] = (_Float16)out;
          else
            ((_Float16*)C0)[(size_t)z * sC1 + (size_t)seg * ((size_t)NB * NH * SEQ * HD)
                            + (((size_t)b * NH + h) * SEQ + s) * HD + d] = (_Float16)out;
        }
      }
    }
  }
}

// ---------------------------------------------------------------------------
// 4-wave NT MFMA GEMM (BM x BN, BK=64), 2-phase gld16 double-buffer,
// XOR-swizzled global source / swizzled ds_read.
// ---------------------------------------------------------------------------
template<int BM, int BN, int EPI, bool RELU, int SPLITK>
__global__ __launch_bounds__(256)
void gemm_k(const _Float16* __restrict__ A, const _Float16* __restrict__ Bm,
            const float* __restrict__ bias0, const float* __restrict__ bias1,
            const float* __restrict__ bias2,
            void* __restrict__ C0, void* __restrict__ C1,
            int K, int lda, int ldb, int ldc,
            long sAz, long sBz, int cdiv, long sC1, long sC2, int vseg, int bstr)
{
  constexpr int MI = BM / 32, NJ = BN / 32;
  __shared__ _Float16 Ah[2][BM * 64];
  __shared__ _Float16 Bh[2][BN * 64];

  const uint3 bi = xcd_swz();
  const int m0 = bi.x * BM;
  const int n0 = bi.y * BN;
  const int z = bi.z;
  const _Float16* Ab;
  const _Float16* Bb;
  size_t coff;
  if (SPLITK > 1) {
    int koff = z * (K / SPLITK);
    Ab = A + koff;
    Bb = Bm + koff;
    coff = (size_t)z * sC1;
  } else {
    Ab = A + (size_t)z * sAz;
    Bb = Bm + (size_t)z * sBz;
    coff = (size_t)(z / cdiv) * sC1 + (size_t)(z % cdiv) * sC2;
  }
  const int tid = threadIdx.x;
  const int lane = tid & 63;
  const int w = tid >> 6;
  const int lr = lane & 15;
  const int hi = lane >> 4;
  const int wr = (w >> 1) * (BM / 2);
  const int wc = (w & 1) * (BN / 2);

  const f32x4 vz = {0.f, 0.f, 0.f, 0.f};
  f32x4 acc[MI][NJ];
#pragma unroll
  for (int i = 0; i < MI; i++)
#pragma unroll
    for (int j = 0; j < NJ; j++) acc[i][j] = vz;

  const int nk = (K / SPLITK) >> 6;

  auto stage = [&](int b, int kt) {
    const int k0 = kt << 6;
#pragma unroll
    for (int c = 0; c < MI; c++) {
      int r = w * (BM / 4) + c * 8 + (lane >> 3);
      int cg = ((lane & 7) ^ (r & 7)) << 3;
      gld16(Ab + (size_t)(m0 + r) * lda + k0 + cg, &Ah[b][(w * (BM / 4) + c * 8) * 64]);
    }
#pragma unroll
    for (int c = 0; c < NJ; c++) {
      int r = w * (BN / 4) + c * 8 + (lane >> 3);
      int cg = ((lane & 7) ^ (r & 7)) << 3;
      gld16(Bb + (size_t)(n0 + r) * ldb + k0 + cg, &Bh[b][(w * (BN / 4) + c * 8) * 64]);
    }
  };

  stage(0, 0);
  int cur = 0;
  for (int kt = 0; kt < nk; ++kt) {
    __syncthreads();
    if (kt + 1 < nk) stage(cur ^ 1, kt + 1);
#pragma unroll
    for (int kk = 0; kk < 2; kk++) {
      f16x8 af[MI], bf[NJ];
#pragma unroll
      for (int i = 0; i < MI; i++) {
        int row = wr + i * 16 + lr;
        int off = ((kk << 6) | (hi << 4)) ^ ((row & 7) << 4);
        af[i] = *(const f16x8*)((const char*)&Ah[cur][0] + row * 128 + off);
      }
#pragma unroll
      for (int j = 0; j < NJ; j++) {
        int row = wc + j * 16 + lr;
        int off = ((kk << 6) | (hi << 4)) ^ ((row & 7) << 4);
        bf[j] = *(const f16x8*)((const char*)&Bh[cur][0] + row * 128 + off);
      }
#pragma unroll
      for (int i = 0; i < MI; i++)
#pragma unroll
        for (int j = 0; j < NJ; j++)
          acc[i][j] = __builtin_amdgcn_mfma_f32_16x16x32_f16(af[i], bf[j], acc[i][j], 0, 0, 0);
    }
    cur ^= 1;
  }

  gemm_epi<MI, NJ, EPI, RELU, SPLITK>(acc, m0, n0, wr, wc, lr, hi, z, coff, ldc,
                                      bias0, bias1, bias2, bstr, C0, C1, sC1, sC2, vseg);
}

// ---------------------------------------------------------------------------
// 8-wave NT MFMA GEMM: BM=128, BN=256, BK=64, 512 threads, wave grid 2x4,
// wave-tile 64x64. 2x MFMA per ds_read vs the 64x128 config; B staged once
// for 8 waves. LDS 96 KB (1 block/CU, 2 waves/SIMD).
// ---------------------------------------------------------------------------
template<int EPI, bool RELU, int SPLITK>
__global__ __launch_bounds__(512)
void gemm8_k(const _Float16* __restrict__ A, const _Float16* __restrict__ Bm,
             const float* __restrict__ bias0, const float* __restrict__ bias1,
             const float* __restrict__ bias2,
             void* __restrict__ C0, void* __restrict__ C1,
             int K, int lda, int ldb, int ldc,
             long sAz, long sBz, long sC1, long sC2, int vseg, int bstr)
{
  constexpr int BM = 128, BN = 256, MI = 4, NJ = 4;
  __shared__ _Float16 Ah[2][BM * 64];
  __shared__ _Float16 Bh[2][BN * 64];

  const uint3 bi = xcd_swz();
  const int m0 = bi.x * BM;
  const int n0 = bi.y * BN;
  const int z = bi.z;
  const _Float16* Ab;
  const _Float16* Bb;
  size_t coff;
  if (SPLITK > 1) {
    int koff = z * (K / SPLITK);
    Ab = A + koff;
    Bb = Bm + koff;
    coff = (size_t)z * sC1;
  } else {
    Ab = A + (size_t)z * sAz;
    Bb = Bm + (size_t)z * sBz;
    coff = (size_t)z * sC1;
  }
  const int tid = threadIdx.x;
  const int lane = tid & 63;
  const int w = tid >> 6;            // 0..7
  const int lr = lane & 15;
  const int hi = lane >> 4;
  const int wr = (w >> 2) * 64;      // 2 wave-rows
  const int wc = (w & 3) * 64;       // 4 wave-cols

  const f32x4 vz = {0.f, 0.f, 0.f, 0.f};
  f32x4 acc[MI][NJ];
#pragma unroll
  for (int i = 0; i < MI; i++)
#pragma unroll
    for (int j = 0; j < NJ; j++) acc[i][j] = vz;

  const int nk = (K / SPLITK) >> 6;

  auto stage = [&](int b, int kt) {
    const int k0 = kt << 6;
#pragma unroll
    for (int c = 0; c < 2; c++) {          // A: 16 rows/wave
      int r = w * 16 + c * 8 + (lane >> 3);
      int cg = ((lane & 7) ^ (r & 7)) << 3;
      gld16(Ab + (size_t)(m0 + r) * lda + k0 + cg, &Ah[b][(w * 16 + c * 8) * 64]);
    }
#pragma unroll
    for (int c = 0; c < 4; c++) {          // B: 32 rows/wave
      int r = w * 32 + c * 8 + (lane >> 3);
      int cg = ((lane & 7) ^ (r & 7)) << 3;
      gld16(Bb + (size_t)(n0 + r) * ldb + k0 + cg, &Bh[b][(w * 32 + c * 8) * 64]);
    }
  };

  stage(0, 0);
  int cur = 0;
  for (int kt = 0; kt < nk; ++kt) {
    __syncthreads();
    if (kt + 1 < nk) stage(cur ^ 1, kt + 1);
#pragma unroll
    for (int kk = 0; kk < 2; kk++) {
      f16x8 af[MI], bf[NJ];
#pragma unroll
      for (int i = 0; i < MI; i++) {
        int row = wr + i * 16 + lr;
        int off = ((kk << 6) | (hi << 4)) ^ ((row & 7) << 4);
        af[i] = *(const f16x8*)((const char*)&Ah[cur][0] + row * 128 + off);
      }
#pragma unroll
      for (int j = 0; j < NJ; j++) {
        int row = wc + j * 16 + lr;
        int off = ((kk << 6) | (hi << 4)) ^ ((row & 7) << 4);
        bf[j] = *(const f16x8*)((const char*)&Bh[cur][0] + row * 128 + off);
      }
#pragma unroll
      for (int i = 0; i < MI; i++)
#pragma unroll
        for (int j = 0; j < NJ; j++)
          acc[i][j] = __builtin_amdgcn_mfma_f32_16x16x32_f16(af[i], bf[j], acc[i][j], 0, 0, 0);
    }
    cur ^= 1;
  }

  gemm_epi<MI, NJ, EPI, RELU, SPLITK>(acc, m0, n0, wr, wc, lr, hi, z, coff, ldc,
                                      bias0, bias1, bias2, bstr, C0, C1, sC1, sC2, vseg);
}

// ---------------------------------------------------------------------------
// Flash attention: one block = 64 q rows of one (b,h); 2 waves x 32 q rows.
// blockIdx.z = layer (batched). Swapped QK^T; S^T C-layout IS the B-fragment
// of mfma_16x16x16_f16 so PV needs no P relayout.
// ---------------------------------------------------------------------------
template<bool CAUSAL>
__global__ __launch_bounds__(128)
void flash_k(const _Float16* __restrict__ qh, const _Float16* __restrict__ kh,
             const _Float16* __restrict__ vTp, _Float16* __restrict__ ob,
             long qs, long ks, long vs, long os)
{
  __shared__ _Float16 Kl[2][64 * 64];
  __shared__ _Float16 Vl[2][64 * 64];
  const uint3 bi = xcd_swz();
  const int qb = bi.x;
  const int bh = bi.y;
  const int layer = bi.z;
  const int b = bh >> 4, h = bh & 15;
  const int q0 = qb * 64;
  const int tid = threadIdx.x;
  const int w = tid >> 6, lane = tid & 63;
  const int lr = lane & 15, hi = lane >> 4;
  const int qw = q0 + w * 32;

  const _Float16* Qp = qh + (size_t)layer * qs + (size_t)bh * SEQ * HD;
  const _Float16* Kp = kh + (size_t)layer * ks + (size_t)bh * SEQ * HD;
  const _Float16* Vp = vTp + (size_t)layer * vs + (size_t)bh * HD * SEQ;
  ob += (size_t)layer * os;

  f16x8 qf[2][2];
#pragma unroll
  for (int jq = 0; jq < 2; jq++)
#pragma unroll
    for (int ds = 0; ds < 2; ds++)
      qf[jq][ds] = *(const f16x8*)(Qp + (size_t)(qw + jq * 16 + lr) * HD + ds * 32 + hi * 8);

  float m[2] = {-1e30f, -1e30f}, l[2] = {0.f, 0.f};
  const f32x4 vz = {0.f, 0.f, 0.f, 0.f};
  f32x4 o[4][2];
#pragma unroll
  for (int dt = 0; dt < 4; dt++)
#pragma unroll
    for (int jq = 0; jq < 2; jq++) o[dt][jq] = vz;

  const int nst = CAUSAL ? ((q0 >> 6) + 1) : (SEQ / 64);

  auto stage = [&](int buf, int kt) {
    const int k0 = kt << 6;
#pragma unroll
    for (int c = 0; c < 4; c++) {
      int r = w * 32 + c * 8 + (lane >> 3);
      int cg = ((lane & 7) ^ (r & 7)) << 3;
      gld16(Kp + (size_t)(k0 + r) * HD + cg, &Kl[buf][(w * 32 + c * 8) * 64]);
      gld16(Vp + (size_t)r * SEQ + k0 + cg, &Vl[buf][(w * 32 + c * 8) * 64]);
    }
  };

  stage(0, 0);
  int cur = 0;
  for (int kt = 0; kt < nst; ++kt) {
    __syncthreads();
    if (kt + 1 < nst) stage(cur ^ 1, kt + 1);
    const int k0 = kt << 6;
    {
      f32x4 s[4][2];
#pragma unroll
      for (int ik = 0; ik < 4; ik++)
#pragma unroll
        for (int jq = 0; jq < 2; jq++) s[ik][jq] = vz;
#pragma unroll
      for (int ds = 0; ds < 2; ds++) {
        f16x8 kf[4];
#pragma unroll
        for (int ik = 0; ik < 4; ik++) {
          int row = ik * 16 + lr;
          int off = (ds * 64 + hi * 16) ^ ((row & 7) << 4);
          kf[ik] = *(const f16x8*)((const char*)&Kl[cur][0] + row * 128 + off);
        }
#pragma unroll
        for (int ik = 0; ik < 4; ik++)
#pragma unroll
          for (int jq = 0; jq < 2; jq++)
            s[ik][jq] = __builtin_amdgcn_mfma_f32_16x16x32_f16(kf[ik], qf[jq][ds], s[ik][jq], 0, 0, 0);
      }
      float mx[2] = {-1e30f, -1e30f};
#pragma unroll
      for (int ik = 0; ik < 4; ik++)
#pragma unroll
        for (int jq = 0; jq < 2; jq++)
#pragma unroll
          for (int r = 0; r < 4; r++) {
            float v = s[ik][jq][r] * 0.03125f;
            if (CAUSAL) {
              int kk = k0 + ik * 16 + hi * 4 + r;
              int qq = qw + jq * 16 + lr;
              if (kk > qq) v = -1e30f;
            }
            s[ik][jq][r] = v;
            mx[jq] = fmaxf(mx[jq], v);
          }
      float sc[2], cs[2] = {0.f, 0.f};
      f16x4 pb[4][2];
#pragma unroll
      for (int jq = 0; jq < 2; jq++) {
        mx[jq] = fmaxf(mx[jq], __shfl_xor(mx[jq], 16, 64));
        mx[jq] = fmaxf(mx[jq], __shfl_xor(mx[jq], 32, 64));
        float mn = fmaxf(m[jq], mx[jq]);
        sc[jq] = __expf(m[jq] - mn);
        m[jq] = mn;
      }
#pragma unroll
      for (int ik = 0; ik < 4; ik++)
#pragma unroll
        for (int jq = 0; jq < 2; jq++)
#pragma unroll
          for (int r = 0; r < 4; r++) {
            float p = __expf(s[ik][jq][r] - m[jq]);
            cs[jq] += p;
            pb[ik][jq][r] = (_Float16)p;
          }
#pragma unroll
      for (int jq = 0; jq < 2; jq++) {
        float t = cs[jq];
        t += __shfl_xor(t, 16, 64);
        t += __shfl_xor(t, 32, 64);
        l[jq] = l[jq] * sc[jq] + t;
      }
#pragma unroll
      for (int dt = 0; dt < 4; dt++)
#pragma unroll
        for (int jq = 0; jq < 2; jq++)
#pragma unroll
          for (int r = 0; r < 4; r++) o[dt][jq][r] *= sc[jq];
#pragma unroll
      for (int ks2 = 0; ks2 < 4; ks2++) {
        f16x4 va[4];
#pragma unroll
        for (int dt = 0; dt < 4; dt++) {
          int row = dt * 16 + lr;
          int off = (ks2 * 32 + hi * 8) ^ ((row & 7) << 4);
          va[dt] = *(const f16x4*)((const char*)&Vl[cur][0] + row * 128 + off);
        }
#pragma unroll
        for (int dt = 0; dt < 4; dt++)
#pragma unroll
          for (int jq = 0; jq < 2; jq++)
            o[dt][jq] = __builtin_amdgcn_mfma_f32_16x16x16f16(va[dt], pb[ks2][jq], o[dt][jq], 0, 0, 0);
      }
    }
    cur ^= 1;
  }

  float inv[2] = {1.f / l[0], 1.f / l[1]};
#pragma unroll
  for (int jq = 0; jq < 2; jq++) {
    int q = qw + jq * 16 + lr;
    size_t rowoff = (size_t)(b * SEQ + q) * ESZ + h * 64;
#pragma unroll
    for (int dt = 0; dt < 4; dt++) {
      f16x4 ov;
#pragma unroll
      for (int r = 0; r < 4; r++) ov[r] = (_Float16)(o[dt][jq][r] * inv[jq]);
      *(f16x4*)(ob + rowoff + dt * 16 + hi * 4) = ov;
    }
  }
}

// ---------------------------------------------------------------------------
// Weight convert+transpose: src f32 [K][Ns] tile -> dst f16 [Ns][K]
// ---------------------------------------------------------------------------
__device__ __forceinline__ void wtr_body(const float* src, _Float16* dst,
                                         int K, int Ns, int k0, int n0,
                                         _Float16 (*t)[80], int tid)
{
  {
    int r = tid >> 4, c4 = (tid & 15) << 2;
#pragma unroll
    for (int rr = 0; rr < 4; rr++) {
      int row = r + rr * 16;
      float4 v = *(const float4*)(src + (size_t)(k0 + row) * Ns + n0 + c4);
      t[c4 + 0][row] = (_Float16)v.x; t[c4 + 1][row] = (_Float16)v.y;
      t[c4 + 2][row] = (_Float16)v.z; t[c4 + 3][row] = (_Float16)v.w;
    }
  }
  __syncthreads();
  {
    int nr = tid >> 3, c8 = (tid & 7) << 3;
#pragma unroll
    for (int rr = 0; rr < 2; rr++) {
      int n = nr + rr * 32;
      f16x8 v = *(const f16x8*)&t[n][c8];
      *(f16x8*)(dst + (size_t)(n0 + n) * K + k0 + c8) = v;
    }
  }
}

struct W8 { const float* p[8]; };

__global__ __launch_bounds__(256)
void wtr8_k(W8 w8, _Float16* dstbase)
{
  __shared__ _Float16 t[64][80];
  int z = blockIdx.z;
  int widx = z >> 2, layer = z & 3;
  const float* src = w8.p[widx] + (size_t)layer * (ESZ * ESZ);
  _Float16* dst = dstbase + (size_t)layer * 16777216 + (size_t)widx * 1048576;
  wtr_body(src, dst, 1024, 1024, blockIdx.x * 64, blockIdx.y * 64, t, threadIdx.x);
}

__global__ __launch_bounds__(256)
void wtrL_k(const float* src, _Float16* dst, int K, int Ns)
{
  __shared__ _Float16 t[64][80];
  int layer = blockIdx.z;
  src += (size_t)layer * K * Ns;
  dst += (size_t)layer * 16777216;
  wtr_body(src, dst, K, Ns, blockIdx.x * 64, blockIdx.y * 64, t, threadIdx.x);
}

// ---------------------------------------------------------------------------
// Embedding + PE (quirk: pe row = batch index).
// ---------------------------------------------------------------------------
__global__ __launch_bounds__(256)
void embed_k(const int* __restrict__ xt, const int* __restrict__ yt,
             const float* __restrict__ emb, const float* __restrict__ cls,
             float* __restrict__ y32, _Float16* __restrict__ y16,
             _Float16* __restrict__ x16)
{
  int row = blockIdx.x;
  bool isx = row < NB * SEQ;
  int rr = isx ? row : row - NB * SEQ;
  int b = rr >> 10, tpos = rr & (SEQ - 1);
  int col0 = threadIdx.x * 4;
  float v[4];
  if (isx && tpos == SEQ - 1) {
#pragma unroll
    for (int j = 0; j < 4; j++) v[j] = cls[col0 + j];
  } else {
    int tok = isx ? xt[b * NXTOK + tpos] : yt[b * SEQ + tpos];
    const float* erow = emb + (size_t)tok * ESZ;
#pragma unroll
    for (int j = 0; j < 4; j++) {
      int e = col0 + j;
      float div = expf((float)(e & ~1) * (-9.210340371976184f / 1024.f));
      float ang = (float)b * div;
      float pe = (e & 1) ? cosf(ang) : sinf(ang);
      v[j] = erow[e] * 32.f + pe;
    }
  }
  size_t off = (size_t)rr * ESZ + col0;
  if (isx) {
#pragma unroll
    for (int j = 0; j < 4; j++) x16[off + j] = (_Float16)v[j];
  } else {
#pragma unroll
    for (int j = 0; j < 4; j++) { y32[off + j] = v[j]; y16[off + j] = (_Float16)v[j]; }
  }
}

// ---------------------------------------------------------------------------
// out = LN(a + sum of NP partials)*g + b; writes f32 + f16.
// blockIdx.y = layer (batched): strides aStr/rStr/oStr/gStr.
// ---------------------------------------------------------------------------
template<int NP>
__global__ __launch_bounds__(256)
void lnres_k(const float* __restrict__ a, const float* __restrict__ r0,
             const float* __restrict__ r1, const float* __restrict__ r2,
             const float* __restrict__ r3,
             const float* __restrict__ g, const float* __restrict__ b,
             float* __restrict__ o32, _Float16* __restrict__ o16,
             long aStr, long rStr, long oStr, int gStr)
{
  int row = blockIdx.x;
  int lz = blockIdx.y;
  a += (size_t)lz * aStr;
  r0 += (size_t)lz * rStr;
  o32 += (size_t)lz * oStr;
  o16 += (size_t)lz * oStr;
  g += (size_t)lz * gStr;
  b += (size_t)lz * gStr;
  size_t off = (size_t)row * ESZ;
  int tid = threadIdx.x;
  float4 va = *(const float4*)(a + off + tid * 4);
  float x[4] = {va.x, va.y, va.z, va.w};
  {
    float4 v = *(const float4*)(r0 + off + tid * 4);
    x[0] += v.x; x[1] += v.y; x[2] += v.z; x[3] += v.w;
  }
  if (NP >= 2) {
    float4 v = *(const float4*)(r1 + off + tid * 4);
    x[0] += v.x; x[1] += v.y; x[2] += v.z; x[3] += v.w;
  }
  if (NP >= 4) {
    float4 v = *(const float4*)(r2 + off + tid * 4);
    x[0] += v.x; x[1] += v.y; x[2] += v.z; x[3] += v.w;
    float4 u = *(const float4*)(r3 + off + tid * 4);
    x[0] += u.x; x[1] += u.y; x[2] += u.z; x[3] += u.w;
  }
  float s = x[0] + x[1] + x[2] + x[3];
  float s2 = x[0] * x[0] + x[1] * x[1] + x[2] * x[2] + x[3] * x[3];
  for (int o = 32; o > 0; o >>= 1) {
    s += __shfl_xor(s, o, 64);
    s2 += __shfl_xor(s2, o, 64);
  }
  __shared__ float rs[4], rs2[4];
  if ((tid & 63) == 0) { rs[tid >> 6] = s; rs2[tid >> 6] = s2; }
  __syncthreads();
  s = rs[0] + rs[1] + rs[2] + rs[3];
  s2 = rs2[0] + rs2[1] + rs2[2] + rs2[3];
  float mean = s * (1.f / ESZ);
  float var = s2 * (1.f / ESZ) - mean * mean;
  float inv = 1.f / sqrtf(var + LNEPS);
  float4 vo;
#pragma unroll
  for (int j = 0; j < 4; j++) {
    int c = tid * 4 + j;
    float o = (x[j] - mean) * inv * g[c] + b[c];
    ((float*)&vo)[j] = o;
    o16[off + c] = (_Float16)o;
  }
  *(float4*)(o32 + off + tid * 4) = vo;
}

// ---------------------------------------------------------------------------

template<int BM, int BN, int EPI, bool RELU, int SPLITK>
static void gemm(hipStream_t st, const _Float16* A, const _Float16* B,
                 const float* b0, const float* b1, const float* b2,
                 void* C0, void* C1, int M, int N, int K,
                 int lda, int ldb, int ldc,
                 int Z, long sAz, long sBz, int cdiv, long sC1, long sC2,
                 int vseg, int bstr)
{
  dim3 g(M / BM, N / BN, Z);
  gemm_k<BM, BN, EPI, RELU, SPLITK><<<g, dim3(256), 0, st>>>(
      A, B, b0, b1, b2, C0, C1, K, lda, ldb, ldc, sAz, sBz, cdiv, sC1, sC2, vseg, bstr);
}

template<int EPI, bool RELU, int SPLITK>
static void gemm8(hipStream_t st, const _Float16* A, const _Float16* B,
                  const float* b0, const float* b1, const float* b2,
                  void* C0, void* C1, int M, int N, int K,
                  int lda, int ldb, int ldc,
                  int Z, long sAz, long sBz, long sC1, long sC2,
                  int vseg, int bstr)
{
  dim3 g(M / 128, N / 256, Z);
  gemm8_k<EPI, RELU, SPLITK><<<g, dim3(512), 0, st>>>(
      A, B, b0, b1, b2, C0, C1, K, lda, ldb, ldc, sAz, sBz, sC1, sC2, vseg, bstr);
}

extern "C" void kernel_launch(void* const* d_in, const int* in_sizes, int n_in,
                              void* d_out, int out_size, void* d_ws, size_t ws_size,
                              hipStream_t stream) {
  (void)n_in; (void)out_size; (void)ws_size;
  const float *emb, *cls, *sWq, *sbq, *sWk, *sbk, *sWv, *sbv, *sWo, *sbo;
  const float *cWq, *cbq, *cWk, *cbk, *cWv, *cbv, *cWo, *cbo;
  const float *fW1, *fb1, *fW2, *fb2, *g1, *g2, *g3, *b1, *b2, *b3;
  const int *xt, *yt;
  if (in_sizes[0] == NB * NXTOK) {
    xt = (const int*)d_in[0]; yt = (const int*)d_in[1];
    emb = (const float*)d_in[2]; cls = (const float*)d_in[3];
    sWq = (const float*)d_in[4]; sbq = (const float*)d_in[5];
    sWk = (const float*)d_in[6]; sbk = (const float*)d_in[7];
    sWv = (const float*)d_in[8]; sbv = (const float*)d_in[9];
    sWo = (const float*)d_in[10]; sbo = (const float*)d_in[11];
    cWq = (const float*)d_in[12]; cbq = (const float*)d_in[13];
    cWk = (const float*)d_in[14]; cbk = (const float*)d_in[15];
    cWv = (const float*)d_in[16]; cbv = (const float*)d_in[17];
    cWo = (const float*)d_in[18]; cbo = (const float*)d_in[19];
    g1 = (const float*)d_in[20]; b1 = (const float*)d_in[21];
    g2 = (const float*)d_in[22]; b2 = (const float*)d_in[23];
    g3 = (const float*)d_in[24]; b3 = (const float*)d_in[25];
    fW1 = (const float*)d_in[26]; fb1 = (const float*)d_in[27];
    fW2 = (const float*)d_in[28]; fb2 = (const float*)d_in[29];
  } else {
    emb = (const float*)d_in[0]; cls = (const float*)d_in[1];
    sWq = (const float*)d_in[2]; sbq = (const float*)d_in[3];
    sWk = (const float*)d_in[4]; sbk = (const float*)d_in[5];
    sWv = (const float*)d_in[6]; sbv = (const float*)d_in[7];
    sWo = (const float*)d_in[8]; sbo = (const float*)d_in[9];
    cWq = (const float*)d_in[10]; cbq = (const float*)d_in[11];
    cWk = (const float*)d_in[12]; cbk = (const float*)d_in[13];
    cWv = (const float*)d_in[14]; cbv = (const float*)d_in[15];
    cWo = (const float*)d_in[16]; cbo = (const float*)d_in[17];
    fW1 = (const float*)d_in[18]; fb1 = (const float*)d_in[19];
    fW2 = (const float*)d_in[20]; fb2 = (const float*)d_in[21];
    g1 = (const float*)d_in[22]; g2 = (const float*)d_in[23]; g3 = (const float*)d_in[24];
    b1 = (const float*)d_in[25]; b2 = (const float*)d_in[26]; b3 = (const float*)d_in[27];
    xt = (const int*)d_in[28]; yt = (const int*)d_in[29];
  }

  // ---- ws layout (~340 MB of ~512 MB) ----
  const size_t MM = (size_t)1 << 20;
  _Float16* W16 = (_Float16*)d_ws;       // weights: 64 MM f16 (4 layers x 16 MM)
  _Float16* qhk_all = W16 + 64 * MM;     // [l]{q 2MM, k 2MM} = 16 MM
  _Float16* vT_all  = W16 + 80 * MM;     // [l] 2MM = 8 MM
  _Float16* ob_all  = W16 + 88 * MM;     // [l] 2MM = 8 MM
  _Float16* y16     = W16 + 96 * MM;     // 2 MM
  _Float16* yl16_all= W16 + 98 * MM;     // [l] 2MM = 8 MM
  _Float16* cqh_all = W16 + 106 * MM;    // [l] 2MM = 8 MM
  _Float16* kh_c    = W16 + 114 * MM;    // 2 MM
  _Float16* vT_c    = W16 + 116 * MM;    // 2 MM
  _Float16* ob_c    = W16 + 118 * MM;    // 2 MM
  _Float16* x16     = W16 + 120 * MM;    // 2 MM
  _Float16* ffn     = W16 + 122 * MM;    // 8 MM
  float* y32      = (float*)(W16 + 130 * MM);  // 2 MM f32
  float* tmp_all  = y32 + 2 * MM;              // 4 x 2MM f32
  float* yl32_all = y32 + 10 * MM;             // 4 x 2MM f32
  float* x32      = y32 + 18 * MM;             // 2 MM f32
  const long SPf = 2048L * 1024;               // 2MM f32 partial/layer stride

  // ---- upfront: weight conversion + embed ----
  W8 w8;
  w8.p[0] = sWq; w8.p[1] = sWk; w8.p[2] = sWv; w8.p[3] = cWq;
  w8.p[4] = cWk; w8.p[5] = cWv; w8.p[6] = sWo; w8.p[7] = cWo;
  wtr8_k<<<dim3(16, 16, 32), 256, 0, stream>>>(w8, W16);
  wtrL_k<<<dim3(16, 64, 4), 256, 0, stream>>>(fW1, W16 + 8 * MM, 1024, 4096);
  wtrL_k<<<dim3(64, 16, 4), 256, 0, stream>>>(fW2, W16 + 12 * MM, 4096, 1024);
  embed_k<<<dim3(2 * NB * SEQ), dim3(256), 0, stream>>>(xt, yt, emb, cls, y32, y16, x16);

  // ---- hoisted: entire self-attn branch + cross-q for ALL layers ----
  gemm8<2, false, 1>(stream, y16, W16, sbq, sbk, sbv,
      qhk_all, vT_all, 2048, 3072, 1024, 1024, 1024, 0,
      4, 0, 16 * MM, 4 * MM, 2 * MM, 2, 1024);
  flash_k<true><<<dim3(16, 32, 4), 128, 0, stream>>>(
      qhk_all, qhk_all + 2 * MM, vT_all, ob_all, 4 * MM, 4 * MM, 2 * MM, 2 * MM);
  gemm<128, 128, 0, false, 1>(stream, ob_all, W16 + 6 * MM, sbo, nullptr, nullptr,
      tmp_all, nullptr, 2048, 1024, 1024, 1024, 1024, 1024,
      4, 2 * MM, 16 * MM, 1, SPf, 0, 0, 1024);
  lnres_k<1><<<dim3(2048, 4), 256, 0, stream>>>(y32, tmp_all, nullptr, nullptr, nullptr,
      g1, b1, yl32_all, yl16_all, 0, SPf, 2 * MM, 1024);
  gemm8<2, false, 1>(stream, yl16_all, W16 + 3 * MM, cbq, nullptr, nullptr,
      cqh_all, nullptr, 2048, 1024, 1024, 1024, 1024, 0,
      4, 2 * MM, 16 * MM, 2 * MM, 0, 3, 1024);

  // ---- sequential decoder chain ----
  for (int l = 0; l < NLAYER; l++) {
    _Float16* wl   = W16 + (size_t)l * 16 * MM;
    _Float16* wckv = wl + 4 * MM;
    _Float16* wco  = wl + 7 * MM;
    _Float16* wf1  = wl + 8 * MM;
    _Float16* wf2  = wl + 12 * MM;

    gemm<128, 128, 2, false, 1>(stream, x16, wckv, cbk + l * ESZ, cbv + l * ESZ,
        nullptr, kh_c, vT_c, 2048, 2048, 1024, 1024, 1024, 0,
        1, 0, 0, 1, 0, 0, 1, 0);
    flash_k<false><<<dim3(16, 32, 1), 128, 0, stream>>>(
        cqh_all + (size_t)l * 2 * MM, kh_c, vT_c, ob_c, 0, 0, 0, 0);
    gemm<128, 128, 0, false, 2>(stream, ob_c, wco, cbo + l * ESZ, nullptr, nullptr,
        tmp_all, nullptr, 2048, 1024, 1024, 1024, 1024, 1024,
        2, 0, 0, 1, SPf, 0, 0, 0);
    lnres_k<2><<<dim3(2048, 1), 256, 0, stream>>>(yl32_all + (size_t)l * 2 * MM,
        tmp_all, tmp_all + SPf, nullptr, nullptr,
        g2 + l * ESZ, b2 + l * ESZ, x32, x16, 0, 0, 0, 0);

    gemm8<1, true, 1>(stream, x16, wf1, fb1 + l * FFD, nullptr, nullptr,
        ffn, nullptr, 2048, 4096, 1024, 1024, 1024, 4096,
        1, 0, 0, 0, 0, 0, 0);
    gemm8<0, false, 4>(stream, ffn, wf2, fb2 + l * ESZ, nullptr, nullptr,
        tmp_all, nullptr, 2048, 1024, 4096, 4096, 4096, 1024,
        4, 0, 0, SPf, 0, 0, 0);
    lnres_k<4><<<dim3(2048, 1), 256, 0, stream>>>(x32, tmp_all, tmp_all + SPf,
        tmp_all + 2 * SPf, tmp_all + 3 * SPf, g3 + l * ESZ, b3 + l * ESZ,
        (l == NLAYER - 1) ? (float*)d_out : x32, x16, 0, 0, 0, 0);
  }
}

// Round 8
// 984.443 us; speedup vs baseline: 9.5249x; 1.0644x over previous
//
#include <hip/hip_runtime.h>
#include <cstdint>

#define ESZ 1024
#define NH 16
#define HD 64
#define NLAYER 4
#define FFD 4096
#define NB 2
#define NXTOK 1023
#define SEQ 1024
#define LNEPS 1e-5f

typedef __attribute__((ext_vector_type(8))) _Float16 f16x8;
typedef __attribute__((ext_vector_type(4))) _Float16 f16x4;
typedef __attribute__((ext_vector_type(4))) float f32x4;

__device__ __forceinline__ void gld16(const void* g, void* l) {
  __builtin_amdgcn_global_load_lds(
      (const __attribute__((address_space(1))) unsigned int*)g,
      (__attribute__((address_space(3))) unsigned int*)l, 16, 0, 0);
}

// Bijective XCD-aware block swizzle (each XCD gets a contiguous work chunk).
__device__ __forceinline__ uint3 xcd_swz() {
  unsigned gx = gridDim.x, gy = gridDim.y;
  unsigned nwg = gx * gy * gridDim.z;
  unsigned lin = (blockIdx.z * gy + blockIdx.y) * gx + blockIdx.x;
  unsigned q = nwg >> 3, r = nwg & 7;
  unsigned xcd = lin & 7, idx = lin >> 3;
  unsigned wid = (xcd < r ? xcd * (q + 1) : r * (q + 1) + (xcd - r) * q) + idx;
  uint3 o;
  o.x = wid % gx;
  unsigned t = wid / gx;
  o.y = t % gy;
  o.z = t / gy;
  return o;
}

// ---------------------------------------------------------------------------
// Shared GEMM epilogue (non-V blocks). EPI: 0 f32, 1 f16, 2 QKV head scatter.
// ---------------------------------------------------------------------------
template<int MI, int NJ, int EPI, bool RELU, int SPLITK>
__device__ __forceinline__ void gemm_epi(
    f32x4 (&acc)[MI][NJ], int m0, int n0, int wr, int wc, int lr, int hi,
    int z, size_t coff, int ldc,
    const float* bias0, const float* bias1, const float* bias2, int bstr,
    void* C0, void* C1, long sC1, long sC2, int vseg)
{
  const int rb = hi * 4;
#pragma unroll
  for (int j = 0; j < NJ; j++) {
    const int n = n0 + wc + j * 16 + lr;
    float bv = 0.f;
    if (EPI == 2) {
      int seg = n >> 10;
      const float* bp = (seg == 0) ? bias0 : ((seg == 1) ? bias1 : bias2);
      bv = bp[bstr * z + (n & 1023)];
    } else if (bias0) bv = bias0[bstr * z + n];
    if (SPLITK > 1 && z > 0) bv = 0.f;
#pragma unroll
    for (int i = 0; i < MI; i++) {
#pragma unroll
      for (int r = 0; r < 4; r++) {
        int row = m0 + wr + i * 16 + rb + r;
        float out = acc[i][j][r] + bv;
        if (RELU) out = fmaxf(out, 0.f);
        if (EPI == 0) {
          ((float*)C0)[coff + (size_t)row * ldc + n] = out;
        } else if (EPI == 1) {
          ((_Float16*)C0)[coff + (size_t)row * ldc + n] = (_Float16)out;
        } else {
          int seg = n >> 10, n1 = n & 1023, h = n1 >> 6, d = n1 & 63;
          int b = row >> 10, s = row & 1023;
          if (seg == vseg)
            ((_Float16*)C1)[(size_t)z * sC2 + (((size_t)b * NH + h) * HD + d) * SEQ + s] = (_Float16)out;
          else
            ((_Float16*)C0)[(size_t)z * sC1 + (size_t)seg * ((size_t)NB * NH * SEQ * HD)
                            + (((size_t)b * NH + h) * SEQ + s) * HD + d] = (_Float16)out;
        }
      }
    }
  }
}

// ---------------------------------------------------------------------------
// 4-wave NT MFMA GEMM, BM=BN=128, BK=32, double-buffered in 32 KB LDS ->
// 4 blocks/CU co-resident (m97/m114: inter-block overlap hides barrier
// drains). gld16 staging, XOR-swizzled global source, swizzled ds_read.
// EPI==2 V-blocks (n0>>10 == vseg): LDS-transpose epilogue -> coalesced
// f16x8 V^T stores (fixes 4x write amplification of the direct scatter).
// ---------------------------------------------------------------------------
template<int BM, int BN, int EPI, bool RELU, int SPLITK>
__global__ __launch_bounds__(256)
void gemm_k(const _Float16* __restrict__ A, const _Float16* __restrict__ Bm,
            const float* __restrict__ bias0, const float* __restrict__ bias1,
            const float* __restrict__ bias2,
            void* __restrict__ C0, void* __restrict__ C1,
            int K, int lda, int ldb, int ldc,
            long sAz, long sBz, int cdiv, long sC1, long sC2, int vseg, int bstr)
{
  constexpr int MI = BM / 32, NJ = BN / 32;
  constexpr int DBUF = 2 * (BM + BN) * 32;            // f16 elems
  constexpr int TBUF = (EPI == 2) ? 128 * 136 : 0;    // transpose buffer
  constexpr int LDSN = (TBUF > DBUF) ? TBUF : DBUF;
  __shared__ _Float16 lds[LDSN];

  const uint3 bi = xcd_swz();
  const int m0 = bi.x * BM;
  const int n0 = bi.y * BN;
  const int z = bi.z;
  const _Float16* Ab;
  const _Float16* Bb;
  size_t coff;
  if (SPLITK > 1) {
    int koff = z * (K / SPLITK);
    Ab = A + koff;
    Bb = Bm + koff;
    coff = (size_t)z * sC1;
  } else {
    Ab = A + (size_t)z * sAz;
    Bb = Bm + (size_t)z * sBz;
    coff = (size_t)(z / cdiv) * sC1 + (size_t)(z % cdiv) * sC2;
  }
  const int tid = threadIdx.x;
  const int lane = tid & 63;
  const int w = tid >> 6;
  const int lr = lane & 15;
  const int hi = lane >> 4;
  const int wr = (w >> 1) * (BM / 2);
  const int wc = (w & 1) * (BN / 2);

  const f32x4 vz = {0.f, 0.f, 0.f, 0.f};
  f32x4 acc[MI][NJ];
#pragma unroll
  for (int i = 0; i < MI; i++)
#pragma unroll
    for (int j = 0; j < NJ; j++) acc[i][j] = vz;

  const int nk = (K / SPLITK) >> 5;

  auto stage = [&](int b, int kt) {
    const int k0 = kt << 5;
    _Float16* Ah = lds + b * (BM * 32);
    _Float16* Bh = lds + 2 * (BM * 32) + b * (BN * 32);
#pragma unroll
    for (int c = 0; c < BM / 64; c++) {          // 16 rows per gld16
      int r = w * (BM / 4) + c * 16 + (lane >> 2);
      int cg = ((lane & 3) ^ (r & 3)) << 3;      // f16 units (16B granules)
      gld16(Ab + (size_t)(m0 + r) * lda + k0 + cg, Ah + (w * (BM / 4) + c * 16) * 32);
    }
#pragma unroll
    for (int c = 0; c < BN / 64; c++) {
      int r = w * (BN / 4) + c * 16 + (lane >> 2);
      int cg = ((lane & 3) ^ (r & 3)) << 3;
      gld16(Bb + (size_t)(n0 + r) * ldb + k0 + cg, Bh + (w * (BN / 4) + c * 16) * 32);
    }
  };

  stage(0, 0);
  int cur = 0;
  for (int kt = 0; kt < nk; ++kt) {
    __syncthreads();
    if (kt + 1 < nk) stage(cur ^ 1, kt + 1);
    const char* Ah = (const char*)(lds + cur * (BM * 32));
    const char* Bh = (const char*)(lds + 2 * (BM * 32) + cur * (BN * 32));
    f16x8 af[MI], bf[NJ];
#pragma unroll
    for (int i = 0; i < MI; i++) {
      int row = wr + i * 16 + lr;
      int off = (hi << 4) ^ ((row & 3) << 4);
      af[i] = *(const f16x8*)(Ah + row * 64 + off);
    }
#pragma unroll
    for (int j = 0; j < NJ; j++) {
      int row = wc + j * 16 + lr;
      int off = (hi << 4) ^ ((row & 3) << 4);
      bf[j] = *(const f16x8*)(Bh + row * 64 + off);
    }
#pragma unroll
    for (int i = 0; i < MI; i++)
#pragma unroll
      for (int j = 0; j < NJ; j++)
        acc[i][j] = __builtin_amdgcn_mfma_f32_16x16x32_f16(af[i], bf[j], acc[i][j], 0, 0, 0);
    cur ^= 1;
  }

  // ---- V^T blocks: coalesced transpose epilogue through LDS ----
  if (EPI == 2 && (n0 >> 10) == vseg) {
    __syncthreads();
    _Float16* T = lds;   // [128][136]
    const float* bp = (vseg == 0) ? bias0 : ((vseg == 1) ? bias1 : bias2);
#pragma unroll
    for (int j = 0; j < NJ; j++) {
      int nloc = wc + j * 16 + lr;
      float bv = bp[bstr * z + ((n0 + nloc) & 1023)];
#pragma unroll
      for (int i = 0; i < MI; i++) {
        f16x4 tv;
#pragma unroll
        for (int r = 0; r < 4; r++) tv[r] = (_Float16)(acc[i][j][r] + bv);
        *(f16x4*)(T + nloc * 136 + wr + i * 16 + hi * 4) = tv;
      }
    }
    __syncthreads();
    int rowT = tid >> 1;
    int c0 = (tid & 1) << 6;
    int nn = (n0 & 1023) + rowT;
    int h = nn >> 6, d = nn & 63;
    int bb = m0 >> 10;
    int s0 = (m0 & 1023) + c0;
    _Float16* dst = (_Float16*)C1 + (size_t)z * sC2
                  + (((size_t)bb * NH + h) * HD + d) * SEQ + s0;
    const _Float16* src = T + rowT * 136 + c0;
#pragma unroll
    for (int t2 = 0; t2 < 8; t2++)
      *(f16x8*)(dst + t2 * 8) = *(const f16x8*)(src + t2 * 8);
    return;
  }

  gemm_epi<MI, NJ, EPI, RELU, SPLITK>(acc, m0, n0, wr, wc, lr, hi, z, coff, ldc,
                                      bias0, bias1, bias2, bstr, C0, C1, sC1, sC2, vseg);
}

// ---------------------------------------------------------------------------
// Flash attention: one block = 64 q rows of one (b,h); 2 waves x 32 q rows.
// blockIdx.z = layer (batched). Swapped QK^T; S^T C-layout IS the B-fragment
// of mfma_16x16x16_f16 so PV needs no P relayout.
// ---------------------------------------------------------------------------
template<bool CAUSAL>
__global__ __launch_bounds__(128)
void flash_k(const _Float16* __restrict__ qh, const _Float16* __restrict__ kh,
             const _Float16* __restrict__ vTp, _Float16* __restrict__ ob,
             long qs, long ks, long vs, long os)
{
  __shared__ _Float16 Kl[2][64 * 64];
  __shared__ _Float16 Vl[2][64 * 64];
  const uint3 bi = xcd_swz();
  const int qb = bi.x;
  const int bh = bi.y;
  const int layer = bi.z;
  const int b = bh >> 4, h = bh & 15;
  const int q0 = qb * 64;
  const int tid = threadIdx.x;
  const int w = tid >> 6, lane = tid & 63;
  const int lr = lane & 15, hi = lane >> 4;
  const int qw = q0 + w * 32;

  const _Float16* Qp = qh + (size_t)layer * qs + (size_t)bh * SEQ * HD;
  const _Float16* Kp = kh + (size_t)layer * ks + (size_t)bh * SEQ * HD;
  const _Float16* Vp = vTp + (size_t)layer * vs + (size_t)bh * HD * SEQ;
  ob += (size_t)layer * os;

  f16x8 qf[2][2];
#pragma unroll
  for (int jq = 0; jq < 2; jq++)
#pragma unroll
    for (int ds = 0; ds < 2; ds++)
      qf[jq][ds] = *(const f16x8*)(Qp + (size_t)(qw + jq * 16 + lr) * HD + ds * 32 + hi * 8);

  float m[2] = {-1e30f, -1e30f}, l[2] = {0.f, 0.f};
  const f32x4 vz = {0.f, 0.f, 0.f, 0.f};
  f32x4 o[4][2];
#pragma unroll
  for (int dt = 0; dt < 4; dt++)
#pragma unroll
    for (int jq = 0; jq < 2; jq++) o[dt][jq] = vz;

  const int nst = CAUSAL ? ((q0 >> 6) + 1) : (SEQ / 64);

  auto stage = [&](int buf, int kt) {
    const int k0 = kt << 6;
#pragma unroll
    for (int c = 0; c < 4; c++) {
      int r = w * 32 + c * 8 + (lane >> 3);
      int cg = ((lane & 7) ^ (r & 7)) << 3;
      gld16(Kp + (size_t)(k0 + r) * HD + cg, &Kl[buf][(w * 32 + c * 8) * 64]);
      gld16(Vp + (size_t)r * SEQ + k0 + cg, &Vl[buf][(w * 32 + c * 8) * 64]);
    }
  };

  stage(0, 0);
  int cur = 0;
  for (int kt = 0; kt < nst; ++kt) {
    __syncthreads();
    if (kt + 1 < nst) stage(cur ^ 1, kt + 1);
    const int k0 = kt << 6;
    {
      f32x4 s[4][2];
#pragma unroll
      for (int ik = 0; ik < 4; ik++)
#pragma unroll
        for (int jq = 0; jq < 2; jq++) s[ik][jq] = vz;
#pragma unroll
      for (int ds = 0; ds < 2; ds++) {
        f16x8 kf[4];
#pragma unroll
        for (int ik = 0; ik < 4; ik++) {
          int row = ik * 16 + lr;
          int off = (ds * 64 + hi * 16) ^ ((row & 7) << 4);
          kf[ik] = *(const f16x8*)((const char*)&Kl[cur][0] + row * 128 + off);
        }
#pragma unroll
        for (int ik = 0; ik < 4; ik++)
#pragma unroll
          for (int jq = 0; jq < 2; jq++)
            s[ik][jq] = __builtin_amdgcn_mfma_f32_16x16x32_f16(kf[ik], qf[jq][ds], s[ik][jq], 0, 0, 0);
      }
      float mx[2] = {-1e30f, -1e30f};
#pragma unroll
      for (int ik = 0; ik < 4; ik++)
#pragma unroll
        for (int jq = 0; jq < 2; jq++)
#pragma unroll
          for (int r = 0; r < 4; r++) {
            float v = s[ik][jq][r] * 0.03125f;
            if (CAUSAL) {
              int kk = k0 + ik * 16 + hi * 4 + r;
              int qq = qw + jq * 16 + lr;
              if (kk > qq) v = -1e30f;
            }
            s[ik][jq][r] = v;
            mx[jq] = fmaxf(mx[jq], v);
          }
      float sc[2], cs[2] = {0.f, 0.f};
      f16x4 pb[4][2];
#pragma unroll
      for (int jq = 0; jq < 2; jq++) {
        mx[jq] = fmaxf(mx[jq], __shfl_xor(mx[jq], 16, 64));
        mx[jq] = fmaxf(mx[jq], __shfl_xor(mx[jq], 32, 64));
        float mn = fmaxf(m[jq], mx[jq]);
        sc[jq] = __expf(m[jq] - mn);
        m[jq] = mn;
      }
#pragma unroll
      for (int ik = 0; ik < 4; ik++)
#pragma unroll
        for (int jq = 0; jq < 2; jq++)
#pragma unroll
          for (int r = 0; r < 4; r++) {
            float p = __expf(s[ik][jq][r] - m[jq]);
            cs[jq] += p;
            pb[ik][jq][r] = (_Float16)p;
          }
#pragma unroll
      for (int jq = 0; jq < 2; jq++) {
        float t = cs[jq];
        t += __shfl_xor(t, 16, 64);
        t += __shfl_xor(t, 32, 64);
        l[jq] = l[jq] * sc[jq] + t;
      }
#pragma unroll
      for (int dt = 0; dt < 4; dt++)
#pragma unroll
        for (int jq = 0; jq < 2; jq++)
#pragma unroll
          for (int r = 0; r < 4; r++) o[dt][jq][r] *= sc[jq];
#pragma unroll
      for (int ks2 = 0; ks2 < 4; ks2++) {
        f16x4 va[4];
#pragma unroll
        for (int dt = 0; dt < 4; dt++) {
          int row = dt * 16 + lr;
          int off = (ks2 * 32 + hi * 8) ^ ((row & 7) << 4);
          va[dt] = *(const f16x4*)((const char*)&Vl[cur][0] + row * 128 + off);
        }
#pragma unroll
        for (int dt = 0; dt < 4; dt++)
#pragma unroll
          for (int jq = 0; jq < 2; jq++)
            o[dt][jq] = __builtin_amdgcn_mfma_f32_16x16x16f16(va[dt], pb[ks2][jq], o[dt][jq], 0, 0, 0);
      }
    }
    cur ^= 1;
  }

  float inv[2] = {1.f / l[0], 1.f / l[1]};
#pragma unroll
  for (int jq = 0; jq < 2; jq++) {
    int q = qw + jq * 16 + lr;
    size_t rowoff = (size_t)(b * SEQ + q) * ESZ + h * 64;
#pragma unroll
    for (int dt = 0; dt < 4; dt++) {
      f16x4 ov;
#pragma unroll
      for (int r = 0; r < 4; r++) ov[r] = (_Float16)(o[dt][jq][r] * inv[jq]);
      *(f16x4*)(ob + rowoff + dt * 16 + hi * 4) = ov;
    }
  }
}

// ---------------------------------------------------------------------------
// Weight convert+transpose: src f32 [K][Ns] tile -> dst f16 [Ns][K]
// ---------------------------------------------------------------------------
__device__ __forceinline__ void wtr_body(const float* src, _Float16* dst,
                                         int K, int Ns, int k0, int n0,
                                         _Float16 (*t)[80], int tid)
{
  {
    int r = tid >> 4, c4 = (tid & 15) << 2;
#pragma unroll
    for (int rr = 0; rr < 4; rr++) {
      int row = r + rr * 16;
      float4 v = *(const float4*)(src + (size_t)(k0 + row) * Ns + n0 + c4);
      t[c4 + 0][row] = (_Float16)v.x; t[c4 + 1][row] = (_Float16)v.y;
      t[c4 + 2][row] = (_Float16)v.z; t[c4 + 3][row] = (_Float16)v.w;
    }
  }
  __syncthreads();
  {
    int nr = tid >> 3, c8 = (tid & 7) << 3;
#pragma unroll
    for (int rr = 0; rr < 2; rr++) {
      int n = nr + rr * 32;
      f16x8 v = *(const f16x8*)&t[n][c8];
      *(f16x8*)(dst + (size_t)(n0 + n) * K + k0 + c8) = v;
    }
  }
}

struct W8 { const float* p[8]; };

__global__ __launch_bounds__(256)
void wtr8_k(W8 w8, _Float16* dstbase)
{
  __shared__ _Float16 t[64][80];
  int z = blockIdx.z;
  int widx = z >> 2, layer = z & 3;
  const float* src = w8.p[widx] + (size_t)layer * (ESZ * ESZ);
  _Float16* dst = dstbase + (size_t)layer * 16777216 + (size_t)widx * 1048576;
  wtr_body(src, dst, 1024, 1024, blockIdx.x * 64, blockIdx.y * 64, t, threadIdx.x);
}

__global__ __launch_bounds__(256)
void wtrL_k(const float* src, _Float16* dst, int K, int Ns)
{
  __shared__ _Float16 t[64][80];
  int layer = blockIdx.z;
  src += (size_t)layer * K * Ns;
  dst += (size_t)layer * 16777216;
  wtr_body(src, dst, K, Ns, blockIdx.x * 64, blockIdx.y * 64, t, threadIdx.x);
}

// ---------------------------------------------------------------------------
// Embedding + PE (quirk: pe row = batch index).
// ---------------------------------------------------------------------------
__global__ __launch_bounds__(256)
void embed_k(const int* __restrict__ xt, const int* __restrict__ yt,
             const float* __restrict__ emb, const float* __restrict__ cls,
             float* __restrict__ y32, _Float16* __restrict__ y16,
             _Float16* __restrict__ x16)
{
  int row = blockIdx.x;
  bool isx = row < NB * SEQ;
  int rr = isx ? row : row - NB * SEQ;
  int b = rr >> 10, tpos = rr & (SEQ - 1);
  int col0 = threadIdx.x * 4;
  float v[4];
  if (isx && tpos == SEQ - 1) {
#pragma unroll
    for (int j = 0; j < 4; j++) v[j] = cls[col0 + j];
  } else {
    int tok = isx ? xt[b * NXTOK + tpos] : yt[b * SEQ + tpos];
    const float* erow = emb + (size_t)tok * ESZ;
#pragma unroll
    for (int j = 0; j < 4; j++) {
      int e = col0 + j;
      float div = expf((float)(e & ~1) * (-9.210340371976184f / 1024.f));
      float ang = (float)b * div;
      float pe = (e & 1) ? cosf(ang) : sinf(ang);
      v[j] = erow[e] * 32.f + pe;
    }
  }
  size_t off = (size_t)rr * ESZ + col0;
  if (isx) {
#pragma unroll
    for (int j = 0; j < 4; j++) x16[off + j] = (_Float16)v[j];
  } else {
#pragma unroll
    for (int j = 0; j < 4; j++) { y32[off + j] = v[j]; y16[off + j] = (_Float16)v[j]; }
  }
}

// ---------------------------------------------------------------------------
// out = LN(a + sum of NP partials)*g + b; writes f32 + f16.
// blockIdx.y = layer (batched): strides aStr/rStr/oStr/gStr.
// ---------------------------------------------------------------------------
template<int NP>
__global__ __launch_bounds__(256)
void lnres_k(const float* __restrict__ a, const float* __restrict__ r0,
             const float* __restrict__ r1, const float* __restrict__ r2,
             const float* __restrict__ r3,
             const float* __restrict__ g, const float* __restrict__ b,
             float* __restrict__ o32, _Float16* __restrict__ o16,
             long aStr, long rStr, long oStr, int gStr)
{
  int row = blockIdx.x;
  int lz = blockIdx.y;
  a += (size_t)lz * aStr;
  r0 += (size_t)lz * rStr;
  o32 += (size_t)lz * oStr;
  o16 += (size_t)lz * oStr;
  g += (size_t)lz * gStr;
  b += (size_t)lz * gStr;
  size_t off = (size_t)row * ESZ;
  int tid = threadIdx.x;
  float4 va = *(const float4*)(a + off + tid * 4);
  float x[4] = {va.x, va.y, va.z, va.w};
  {
    float4 v = *(const float4*)(r0 + off + tid * 4);
    x[0] += v.x; x[1] += v.y; x[2] += v.z; x[3] += v.w;
  }
  if (NP >= 2) {
    float4 v = *(const float4*)(r1 + off + tid * 4);
    x[0] += v.x; x[1] += v.y; x[2] += v.z; x[3] += v.w;
  }
  if (NP >= 4) {
    float4 v = *(const float4*)(r2 + off + tid * 4);
    x[0] += v.x; x[1] += v.y; x[2] += v.z; x[3] += v.w;
    float4 u = *(const float4*)(r3 + off + tid * 4);
    x[0] += u.x; x[1] += u.y; x[2] += u.z; x[3] += u.w;
  }
  float s = x[0] + x[1] + x[2] + x[3];
  float s2 = x[0] * x[0] + x[1] * x[1] + x[2] * x[2] + x[3] * x[3];
  for (int o = 32; o > 0; o >>= 1) {
    s += __shfl_xor(s, o, 64);
    s2 += __shfl_xor(s2, o, 64);
  }
  __shared__ float rs[4], rs2[4];
  if ((tid & 63) == 0) { rs[tid >> 6] = s; rs2[tid >> 6] = s2; }
  __syncthreads();
  s = rs[0] + rs[1] + rs[2] + rs[3];
  s2 = rs2[0] + rs2[1] + rs2[2] + rs2[3];
  float mean = s * (1.f / ESZ);
  float var = s2 * (1.f / ESZ) - mean * mean;
  float inv = 1.f / sqrtf(var + LNEPS);
  float4 vo;
#pragma unroll
  for (int j = 0; j < 4; j++) {
    int c = tid * 4 + j;
    float o = (x[j] - mean) * inv * g[c] + b[c];
    ((float*)&vo)[j] = o;
    o16[off + c] = (_Float16)o;
  }
  *(float4*)(o32 + off + tid * 4) = vo;
}

// ---------------------------------------------------------------------------

template<int BM, int BN, int EPI, bool RELU, int SPLITK>
static void gemm(hipStream_t st, const _Float16* A, const _Float16* B,
                 const float* b0, const float* b1, const float* b2,
                 void* C0, void* C1, int M, int N, int K,
                 int lda, int ldb, int ldc,
                 int Z, long sAz, long sBz, int cdiv, long sC1, long sC2,
                 int vseg, int bstr)
{
  dim3 g(M / BM, N / BN, Z);
  gemm_k<BM, BN, EPI, RELU, SPLITK><<<g, dim3(256), 0, st>>>(
      A, B, b0, b1, b2, C0, C1, K, lda, ldb, ldc, sAz, sBz, cdiv, sC1, sC2, vseg, bstr);
}

extern "C" void kernel_launch(void* const* d_in, const int* in_sizes, int n_in,
                              void* d_out, int out_size, void* d_ws, size_t ws_size,
                              hipStream_t stream) {
  (void)n_in; (void)out_size; (void)ws_size;
  const float *emb, *cls, *sWq, *sbq, *sWk, *sbk, *sWv, *sbv, *sWo, *sbo;
  const float *cWq, *cbq, *cWk, *cbk, *cWv, *cbv, *cWo, *cbo;
  const float *fW1, *fb1, *fW2, *fb2, *g1, *g2, *g3, *b1, *b2, *b3;
  const int *xt, *yt;
  if (in_sizes[0] == NB * NXTOK) {
    xt = (const int*)d_in[0]; yt = (const int*)d_in[1];
    emb = (const float*)d_in[2]; cls = (const float*)d_in[3];
    sWq = (const float*)d_in[4]; sbq = (const float*)d_in[5];
    sWk = (const float*)d_in[6]; sbk = (const float*)d_in[7];
    sWv = (const float*)d_in[8]; sbv = (const float*)d_in[9];
    sWo = (const float*)d_in[10]; sbo = (const float*)d_in[11];
    cWq = (const float*)d_in[12]; cbq = (const float*)d_in[13];
    cWk = (const float*)d_in[14]; cbk = (const float*)d_in[15];
    cWv = (const float*)d_in[16]; cbv = (const float*)d_in[17];
    cWo = (const float*)d_in[18]; cbo = (const float*)d_in[19];
    g1 = (const float*)d_in[20]; b1 = (const float*)d_in[21];
    g2 = (const float*)d_in[22]; b2 = (const float*)d_in[23];
    g3 = (const float*)d_in[24]; b3 = (const float*)d_in[25];
    fW1 = (const float*)d_in[26]; fb1 = (const float*)d_in[27];
    fW2 = (const float*)d_in[28]; fb2 = (const float*)d_in[29];
  } else {
    emb = (const float*)d_in[0]; cls = (const float*)d_in[1];
    sWq = (const float*)d_in[2]; sbq = (const float*)d_in[3];
    sWk = (const float*)d_in[4]; sbk = (const float*)d_in[5];
    sWv = (const float*)d_in[6]; sbv = (const float*)d_in[7];
    sWo = (const float*)d_in[8]; sbo = (const float*)d_in[9];
    cWq = (const float*)d_in[10]; cbq = (const float*)d_in[11];
    cWk = (const float*)d_in[12]; cbk = (const float*)d_in[13];
    cWv = (const float*)d_in[14]; cbv = (const float*)d_in[15];
    cWo = (const float*)d_in[16]; cbo = (const float*)d_in[17];
    fW1 = (const float*)d_in[18]; fb1 = (const float*)d_in[19];
    fW2 = (const float*)d_in[20]; fb2 = (const float*)d_in[21];
    g1 = (const float*)d_in[22]; g2 = (const float*)d_in[23]; g3 = (const float*)d_in[24];
    b1 = (const float*)d_in[25]; b2 = (const float*)d_in[26]; b3 = (const float*)d_in[27];
    xt = (const int*)d_in[28]; yt = (const int*)d_in[29];
  }

  // ---- ws layout (~340 MB of ~512 MB) ----
  const size_t MM = (size_t)1 << 20;
  _Float16* W16 = (_Float16*)d_ws;       // weights: 64 MM f16 (4 layers x 16 MM)
  _Float16* qhk_all = W16 + 64 * MM;     // [l]{q 2MM, k 2MM} = 16 MM
  _Float16* vT_all  = W16 + 80 * MM;     // [l] 2MM = 8 MM
  _Float16* ob_all  = W16 + 88 * MM;     // [l] 2MM = 8 MM
  _Float16* y16     = W16 + 96 * MM;     // 2 MM
  _Float16* yl16_all= W16 + 98 * MM;     // [l] 2MM = 8 MM
  _Float16* cqh_all = W16 + 106 * MM;    // [l] 2MM = 8 MM
  _Float16* kh_c    = W16 + 114 * MM;    // 2 MM
  _Float16* vT_c    = W16 + 116 * MM;    // 2 MM
  _Float16* ob_c    = W16 + 118 * MM;    // 2 MM
  _Float16* x16     = W16 + 120 * MM;    // 2 MM
  _Float16* ffn     = W16 + 122 * MM;    // 8 MM
  float* y32      = (float*)(W16 + 130 * MM);  // 2 MM f32
  float* tmp_all  = y32 + 2 * MM;              // 4 x 2MM f32
  float* yl32_all = y32 + 10 * MM;             // 4 x 2MM f32
  float* x32      = y32 + 18 * MM;             // 2 MM f32
  const long SPf = 2048L * 1024;               // 2MM f32 partial/layer stride

  // ---- upfront: weight conversion + embed ----
  W8 w8;
  w8.p[0] = sWq; w8.p[1] = sWk; w8.p[2] = sWv; w8.p[3] = cWq;
  w8.p[4] = cWk; w8.p[5] = cWv; w8.p[6] = sWo; w8.p[7] = cWo;
  wtr8_k<<<dim3(16, 16, 32), 256, 0, stream>>>(w8, W16);
  wtrL_k<<<dim3(16, 64, 4), 256, 0, stream>>>(fW1, W16 + 8 * MM, 1024, 4096);
  wtrL_k<<<dim3(64, 16, 4), 256, 0, stream>>>(fW2, W16 + 12 * MM, 4096, 1024);
  embed_k<<<dim3(2 * NB * SEQ), dim3(256), 0, stream>>>(xt, yt, emb, cls, y32, y16, x16);

  // ---- hoisted: entire self-attn branch + cross-q for ALL layers ----
  gemm<128, 128, 2, false, 1>(stream, y16, W16, sbq, sbk, sbv,
      qhk_all, vT_all, 2048, 3072, 1024, 1024, 1024, 0,
      4, 0, 16 * MM, 1, 4 * MM, 2 * MM, 2, 1024);
  flash_k<true><<<dim3(16, 32, 4), 128, 0, stream>>>(
      qhk_all, qhk_all + 2 * MM, vT_all, ob_all, 4 * MM, 4 * MM, 2 * MM, 2 * MM);
  gemm<128, 128, 0, false, 1>(stream, ob_all, W16 + 6 * MM, sbo, nullptr, nullptr,
      tmp_all, nullptr, 2048, 1024, 1024, 1024, 1024, 1024,
      4, 2 * MM, 16 * MM, 1, SPf, 0, 0, 1024);
  lnres_k<1><<<dim3(2048, 4), 256, 0, stream>>>(y32, tmp_all, nullptr, nullptr, nullptr,
      g1, b1, yl32_all, yl16_all, 0, SPf, 2 * MM, 1024);
  gemm<128, 128, 2, false, 1>(stream, yl16_all, W16 + 3 * MM, cbq, nullptr, nullptr,
      cqh_all, nullptr, 2048, 1024, 1024, 1024, 1024, 0,
      4, 2 * MM, 16 * MM, 1, 2 * MM, 0, 3, 1024);

  // ---- sequential decoder chain ----
  for (int l = 0; l < NLAYER; l++) {
    _Float16* wl   = W16 + (size_t)l * 16 * MM;
    _Float16* wckv = wl + 4 * MM;
    _Float16* wco  = wl + 7 * MM;
    _Float16* wf1  = wl + 8 * MM;
    _Float16* wf2  = wl + 12 * MM;

    gemm<128, 128, 2, false, 1>(stream, x16, wckv, cbk + l * ESZ, cbv + l * ESZ,
        nullptr, kh_c, vT_c, 2048, 2048, 1024, 1024, 1024, 0,
        1, 0, 0, 1, 0, 0, 1, 0);
    flash_k<false><<<dim3(16, 32, 1), 128, 0, stream>>>(
        cqh_all + (size_t)l * 2 * MM, kh_c, vT_c, ob_c, 0, 0, 0, 0);
    gemm<128, 128, 0, false, 4>(stream, ob_c, wco, cbo + l * ESZ, nullptr, nullptr,
        tmp_all, nullptr, 2048, 1024, 1024, 1024, 1024, 1024,
        4, 0, 0, 1, SPf, 0, 0, 0);
    lnres_k<4><<<dim3(2048, 1), 256, 0, stream>>>(yl32_all + (size_t)l * 2 * MM,
        tmp_all, tmp_all + SPf, tmp_all + 2 * SPf, tmp_all + 3 * SPf,
        g2 + l * ESZ, b2 + l * ESZ, x32, x16, 0, 0, 0, 0);

    gemm<128, 128, 1, true, 1>(stream, x16, wf1, fb1 + l * FFD, nullptr, nullptr,
        ffn, nullptr, 2048, 4096, 1024, 1024, 1024, 4096,
        1, 0, 0, 1, 0, 0, 0, 0);
    gemm<128, 128, 0, false, 4>(stream, ffn, wf2, fb2 + l * ESZ, nullptr, nullptr,
        tmp_all, nullptr, 2048, 1024, 4096, 4096, 4096, 1024,
        4, 0, 0, 1, SPf, 0, 0, 0);
    lnres_k<4><<<dim3(2048, 1), 256, 0, stream>>>(x32, tmp_all, tmp_all + SPf,
        tmp_all + 2 * SPf, tmp_all + 3 * SPf, g3 + l * ESZ, b3 + l * ESZ,
        (l == NLAYER - 1) ? (float*)d_out : x32, x16, 0, 0, 0, 0);
  }
}